// Round 3
// baseline (883.449 us; speedup 1.0000x reference)
//
#include <hip/hip_runtime.h>

#define TILE 64
#define BK 16

#define B_ 4
#define T_ 1024
#define NH 12
#define HS 64
#define CDIM 768
#define QKVW 2304   // 3*CDIM

#define SLOTS 12
#define SLOT_F 192  // floats per ring slot: q[64] k[64] v[64]

// s_waitcnt immediate: vmcnt 6-bit split [3:0]+[15:14], expcnt [6:4]=7 (no wait),
// lgkmcnt [11:8]=0xF (no wait) unless overridden.
#define WAIT_VM(vm)  ((((vm) & 0xF)) | ((((vm) >> 4) & 0x3) << 14) | (7 << 4) | (0xF << 8))
#define WAIT_LGKM0   (0xF | (0x3 << 14) | (7 << 4))   // vm=63 (no wait), lgkm=0

// ---------------- GEMM: C[M,N] = A[M,K] @ B[K,N] (+ R) -----------------
template<bool ADD_RES>
__global__ __launch_bounds__(256)
void gemm64(const float* __restrict__ A, const float* __restrict__ Bm,
            const float* __restrict__ R, float* __restrict__ C,
            int M, int N, int K) {
    __shared__ float As[BK][TILE + 4];
    __shared__ float Bs[BK][TILE];

    const int tid = threadIdx.x;
    const int tm  = tid >> 4;
    const int tn  = tid & 15;
    const int m0  = blockIdx.y * TILE;
    const int n0  = blockIdx.x * TILE;

    const int am = tid >> 2;
    const int ak = (tid & 3) * 4;
    const int bk = tid >> 4;
    const int bn = (tid & 15) * 4;

    const float* Aptr = A + (size_t)(m0 + am) * K + ak;
    const float* Bptr = Bm + (size_t)bk * N + n0 + bn;

    float acc[4][4];
#pragma unroll
    for (int ii = 0; ii < 4; ++ii)
#pragma unroll
        for (int jj = 0; jj < 4; ++jj) acc[ii][jj] = 0.f;

    for (int k0 = 0; k0 < K; k0 += BK) {
        const float4 av = *(const float4*)(Aptr + k0);
        const float4 bv = *(const float4*)(Bptr + (size_t)k0 * N);
        __syncthreads();
        As[ak + 0][am] = av.x;
        As[ak + 1][am] = av.y;
        As[ak + 2][am] = av.z;
        As[ak + 3][am] = av.w;
        *(float4*)&Bs[bk][bn] = bv;
        __syncthreads();
#pragma unroll
        for (int kk = 0; kk < BK; ++kk) {
            const float4 a = *(const float4*)&As[kk][tm * 4];
            const float4 b = *(const float4*)&Bs[kk][tn * 4];
            const float ar[4] = {a.x, a.y, a.z, a.w};
            const float br[4] = {b.x, b.y, b.z, b.w};
#pragma unroll
            for (int ii = 0; ii < 4; ++ii)
#pragma unroll
                for (int jj = 0; jj < 4; ++jj)
                    acc[ii][jj] = fmaf(ar[ii], br[jj], acc[ii][jj]);
        }
    }

#pragma unroll
    for (int ii = 0; ii < 4; ++ii) {
        const int m = m0 + tm * 4 + ii;
        float4 out;
        out.x = acc[ii][0]; out.y = acc[ii][1]; out.z = acc[ii][2]; out.w = acc[ii][3];
        if (ADD_RES) {
            const float4 r = *(const float4*)(R + (size_t)m * N + n0 + tn * 4);
            out.x += r.x; out.y += r.y; out.z += r.z; out.w += r.w;
        }
        *(float4*)(C + (size_t)m * N + n0 + tn * 4) = out;
    }
}

// -------- per-64-element standardization (mean / unbiased std) ----------
__global__ __launch_bounds__(256)
void norm_kernel(float* __restrict__ qkv) {
    const int g    = blockIdx.x * 4 + (threadIdx.x >> 6);
    const int lane = threadIdx.x & 63;
    const size_t idx = (size_t)g * 64 + lane;
    const float v = qkv[idx];
    float s = v, ss = v * v;
#pragma unroll
    for (int off = 1; off < 64; off <<= 1) {
        s  += __shfl_xor(s,  off, 64);
        ss += __shfl_xor(ss, off, 64);
    }
    const float mu  = s * (1.0f / 64.0f);
    const float var = (ss - 64.0f * mu * mu) * (1.0f / 63.0f);
    const float rs  = rsqrtf(var);
    qkv[idx] = (v - mu) * rs;
}

// ----------------------------- scan -------------------------------------
// 192 single-wave blocks: 48 (b,h) x 4 row-blocks (16 rows each).
// Lane (r,cg): r=tid>>2 row 0..15, cg=tid&3 col-group (16 cols). S[16]/lane.
// Async global->LDS ring (12 slots) + register double-buffer from LDS.
// Per-iter vmcnt ops: 3 global_load_lds + 1 store = 4; wait vmcnt(32) ensures
// slot's 3 loads (issued ~12 iters = 48 ops ago; min 33 across all t) done.

__device__ __forceinline__ void async_vec(const float* g, const float* lds_base) {
    // lane L: g[L] -> lds_base[L]  (HW: uniform LDS base + lane*4)
    __builtin_amdgcn_global_load_lds(
        (const __attribute__((address_space(1))) unsigned int*)g,
        (__attribute__((address_space(3))) unsigned int*)(lds_base),
        4, 0, 0);
}

__device__ __forceinline__ void refill_slot(const float* stepbase, const float* slotbase, int lane) {
    async_vec(stepbase + lane,            slotbase);        // q
    async_vec(stepbase + CDIM + lane,     slotbase + 64);   // k
    async_vec(stepbase + 2 * CDIM + lane, slotbase + 128);  // v
}

__device__ __forceinline__ void load16s(const float* p, float (&d)[16]) {
    const float4 a = *(const float4*)(p + 0);
    const float4 b = *(const float4*)(p + 4);
    const float4 c = *(const float4*)(p + 8);
    const float4 e = *(const float4*)(p + 12);
    d[0]=a.x; d[1]=a.y; d[2]=a.z; d[3]=a.w;
    d[4]=b.x; d[5]=b.y; d[6]=b.z; d[7]=b.w;
    d[8]=c.x; d[9]=c.y; d[10]=c.z; d[11]=c.w;
    d[12]=e.x; d[13]=e.y; d[14]=e.z; d[15]=e.w;
}

__device__ __forceinline__ void read_slot(const float* slot, int j0, int i,
                                          float (&q)[16], float (&k)[16], float (&v)[16],
                                          float& ki) {
    load16s(slot + j0,        q);
    load16s(slot + 64 + j0,   k);
    load16s(slot + 128 + j0,  v);
    ki = slot[64 + i];
}

// step t: bu=-0.01*uc; S=0.99S+bu*k+ki*v; ov=S.q (this step); un=S.kn (next step's k)
__device__ __forceinline__ void scan_step(float (&S)[16], float& uc,
                                          const float (&q)[16], const float (&k)[16],
                                          const float (&v)[16], float ki,
                                          const float (&kn)[16],
                                          float* __restrict__ sp, bool doStore) {
    const float bu = -0.01f * uc;
    float ov0 = 0.f, ov1 = 0.f, un0 = 0.f, un1 = 0.f;
#pragma unroll
    for (int z = 0; z < 16; z += 2) {
        const float sa = fmaf(bu, k[z],   fmaf(ki, v[z],   0.99f * S[z]));
        const float sb = fmaf(bu, k[z+1], fmaf(ki, v[z+1], 0.99f * S[z+1]));
        S[z]   = sa;
        S[z+1] = sb;
        ov0 = fmaf(sa, q[z],    ov0);
        ov1 = fmaf(sb, q[z+1],  ov1);
        un0 = fmaf(sa, kn[z],   un0);
        un1 = fmaf(sb, kn[z+1], un1);
    }
    float ov = ov0 + ov1;
    float un = un0 + un1;
    ov += __shfl_xor(ov, 1, 64);
    un += __shfl_xor(un, 1, 64);
    ov += __shfl_xor(ov, 2, 64);
    un += __shfl_xor(un, 2, 64);
    uc = un;
    if (doStore) *sp = ov;
}

__global__ __launch_bounds__(64, 1)
void scan_kernel(const float* __restrict__ qkv, float* __restrict__ o) {
    __shared__ float ring[SLOTS * SLOT_F];

    const int bh = blockIdx.x >> 2;   // 0..47
    const int rb = blockIdx.x & 3;    // 0..3
    const int b  = bh / NH;
    const int h  = bh - b * NH;
    const int tid = threadIdx.x;
    const int r   = tid >> 2;         // 0..15
    const int cg  = tid & 3;          // 0..3
    const int i   = rb * 16 + r;      // state row 0..63
    const int j0  = cg * 16;

    const float* base = qkv + (size_t)b * T_ * QKVW + h * HS;
    float* sp = o + (size_t)b * T_ * CDIM + h * HS + i;
    const bool doStore = (cg == 0);

    float S[16];
#pragma unroll
    for (int z = 0; z < 16; ++z) S[z] = 0.f;

    // ---- prologue: stage steps 0..11 into the ring
#pragma unroll
    for (int s = 0; s < SLOTS; ++s)
        refill_slot(base + (size_t)s * QKVW, ring + s * SLOT_F, tid);

    float qA[16], kA[16], vA[16], kiA;
    float qB[16], kB[16], vB[16], kiB;

    __builtin_amdgcn_s_waitcnt(WAIT_VM(33));   // slot 0's 3 loads done
    __builtin_amdgcn_sched_barrier(0);
    read_slot(ring + 0, j0, i, qA, kA, vA, kiA);
    __builtin_amdgcn_s_waitcnt(WAIT_LGKM0);    // slot 0 fully read
    refill_slot(base + (size_t)SLOTS * QKVW, ring + 0, tid);   // step 12 -> slot 0

    float uc = 0.f;     // u for step 0 (S=0)
    int slot_rd = 1;    // slot holding step t+1
    int step_rf = SLOTS + 1;   // next step index to stage (t+13), wraps mod T_

    for (int t = 0; t < T_; t += 2) {
        // ---- iter A: compute step t from A; ds_read step t+1 -> B
        __builtin_amdgcn_s_waitcnt(WAIT_VM(32));
        __builtin_amdgcn_sched_barrier(0);
        read_slot(ring + slot_rd * SLOT_F, j0, i, qB, kB, vB, kiB);
        scan_step(S, uc, qA, kA, vA, kiA, kB, sp + (size_t)t * CDIM, doStore);
        __builtin_amdgcn_s_waitcnt(WAIT_LGKM0);    // B's ds_reads drained
        refill_slot(base + (size_t)step_rf * QKVW, ring + slot_rd * SLOT_F, tid);
        slot_rd = (slot_rd == SLOTS - 1) ? 0 : slot_rd + 1;
        step_rf = (step_rf == T_ - 1) ? 0 : step_rf + 1;

        // ---- iter B: compute step t+1 from B; ds_read step t+2 -> A
        __builtin_amdgcn_s_waitcnt(WAIT_VM(32));
        __builtin_amdgcn_sched_barrier(0);
        read_slot(ring + slot_rd * SLOT_F, j0, i, qA, kA, vA, kiA);
        scan_step(S, uc, qB, kB, vB, kiB, kA, sp + (size_t)(t + 1) * CDIM, doStore);
        __builtin_amdgcn_s_waitcnt(WAIT_LGKM0);
        refill_slot(base + (size_t)step_rf * QKVW, ring + slot_rd * SLOT_F, tid);
        slot_rd = (slot_rd == SLOTS - 1) ? 0 : slot_rd + 1;
        step_rf = (step_rf == T_ - 1) ? 0 : step_rf + 1;
    }
}

// ------------------------------ launch ----------------------------------
extern "C" void kernel_launch(void* const* d_in, const int* in_sizes, int n_in,
                              void* d_out, int out_size, void* d_ws, size_t ws_size,
                              hipStream_t stream) {
    const float* x      = (const float*)d_in[0];   // (4,1024,768)
    const float* w_attn = (const float*)d_in[1];   // (768, 2304)
    const float* w_proj = (const float*)d_in[2];   // (768, 768)
    float* out = (float*)d_out;
    float* qkv = (float*)d_ws;                     // 4096 x 2304 fp32
    float* y   = (float*)d_ws;                     // reuse after scan

    const int M = B_ * T_;   // 4096

    gemm64<false><<<dim3(QKVW / TILE, M / TILE), 256, 0, stream>>>(
        x, w_attn, nullptr, qkv, M, QKVW, CDIM);

    norm_kernel<<<(M * 3 * NH) / 4, 256, 0, stream>>>(qkv);

    scan_kernel<<<48 * 4, 64, 0, stream>>>(qkv, out);

    gemm64<true><<<dim3(CDIM / TILE, M / TILE), 256, 0, stream>>>(
        out, w_proj, x, y, M, CDIM, CDIM);

    hipMemcpyAsync(d_out, y, (size_t)M * CDIM * sizeof(float),
                   hipMemcpyDeviceToDevice, stream);
}

// Round 4
// 801.116 us; speedup vs baseline: 1.1028x; 1.1028x over previous
//
#include <hip/hip_runtime.h>

#define TILE 64
#define BK 16

#define B_ 4
#define T_ 1024
#define NH 12
#define HS 64
#define CDIM 768
#define QKVW 2304   // 3*CDIM
#define NC 16       // chunks per sequence
#define CS 64       // chunk length
#define LAM 0.99f
#define BP  (0.01f/0.99f)

// ws layout (float offsets)
#define OFF_W  9437184            // after qkv (4096*2304)
#define OFF_U  (OFF_W  + 768*4096)
#define OFF_C  (OFF_U  + 768*4096)
#define OFF_R0 (OFF_C  + 768*4096)

// ---------------- GEMM: C[M,N] = A[M,K] @ B[K,N] (+ R) -----------------
template<bool ADD_RES>
__global__ __launch_bounds__(256)
void gemm64(const float* __restrict__ A, const float* __restrict__ Bm,
            const float* __restrict__ R, float* __restrict__ C,
            int M, int N, int K) {
    __shared__ float As[BK][TILE + 4];
    __shared__ float Bs[BK][TILE];

    const int tid = threadIdx.x;
    const int tm  = tid >> 4;
    const int tn  = tid & 15;
    const int m0  = blockIdx.y * TILE;
    const int n0  = blockIdx.x * TILE;

    const int am = tid >> 2;
    const int ak = (tid & 3) * 4;
    const int bk = tid >> 4;
    const int bn = (tid & 15) * 4;

    const float* Aptr = A + (size_t)(m0 + am) * K + ak;
    const float* Bptr = Bm + (size_t)bk * N + n0 + bn;

    float acc[4][4];
#pragma unroll
    for (int ii = 0; ii < 4; ++ii)
#pragma unroll
        for (int jj = 0; jj < 4; ++jj) acc[ii][jj] = 0.f;

    for (int k0 = 0; k0 < K; k0 += BK) {
        const float4 av = *(const float4*)(Aptr + k0);
        const float4 bv = *(const float4*)(Bptr + (size_t)k0 * N);
        __syncthreads();
        As[ak + 0][am] = av.x;
        As[ak + 1][am] = av.y;
        As[ak + 2][am] = av.z;
        As[ak + 3][am] = av.w;
        *(float4*)&Bs[bk][bn] = bv;
        __syncthreads();
#pragma unroll
        for (int kk = 0; kk < BK; ++kk) {
            const float4 a = *(const float4*)&As[kk][tm * 4];
            const float4 b = *(const float4*)&Bs[kk][tn * 4];
            const float ar[4] = {a.x, a.y, a.z, a.w};
            const float br[4] = {b.x, b.y, b.z, b.w};
#pragma unroll
            for (int ii = 0; ii < 4; ++ii)
#pragma unroll
                for (int jj = 0; jj < 4; ++jj)
                    acc[ii][jj] = fmaf(ar[ii], br[jj], acc[ii][jj]);
        }
    }

#pragma unroll
    for (int ii = 0; ii < 4; ++ii) {
        const int m = m0 + tm * 4 + ii;
        float4 out;
        out.x = acc[ii][0]; out.y = acc[ii][1]; out.z = acc[ii][2]; out.w = acc[ii][3];
        if (ADD_RES) {
            const float4 r = *(const float4*)(R + (size_t)m * N + n0 + tn * 4);
            out.x += r.x; out.y += r.y; out.z += r.z; out.w += r.w;
        }
        *(float4*)(C + (size_t)m * N + n0 + tn * 4) = out;
    }
}

// -------- per-64-element standardization (mean / unbiased std) ----------
__global__ __launch_bounds__(256)
void norm_kernel(float* __restrict__ qkv) {
    const int g    = blockIdx.x * 4 + (threadIdx.x >> 6);
    const int lane = threadIdx.x & 63;
    const size_t idx = (size_t)g * 64 + lane;
    const float v = qkv[idx];
    float s = v, ss = v * v;
#pragma unroll
    for (int off = 1; off < 64; off <<= 1) {
        s  += __shfl_xor(s,  off, 64);
        ss += __shfl_xor(ss, off, 64);
    }
    const float mu  = s * (1.0f / 64.0f);
    const float var = (ss - 64.0f * mu * mu) * (1.0f / 63.0f);
    const float rs  = rsqrtf(var);
    qkv[idx] = (v - mu) * rs;
}

// ---------------- 64x64x64 register-tile matmul microkernel -------------
// out[y][x] += scale * sum_r a(y,r)*b(r,x); thread (ty,tx) owns 4x4 tile.
// AOM: A stored out-major A[y*ast+r]; else A[r*ast+y]. Same for BOM.
// r is skewed per ty-group to avoid LDS bank conflicts on out-major reads.
template<bool AOM, bool BOM>
__device__ __forceinline__ void mm64(const float* __restrict__ A, int ast,
                                     const float* __restrict__ B, int bst,
                                     int ty, int tx, float (&acc)[4][4],
                                     float scale) {
    const int skew = 16 * (ty & 3);
#pragma unroll 4
    for (int r = 0; r < 64; ++r) {
        const int rr = (r + skew) & 63;
        float a_[4], b_[4];
#pragma unroll
        for (int i = 0; i < 4; ++i)
            a_[i] = AOM ? A[(4*ty + i)*ast + rr] : A[rr*ast + 4*ty + i];
#pragma unroll
        for (int j = 0; j < 4; ++j)
            b_[j] = BOM ? B[(4*tx + j)*bst + rr] : B[rr*bst + 4*tx + j];
#pragma unroll
        for (int i = 0; i < 4; ++i) {
            const float as = scale * a_[i];
#pragma unroll
            for (int j = 0; j < 4; ++j)
                acc[i][j] = fmaf(as, b_[j], acc[i][j]);
        }
    }
}

// ---------------- Kernel A: per-(bh,chunk) W, U, C ----------------------
// W = T K ; U = T SL(H) K ; C = Vt^T K - b' K^T U
// T = (I + b' SL(G))^{-1}, G = K K^T, H[t][s] = k_t . vt_s (s<t)
__global__ __launch_bounds__(256)
void chunkA(const float* __restrict__ qkv, float* __restrict__ ws) {
    __shared__ float pool[16384];   // 64 KB exact
    float* Ksh  = pool;             // stride 65 (padded), 4160 floats
    float* Vsh  = pool + 4160;      // stride 64, 4096
    float* HT   = pool + 8256;      // stride 64, 4096  (HT[s][t])
    float* Gp   = pool + 12352;     // rows s-1 (s=1..63), stride 64, 4032
    float* Rsol = pool + 4160;      // stride 128, 8192 (aliases Vsh+HT)

    const int cc = blockIdx.x;           // 0..767
    const int bh = cc >> 4, c = cc & 15;
    const int b = bh / NH, h = bh - b * NH;
    const int tid = threadIdx.x;
    const int ty = tid >> 4, tx = tid & 15;
    const float* base = qkv + ((size_t)(b * T_ + c * CS)) * QKVW + h * HS;

    for (int e = tid; e < 4096; e += 256) {
        const int t = e >> 6, d = e & 63;
        Ksh[t*65 + d] = base[(size_t)t*QKVW + CDIM + d];
        Vsh[t*64 + d] = base[(size_t)t*QKVW + 2*CDIM + d] * __powf(LAM, -(float)(t+1));
    }
    __syncthreads();

    float accC[4][4] = {{0}};                       // Vt^T K
    mm64<false,false>(Vsh, 64, Ksh, 65, ty, tx, accC, 1.0f);
    float accG[4][4] = {{0}};                       // G = K K^T
    mm64<true,true>(Ksh, 65, Ksh, 65, ty, tx, accG, 1.0f);
    float accH[4][4] = {{0}};                       // HT[s][t] = vt_s . k_t
    mm64<true,true>(Vsh, 64, Ksh, 65, ty, tx, accH, 1.0f);

#pragma unroll
    for (int i = 0; i < 4; ++i)
#pragma unroll
        for (int j = 0; j < 4; ++j) {
            const int s = 4*ty + i, t = 4*tx + j;
            if (s >= 1) Gp[(s-1)*64 + t] = accG[i][j];
            HT[s*64 + t] = (s < t) ? accH[i][j] : 0.f;
        }
    __syncthreads();

    float accS[4][4] = {{0}};                       // SL(H) K
    mm64<false,false>(HT, 64, Ksh, 65, ty, tx, accS, 1.0f);
    __syncthreads();                                // done reading HT/Vsh region

    for (int e = tid; e < 4096; e += 256) {
        const int t = e >> 6, d = e & 63;
        Rsol[t*128 + d] = Ksh[t*65 + d];
    }
#pragma unroll
    for (int i = 0; i < 4; ++i)
#pragma unroll
        for (int j = 0; j < 4; ++j)
            Rsol[(4*ty + i)*128 + 64 + 4*tx + j] = accS[i][j];
    __syncthreads();

    // forward substitution: row_s -= b'*G[s][t]*row_t, unit diagonal
    const int col = tid & 127, half = tid >> 7;
    for (int t = 0; t < 64; ++t) {
        const float piv = Rsol[t*128 + col] * (-BP);
        for (int s = t + 1 + half; s < 64; s += 2)
            Rsol[s*128 + col] = fmaf(Gp[(s-1)*64 + t], piv, Rsol[s*128 + col]);
        __syncthreads();
    }

    // C += -b' K^T U
    mm64<false,false>(Ksh, 65, Rsol + 64, 128, ty, tx, accC, -BP);

    float* Wg = ws + OFF_W + (size_t)cc * 4096;
    float* Ug = ws + OFF_U + (size_t)cc * 4096;
    float* Cg = ws + OFF_C + (size_t)cc * 4096;
    for (int e = tid; e < 4096; e += 256) {
        const int t = e >> 6, d = e & 63;
        Wg[e] = Rsol[t*128 + d];
        Ug[e] = Rsol[t*128 + 64 + d];
    }
#pragma unroll
    for (int i = 0; i < 4; ++i)
#pragma unroll
        for (int j = 0; j < 4; ++j)
            Cg[(4*ty + i)*64 + 4*tx + j] = accC[i][j];
}

// ---------------- Kernel B: sequential 16-chunk sweep per bh ------------
// R' = lam^64 * (R - b' K^T (W R) + C); stores incoming R as R0[cc].
__global__ __launch_bounds__(256)
void chunkB(const float* __restrict__ qkv, float* __restrict__ ws) {
    __shared__ float Rh[64*65], Wb[64*65], Pb[64*65];
    const int bh = blockIdx.x;
    const int b = bh / NH, h = bh - b * NH;
    const int tid = threadIdx.x;
    const int ty = tid >> 4, tx = tid & 15;
    const float lam64 = __powf(LAM, 64.0f);

    for (int e = tid; e < 4096; e += 256) Rh[(e >> 6)*65 + (e & 63)] = 0.f;
    __syncthreads();

    for (int c = 0; c < NC; ++c) {
        const int cc = bh * 16 + c;
        float* R0g = ws + OFF_R0 + (size_t)cc * 4096;
        const float* Wg = ws + OFF_W + (size_t)cc * 4096;
        const float* Cg = ws + OFF_C + (size_t)cc * 4096;
        for (int e = tid; e < 4096; e += 256) {
            const int t = e >> 6, d = e & 63;
            R0g[e] = Rh[t*65 + d];
            Wb[t*65 + d] = Wg[e];
        }
        __syncthreads();

        float pa[4][4] = {{0}};                      // P = W R
        mm64<true,false>(Wb, 65, Rh, 65, ty, tx, pa, 1.0f);
#pragma unroll
        for (int i = 0; i < 4; ++i)
#pragma unroll
            for (int j = 0; j < 4; ++j)
                Pb[(4*ty + i)*65 + 4*tx + j] = pa[i][j];
        __syncthreads();                             // Wb free, Pb complete pending next sync

        const float* kb = qkv + ((size_t)(b * T_ + c * CS)) * QKVW + h * HS + CDIM;
        for (int e = tid; e < 4096; e += 256) {
            const int t = e >> 6, d = e & 63;
            Wb[t*65 + d] = kb[(size_t)t*QKVW + d];
        }
        __syncthreads();

        float ka[4][4] = {{0}};                      // K^T P
        mm64<false,false>(Wb, 65, Pb, 65, ty, tx, ka, 1.0f);
#pragma unroll
        for (int i = 0; i < 4; ++i)
#pragma unroll
            for (int j = 0; j < 4; ++j) {
                const int y = 4*ty + i, x = 4*tx + j;
                Rh[y*65 + x] = lam64 * (fmaf(-BP, ka[i][j], Rh[y*65 + x]) + Cg[y*64 + x]);
            }
        __syncthreads();
    }
}

// ---------------- Kernel C: outputs per (bh,chunk) ----------------------
// O = Qh R0 + TRIL(Qh Vt^T) K - b' TRIL(Qh K^T) (W R0 + U)
__global__ __launch_bounds__(256)
void chunkC(const float* __restrict__ qkv, const float* __restrict__ ws,
            float* __restrict__ o) {
    __shared__ float S1[4096], S2[4096], S3[4096], S4[4096];
    const int cc = blockIdx.x;
    const int bh = cc >> 4, c = cc & 15;
    const int b = bh / NH, h = bh - b * NH;
    const int tid = threadIdx.x;
    const int ty = tid >> 4, tx = tid & 15;
    const float* base = qkv + ((size_t)(b * T_ + c * CS)) * QKVW + h * HS;
    const float* R0g = ws + OFF_R0 + (size_t)cc * 4096;
    const float* Wg  = ws + OFF_W  + (size_t)cc * 4096;
    const float* Ug  = ws + OFF_U  + (size_t)cc * 4096;

    for (int e = tid; e < 4096; e += 256) {
        const int t = e >> 6, d = e & 63;
        S1[t*64 + d] = base[(size_t)t*QKVW + d] * __powf(LAM, (float)(t+1));      // Qhat
        S3[t*64 + d] = base[(size_t)t*QKVW + CDIM + d];                            // K
        S4[t*64 + d] = base[(size_t)t*QKVW + 2*CDIM + d] * __powf(LAM, -(float)(t+1)); // Vt
        S2[e] = R0g[e];                                                            // R0
    }
    __syncthreads();

    float Oacc[4][4] = {{0}};
    mm64<true,false>(S1, 64, S2, 64, ty, tx, Oacc, 1.0f);   // Qh R0
    float a1[4][4] = {{0}};
    mm64<true,true>(S3, 64, S1, 64, ty, tx, a1, 1.0f);      // A1T[s][t] = k_s.qh_t
    float a2[4][4] = {{0}};
    mm64<true,true>(S4, 64, S1, 64, ty, tx, a2, 1.0f);      // A2T[s][t] = vt_s.qh_t
    __syncthreads();                                        // Qh dead

    for (int e = tid; e < 4096; e += 256) S1[e] = Wg[e];    // W -> S1
    __syncthreads();

    float rm[4][4] = {{0}};
    mm64<true,false>(S1, 64, S2, 64, ty, tx, rm, 1.0f);     // W R0
    __syncthreads();                                        // R0/W dead

#pragma unroll
    for (int i = 0; i < 4; ++i)
#pragma unroll
        for (int j = 0; j < 4; ++j) {
            const int y = 4*ty + i, x = 4*tx + j;
            S2[y*64 + x] = rm[i][j] + Ug[y*64 + x];                 // Rm
            S1[y*64 + x] = (y <= x) ? (-BP) * a1[i][j] : 0.f;       // -b' TRIL A1T
            S4[y*64 + x] = (y <= x) ? a2[i][j] : 0.f;               // TRIL A2T
        }
    __syncthreads();

    mm64<false,false>(S4, 64, S3, 64, ty, tx, Oacc, 1.0f);  // TRIL(A2) K
    mm64<false,false>(S1, 64, S2, 64, ty, tx, Oacc, 1.0f);  // -b' TRIL(A1) Rm

#pragma unroll
    for (int i = 0; i < 4; ++i)
#pragma unroll
        for (int j = 0; j < 4; ++j)
            o[((size_t)(b * T_ + c * CS + 4*ty + i)) * CDIM + h * HS + 4*tx + j] = Oacc[i][j];
}

// ------------------------------ launch ----------------------------------
extern "C" void kernel_launch(void* const* d_in, const int* in_sizes, int n_in,
                              void* d_out, int out_size, void* d_ws, size_t ws_size,
                              hipStream_t stream) {
    const float* x      = (const float*)d_in[0];   // (4,1024,768)
    const float* w_attn = (const float*)d_in[1];   // (768, 2304)
    const float* w_proj = (const float*)d_in[2];   // (768, 768)
    float* out = (float*)d_out;
    float* ws  = (float*)d_ws;
    float* qkv = ws;                                // 4096 x 2304
    float* y   = ws;                                // reuse qkv region after scan

    const int M = B_ * T_;   // 4096

    gemm64<false><<<dim3(QKVW / TILE, M / TILE), 256, 0, stream>>>(
        x, w_attn, nullptr, qkv, M, QKVW, CDIM);

    norm_kernel<<<(M * 3 * NH) / 4, 256, 0, stream>>>(qkv);

    chunkA<<<768, 256, 0, stream>>>(qkv, ws);
    chunkB<<<48,  256, 0, stream>>>(qkv, ws);
    chunkC<<<768, 256, 0, stream>>>(qkv, ws, out);

    gemm64<true><<<dim3(CDIM / TILE, M / TILE), 256, 0, stream>>>(
        out, w_proj, x, y, M, CDIM, CDIM);

    hipMemcpyAsync(d_out, y, (size_t)M * CDIM * sizeof(float),
                   hipMemcpyDeviceToDevice, stream);
}

// Round 5
// 598.655 us; speedup vs baseline: 1.4757x; 1.3382x over previous
//
#include <hip/hip_runtime.h>

typedef unsigned short u16;
typedef __attribute__((ext_vector_type(4))) unsigned short u16x4;
typedef __attribute__((ext_vector_type(8))) short bf16x8;
typedef __attribute__((ext_vector_type(4))) float f32x4;

#define B_ 4
#define T_ 1024
#define NH 12
#define HS 64
#define CDIM 768
#define QKVW 2304   // 3*CDIM
#define NC 16
#define CS 64
#define LAM 0.99f
#define BP  (0.01f/0.99f)
#define MROWS 4096

// ws layout (float offsets)
#define OFF_W  9437184            // after qkv (4096*2304)
#define OFF_U  (OFF_W  + 768*4096)
#define OFF_C  (OFF_U  + 768*4096)
#define OFF_R0 (OFF_C  + 768*4096)
#define OFF_XB (OFF_W)                       // bf16 x, aliases W (dead until chunkA)
#define OFF_WAT (OFF_W + 1572864)            // bf16 w_attn^T, aliases W
// ob (bf16 o) aliases OFF_C; w_proj^T bf16 goes at ws[0] (qkv dead after chunkC)

__device__ __forceinline__ u16 f2bf(float f) {
    union { float f; unsigned u; } a; a.f = f;
    const unsigned r = a.u + 0x7FFF + ((a.u >> 16) & 1);
    return (u16)(r >> 16);
}

// ---------------- cast kernels ------------------------------------------
__global__ __launch_bounds__(256)
void cast_x_kernel(const float* __restrict__ src, u16* __restrict__ dst) {
    const size_t i = ((size_t)blockIdx.x * 256 + threadIdx.x) * 4;
    const float4 v = *(const float4*)(src + i);
    u16x4 u;
    u.x = f2bf(v.x); u.y = f2bf(v.y); u.z = f2bf(v.z); u.w = f2bf(v.w);
    *(u16x4*)(dst + i) = u;
}

// src [Rr][Cn] fp32  ->  dst [Cn][Rr] bf16. grid (Cn/64, Rr/64), 256 thr.
__global__ __launch_bounds__(256)
void tcast_kernel(const float* __restrict__ src, u16* __restrict__ dst,
                  int Cn, int Rr) {
    const int ln = threadIdx.x & 63, kg = threadIdx.x >> 6;
    const int n = blockIdx.x * 64 + ln;
    const int kb = blockIdx.y * 64 + kg * 16;
    u16 tmp[16];
#pragma unroll
    for (int j = 0; j < 16; ++j)
        tmp[j] = f2bf(src[(size_t)(kb + j) * Cn + n]);
#pragma unroll
    for (int j4 = 0; j4 < 4; ++j4) {
        u16x4 u; u.x = tmp[j4*4]; u.y = tmp[j4*4+1]; u.z = tmp[j4*4+2]; u.w = tmp[j4*4+3];
        *(u16x4*)&dst[(size_t)n * Rr + kb + j4*4] = u;
    }
}

// ---------------- MFMA GEMM: C[M,N] = A[M,K] @ Bt[N,K]^T (+R) -----------
// A, Bt bf16 row-major (k contiguous). 128x128 tile, BK=64, 4 waves 2x2.
// LDS XOR swizzle: element [row][k] stored at k' = k ^ ((row&7)*8).
__device__ __forceinline__ void gll16(const u16* g, u16* lds) {
    __builtin_amdgcn_global_load_lds(
        (const __attribute__((address_space(1))) unsigned*)g,
        (__attribute__((address_space(3))) unsigned*)lds, 16, 0, 0);
}

template<bool ADD_RES>
__global__ __launch_bounds__(256)
void gemm_mfma(const u16* __restrict__ A, const u16* __restrict__ Bt,
               const float* __restrict__ R, float* __restrict__ C,
               int N, int K) {
    __shared__ u16 As[128 * 64];
    __shared__ u16 Bs[128 * 64];
    const int tid  = threadIdx.x;
    const int wave = tid >> 6, lane = tid & 63;
    const int wm = wave >> 1, wn = wave & 1;
    const int ln = lane & 15, quad = lane >> 4;
    const int m0 = blockIdx.y * 128, n0 = blockIdx.x * 128;

    // staging: per instr, lane L -> lds base + L*16B; 8 rows x 64 k per instr
    const int rl = lane >> 3;                  // row within 8-row slab
    const int kx = ((lane & 7) ^ rl) * 8;      // swizzled source k
    const u16* Ag = A + (size_t)(m0 + wave * 32 + rl) * K + kx;
    const u16* Bg = Bt + (size_t)(n0 + wave * 32 + rl) * K + kx;
    u16* AsW = &As[(wave * 32) * 64];
    u16* BsW = &Bs[(wave * 32) * 64];

    f32x4 acc[4][4] = {};

    for (int k0 = 0; k0 < K; k0 += 64) {
        __syncthreads();
#pragma unroll
        for (int c8 = 0; c8 < 4; ++c8) {
            gll16(Ag + (size_t)(c8 * 8) * K + k0, AsW + c8 * 8 * 64);
            gll16(Bg + (size_t)(c8 * 8) * K + k0, BsW + c8 * 8 * 64);
        }
        __syncthreads();
#pragma unroll
        for (int k32 = 0; k32 < 64; k32 += 32) {
            const int ko = (k32 + quad * 8) ^ ((ln & 7) * 8);
            bf16x8 af[4], bfr[4];
#pragma unroll
            for (int mi = 0; mi < 4; ++mi)
                af[mi] = *(const bf16x8*)&As[(wm * 64 + mi * 16 + ln) * 64 + ko];
#pragma unroll
            for (int ni = 0; ni < 4; ++ni)
                bfr[ni] = *(const bf16x8*)&Bs[(wn * 64 + ni * 16 + ln) * 64 + ko];
#pragma unroll
            for (int mi = 0; mi < 4; ++mi)
#pragma unroll
                for (int ni = 0; ni < 4; ++ni)
                    acc[mi][ni] = __builtin_amdgcn_mfma_f32_16x16x32_bf16(
                        af[mi], bfr[ni], acc[mi][ni], 0, 0, 0);
        }
    }

#pragma unroll
    for (int mi = 0; mi < 4; ++mi) {
        const int rb = m0 + wm * 64 + mi * 16 + quad * 4;
#pragma unroll
        for (int ni = 0; ni < 4; ++ni) {
            const int col = n0 + wn * 64 + ni * 16 + ln;
#pragma unroll
            for (int r = 0; r < 4; ++r) {
                float v = acc[mi][ni][r];
                if (ADD_RES) v += R[(size_t)(rb + r) * N + col];
                C[(size_t)(rb + r) * N + col] = v;
            }
        }
    }
}

// -------- per-64-element standardization (mean / unbiased std) ----------
__global__ __launch_bounds__(256)
void norm_kernel(float* __restrict__ qkv) {
    const int g    = blockIdx.x * 4 + (threadIdx.x >> 6);
    const int lane = threadIdx.x & 63;
    const size_t idx = (size_t)g * 64 + lane;
    const float v = qkv[idx];
    float s = v, ss = v * v;
#pragma unroll
    for (int off = 1; off < 64; off <<= 1) {
        s  += __shfl_xor(s,  off, 64);
        ss += __shfl_xor(ss, off, 64);
    }
    const float mu  = s * (1.0f / 64.0f);
    const float var = (ss - 64.0f * mu * mu) * (1.0f / 63.0f);
    const float rs  = rsqrtf(var);
    qkv[idx] = (v - mu) * rs;
}

// ---------------- 64x64x64 register-tile matmul microkernel -------------
template<bool AOM, bool BOM>
__device__ __forceinline__ void mm64(const float* __restrict__ A, int ast,
                                     const float* __restrict__ B, int bst,
                                     int ty, int tx, float (&acc)[4][4],
                                     float scale) {
    const int skew = 16 * (ty & 3);
#pragma unroll 4
    for (int r = 0; r < 64; ++r) {
        const int rr = (r + skew) & 63;
        float a_[4], b_[4];
#pragma unroll
        for (int i = 0; i < 4; ++i)
            a_[i] = AOM ? A[(4*ty + i)*ast + rr] : A[rr*ast + 4*ty + i];
#pragma unroll
        for (int j = 0; j < 4; ++j)
            b_[j] = BOM ? B[(4*tx + j)*bst + rr] : B[rr*bst + 4*tx + j];
#pragma unroll
        for (int i = 0; i < 4; ++i) {
            const float as = scale * a_[i];
#pragma unroll
            for (int j = 0; j < 4; ++j)
                acc[i][j] = fmaf(as, b_[j], acc[i][j]);
        }
    }
}

// ---------------- Kernel A: per-(bh,chunk) W, U, C ----------------------
__global__ __launch_bounds__(256)
void chunkA(const float* __restrict__ qkv, float* __restrict__ ws) {
    __shared__ float pool[16384];
    float* Ksh  = pool;             // stride 65, 4160
    float* Vsh  = pool + 4160;      // stride 64, 4096
    float* HT   = pool + 8256;      // stride 64, 4096
    float* Gp   = pool + 12352;     // stride 64, 4032
    float* Rsol = pool + 4160;      // stride 128, 8192 (aliases Vsh+HT)

    const int cc = blockIdx.x;
    const int bh = cc >> 4, c = cc & 15;
    const int b = bh / NH, h = bh - b * NH;
    const int tid = threadIdx.x;
    const int ty = tid >> 4, tx = tid & 15;
    const float* base = qkv + ((size_t)(b * T_ + c * CS)) * QKVW + h * HS;

    for (int e = tid; e < 4096; e += 256) {
        const int t = e >> 6, d = e & 63;
        Ksh[t*65 + d] = base[(size_t)t*QKVW + CDIM + d];
        Vsh[t*64 + d] = base[(size_t)t*QKVW + 2*CDIM + d] * __powf(LAM, -(float)(t+1));
    }
    __syncthreads();

    float accC[4][4] = {{0}};
    mm64<false,false>(Vsh, 64, Ksh, 65, ty, tx, accC, 1.0f);
    float accG[4][4] = {{0}};
    mm64<true,true>(Ksh, 65, Ksh, 65, ty, tx, accG, 1.0f);
    float accH[4][4] = {{0}};
    mm64<true,true>(Vsh, 64, Ksh, 65, ty, tx, accH, 1.0f);

#pragma unroll
    for (int i = 0; i < 4; ++i)
#pragma unroll
        for (int j = 0; j < 4; ++j) {
            const int s = 4*ty + i, t = 4*tx + j;
            if (s >= 1) Gp[(s-1)*64 + t] = accG[i][j];
            HT[s*64 + t] = (s < t) ? accH[i][j] : 0.f;
        }
    __syncthreads();

    float accS[4][4] = {{0}};
    mm64<false,false>(HT, 64, Ksh, 65, ty, tx, accS, 1.0f);
    __syncthreads();

    for (int e = tid; e < 4096; e += 256) {
        const int t = e >> 6, d = e & 63;
        Rsol[t*128 + d] = Ksh[t*65 + d];
    }
#pragma unroll
    for (int i = 0; i < 4; ++i)
#pragma unroll
        for (int j = 0; j < 4; ++j)
            Rsol[(4*ty + i)*128 + 64 + 4*tx + j] = accS[i][j];
    __syncthreads();

    const int col = tid & 127, half = tid >> 7;
    for (int t = 0; t < 64; ++t) {
        const float piv = Rsol[t*128 + col] * (-BP);
        for (int s = t + 1 + half; s < 64; s += 2)
            Rsol[s*128 + col] = fmaf(Gp[(s-1)*64 + t], piv, Rsol[s*128 + col]);
        __syncthreads();
    }

    mm64<false,false>(Ksh, 65, Rsol + 64, 128, ty, tx, accC, -BP);

    float* Wg = ws + OFF_W + (size_t)cc * 4096;
    float* Ug = ws + OFF_U + (size_t)cc * 4096;
    float* Cg = ws + OFF_C + (size_t)cc * 4096;
    for (int e = tid; e < 4096; e += 256) {
        const int t = e >> 6, d = e & 63;
        Wg[e] = Rsol[t*128 + d];
        Ug[e] = Rsol[t*128 + 64 + d];
    }
#pragma unroll
    for (int i = 0; i < 4; ++i)
#pragma unroll
        for (int j = 0; j < 4; ++j)
            Cg[(4*ty + i)*64 + 4*tx + j] = accC[i][j];
}

// ---------------- Kernel B: sequential 16-chunk sweep per bh ------------
__global__ __launch_bounds__(256)
void chunkB(const float* __restrict__ qkv, float* __restrict__ ws) {
    __shared__ float Rh[64*65], Wb[64*65], Pb[64*65];
    const int bh = blockIdx.x;
    const int b = bh / NH, h = bh - b * NH;
    const int tid = threadIdx.x;
    const int ty = tid >> 4, tx = tid & 15;
    const float lam64 = __powf(LAM, 64.0f);

    for (int e = tid; e < 4096; e += 256) Rh[(e >> 6)*65 + (e & 63)] = 0.f;
    __syncthreads();

    for (int c = 0; c < NC; ++c) {
        const int cc = bh * 16 + c;
        float* R0g = ws + OFF_R0 + (size_t)cc * 4096;
        const float* Wg = ws + OFF_W + (size_t)cc * 4096;
        const float* Cg = ws + OFF_C + (size_t)cc * 4096;
        for (int e = tid; e < 4096; e += 256) {
            const int t = e >> 6, d = e & 63;
            R0g[e] = Rh[t*65 + d];
            Wb[t*65 + d] = Wg[e];
        }
        __syncthreads();

        float pa[4][4] = {{0}};
        mm64<true,false>(Wb, 65, Rh, 65, ty, tx, pa, 1.0f);
#pragma unroll
        for (int i = 0; i < 4; ++i)
#pragma unroll
            for (int j = 0; j < 4; ++j)
                Pb[(4*ty + i)*65 + 4*tx + j] = pa[i][j];
        __syncthreads();

        const float* kb = qkv + ((size_t)(b * T_ + c * CS)) * QKVW + h * HS + CDIM;
        for (int e = tid; e < 4096; e += 256) {
            const int t = e >> 6, d = e & 63;
            Wb[t*65 + d] = kb[(size_t)t*QKVW + d];
        }
        __syncthreads();

        float ka[4][4] = {{0}};
        mm64<false,false>(Wb, 65, Pb, 65, ty, tx, ka, 1.0f);
#pragma unroll
        for (int i = 0; i < 4; ++i)
#pragma unroll
            for (int j = 0; j < 4; ++j) {
                const int y = 4*ty + i, x = 4*tx + j;
                Rh[y*65 + x] = lam64 * (fmaf(-BP, ka[i][j], Rh[y*65 + x]) + Cg[y*64 + x]);
            }
        __syncthreads();
    }
}

// ---------------- Kernel C: outputs per (bh,chunk), bf16 out ------------
__global__ __launch_bounds__(256)
void chunkC(const float* __restrict__ qkv, const float* __restrict__ ws,
            u16* __restrict__ ob) {
    __shared__ float S1[4096], S2[4096], S3[4096], S4[4096];
    const int cc = blockIdx.x;
    const int bh = cc >> 4, c = cc & 15;
    const int b = bh / NH, h = bh - b * NH;
    const int tid = threadIdx.x;
    const int ty = tid >> 4, tx = tid & 15;
    const float* base = qkv + ((size_t)(b * T_ + c * CS)) * QKVW + h * HS;
    const float* R0g = ws + OFF_R0 + (size_t)cc * 4096;
    const float* Wg  = ws + OFF_W  + (size_t)cc * 4096;
    const float* Ug  = ws + OFF_U  + (size_t)cc * 4096;

    for (int e = tid; e < 4096; e += 256) {
        const int t = e >> 6, d = e & 63;
        S1[t*64 + d] = base[(size_t)t*QKVW + d] * __powf(LAM, (float)(t+1));
        S3[t*64 + d] = base[(size_t)t*QKVW + CDIM + d];
        S4[t*64 + d] = base[(size_t)t*QKVW + 2*CDIM + d] * __powf(LAM, -(float)(t+1));
        S2[e] = R0g[e];
    }
    __syncthreads();

    float Oacc[4][4] = {{0}};
    mm64<true,false>(S1, 64, S2, 64, ty, tx, Oacc, 1.0f);
    float a1[4][4] = {{0}};
    mm64<true,true>(S3, 64, S1, 64, ty, tx, a1, 1.0f);
    float a2[4][4] = {{0}};
    mm64<true,true>(S4, 64, S1, 64, ty, tx, a2, 1.0f);
    __syncthreads();

    for (int e = tid; e < 4096; e += 256) S1[e] = Wg[e];
    __syncthreads();

    float rm[4][4] = {{0}};
    mm64<true,false>(S1, 64, S2, 64, ty, tx, rm, 1.0f);
    __syncthreads();

#pragma unroll
    for (int i = 0; i < 4; ++i)
#pragma unroll
        for (int j = 0; j < 4; ++j) {
            const int y = 4*ty + i, x = 4*tx + j;
            S2[y*64 + x] = rm[i][j] + Ug[y*64 + x];
            S1[y*64 + x] = (y <= x) ? (-BP) * a1[i][j] : 0.f;
            S4[y*64 + x] = (y <= x) ? a2[i][j] : 0.f;
        }
    __syncthreads();

    mm64<false,false>(S4, 64, S3, 64, ty, tx, Oacc, 1.0f);
    mm64<false,false>(S1, 64, S2, 64, ty, tx, Oacc, 1.0f);

#pragma unroll
    for (int i = 0; i < 4; ++i)
#pragma unroll
        for (int j = 0; j < 4; ++j)
            ob[((size_t)(b * T_ + c * CS + 4*ty + i)) * CDIM + h * HS + 4*tx + j] =
                f2bf(Oacc[i][j]);
}

// ------------------------------ launch ----------------------------------
extern "C" void kernel_launch(void* const* d_in, const int* in_sizes, int n_in,
                              void* d_out, int out_size, void* d_ws, size_t ws_size,
                              hipStream_t stream) {
    const float* x      = (const float*)d_in[0];   // (4,1024,768)
    const float* w_attn = (const float*)d_in[1];   // (768, 2304)
    const float* w_proj = (const float*)d_in[2];   // (768, 768)
    float* out = (float*)d_out;
    float* ws  = (float*)d_ws;
    float* qkv = ws;
    u16* xb  = (u16*)(ws + OFF_XB);
    u16* waT = (u16*)(ws + OFF_WAT);
    u16* ob  = (u16*)(ws + OFF_C);
    u16* wpT = (u16*)ws;   // qkv region, cast after chunkC

    // casts for gemm1
    cast_x_kernel<<<(MROWS * CDIM) / (256 * 4), 256, 0, stream>>>(x, xb);
    tcast_kernel<<<dim3(QKVW / 64, CDIM / 64), 256, 0, stream>>>(w_attn, waT, QKVW, CDIM);

    // 1) qkv = x @ w_attn   (bf16 MFMA)
    gemm_mfma<false><<<dim3(QKVW / 128, MROWS / 128), 256, 0, stream>>>(
        xb, waT, nullptr, qkv, QKVW, CDIM);

    // 2) standardization
    norm_kernel<<<(MROWS * 3 * NH) / 4, 256, 0, stream>>>(qkv);

    // 3) chunked WY scan
    chunkA<<<768, 256, 0, stream>>>(qkv, ws);
    chunkB<<<48,  256, 0, stream>>>(qkv, ws);
    chunkC<<<768, 256, 0, stream>>>(qkv, ws, ob);

    // 4) y = o @ w_proj + x  (bf16 MFMA, residual fused, writes d_out)
    tcast_kernel<<<dim3(CDIM / 64, CDIM / 64), 256, 0, stream>>>(w_proj, wpT, CDIM, CDIM);
    gemm_mfma<true><<<dim3(CDIM / 128, MROWS / 128), 256, 0, stream>>>(
        ob, wpT, x, out, CDIM, CDIM);
}

// Round 6
// 458.769 us; speedup vs baseline: 1.9257x; 1.3049x over previous
//
#include <hip/hip_runtime.h>

typedef unsigned short u16;
typedef __attribute__((ext_vector_type(4))) unsigned short u16x4;
typedef __attribute__((ext_vector_type(8))) short bf16x8;
typedef __attribute__((ext_vector_type(4))) float f32x4;

#define B_ 4
#define T_ 1024
#define NH 12
#define HS 64
#define CDIM 768
#define QKVW 2304   // 3*CDIM
#define NC 16
#define CS 64
#define LAM 0.99f
#define BP  (0.01f/0.99f)
#define MROWS 4096
#define LSTR 72     // bf16 LDS row stride: 144B, 16B-aligned, 2-way banks (free)

// ws layout (float offsets)
#define OFF_W  9437184            // after qkv (4096*2304)
#define OFF_U  (OFF_W  + 768*4096)
#define OFF_C  (OFF_U  + 768*4096)
#define OFF_R0 (OFF_C  + 768*4096)
#define OFF_XB (OFF_W)                       // bf16 x, aliases W (dead until chunkA)
#define OFF_WAT (OFF_W + 1572864)            // bf16 w_attn^T, aliases W
// ob (bf16 o) aliases OFF_C; w_proj^T bf16 goes at ws[0] (qkv dead after chunkC)

__device__ __forceinline__ u16 f2bf(float f) {
    union { float f; unsigned u; } a; a.f = f;
    const unsigned r = a.u + 0x7FFF + ((a.u >> 16) & 1);
    return (u16)(r >> 16);
}
__device__ __forceinline__ float bf2f(u16 h) {
    union { unsigned u; float f; } a; a.u = ((unsigned)h) << 16; return a.f;
}

// ---------------- cast kernels ------------------------------------------
__global__ __launch_bounds__(256)
void cast_x_kernel(const float* __restrict__ src, u16* __restrict__ dst) {
    const size_t i = ((size_t)blockIdx.x * 256 + threadIdx.x) * 4;
    const float4 v = *(const float4*)(src + i);
    u16x4 u;
    u.x = f2bf(v.x); u.y = f2bf(v.y); u.z = f2bf(v.z); u.w = f2bf(v.w);
    *(u16x4*)(dst + i) = u;
}

// src [Rr][Cn] fp32  ->  dst [Cn][Rr] bf16. grid (Cn/64, Rr/64), 256 thr.
__global__ __launch_bounds__(256)
void tcast_kernel(const float* __restrict__ src, u16* __restrict__ dst,
                  int Cn, int Rr) {
    const int ln = threadIdx.x & 63, kg = threadIdx.x >> 6;
    const int n = blockIdx.x * 64 + ln;
    const int kb = blockIdx.y * 64 + kg * 16;
    u16 tmp[16];
#pragma unroll
    for (int j = 0; j < 16; ++j)
        tmp[j] = f2bf(src[(size_t)(kb + j) * Cn + n]);
#pragma unroll
    for (int j4 = 0; j4 < 4; ++j4) {
        u16x4 u; u.x = tmp[j4*4]; u.y = tmp[j4*4+1]; u.z = tmp[j4*4+2]; u.w = tmp[j4*4+3];
        *(u16x4*)&dst[(size_t)n * Rr + kb + j4*4] = u;
    }
}

// ---------------- MFMA GEMM: C[M,N] = A[M,K] @ Bt[N,K]^T (+R) -----------
__device__ __forceinline__ void gll16(const u16* g, u16* lds) {
    __builtin_amdgcn_global_load_lds(
        (const __attribute__((address_space(1))) unsigned*)g,
        (__attribute__((address_space(3))) unsigned*)lds, 16, 0, 0);
}

template<bool ADD_RES>
__global__ __launch_bounds__(256)
void gemm_mfma(const u16* __restrict__ A, const u16* __restrict__ Bt,
               const float* __restrict__ R, float* __restrict__ C,
               int N, int K) {
    __shared__ u16 As[128 * 64];
    __shared__ u16 Bs[128 * 64];
    const int tid  = threadIdx.x;
    const int wave = tid >> 6, lane = tid & 63;
    const int wm = wave >> 1, wn = wave & 1;
    const int ln = lane & 15, quad = lane >> 4;
    const int m0 = blockIdx.y * 128, n0 = blockIdx.x * 128;

    const int rl = lane >> 3;
    const int kx = ((lane & 7) ^ rl) * 8;
    const u16* Ag = A + (size_t)(m0 + wave * 32 + rl) * K + kx;
    const u16* Bg = Bt + (size_t)(n0 + wave * 32 + rl) * K + kx;
    u16* AsW = &As[(wave * 32) * 64];
    u16* BsW = &Bs[(wave * 32) * 64];

    f32x4 acc[4][4] = {};

    for (int k0 = 0; k0 < K; k0 += 64) {
        __syncthreads();
#pragma unroll
        for (int c8 = 0; c8 < 4; ++c8) {
            gll16(Ag + (size_t)(c8 * 8) * K + k0, AsW + c8 * 8 * 64);
            gll16(Bg + (size_t)(c8 * 8) * K + k0, BsW + c8 * 8 * 64);
        }
        __syncthreads();
#pragma unroll
        for (int k32 = 0; k32 < 64; k32 += 32) {
            const int ko = (k32 + quad * 8) ^ ((ln & 7) * 8);
            bf16x8 af[4], bfr[4];
#pragma unroll
            for (int mi = 0; mi < 4; ++mi)
                af[mi] = *(const bf16x8*)&As[(wm * 64 + mi * 16 + ln) * 64 + ko];
#pragma unroll
            for (int ni = 0; ni < 4; ++ni)
                bfr[ni] = *(const bf16x8*)&Bs[(wn * 64 + ni * 16 + ln) * 64 + ko];
#pragma unroll
            for (int mi = 0; mi < 4; ++mi)
#pragma unroll
                for (int ni = 0; ni < 4; ++ni)
                    acc[mi][ni] = __builtin_amdgcn_mfma_f32_16x16x32_bf16(
                        af[mi], bfr[ni], acc[mi][ni], 0, 0, 0);
        }
    }

#pragma unroll
    for (int mi = 0; mi < 4; ++mi) {
        const int rb = m0 + wm * 64 + mi * 16 + quad * 4;
#pragma unroll
        for (int ni = 0; ni < 4; ++ni) {
            const int col = n0 + wn * 64 + ni * 16 + ln;
#pragma unroll
            for (int r = 0; r < 4; ++r) {
                float v = acc[mi][ni][r];
                if (ADD_RES) v += R[(size_t)(rb + r) * N + col];
                C[(size_t)(rb + r) * N + col] = v;
            }
        }
    }
}

// -------- per-64-element standardization (mean / unbiased std) ----------
__global__ __launch_bounds__(256)
void norm_kernel(float* __restrict__ qkv) {
    const int g    = blockIdx.x * 4 + (threadIdx.x >> 6);
    const int lane = threadIdx.x & 63;
    const size_t idx = (size_t)g * 64 + lane;
    const float v = qkv[idx];
    float s = v, ss = v * v;
#pragma unroll
    for (int off = 1; off < 64; off <<= 1) {
        s  += __shfl_xor(s,  off, 64);
        ss += __shfl_xor(ss, off, 64);
    }
    const float mu  = s * (1.0f / 64.0f);
    const float var = (ss - 64.0f * mu * mu) * (1.0f / 63.0f);
    const float rs  = rsqrtf(var);
    qkv[idx] = (v - mu) * rs;
}

// ---------------- MFMA strip microkernel --------------------------------
// acc[nt] += P[wr..wr+16][0..64] x QT[nt*16..][0..64]^T (contract over k).
// P, QT: bf16 LDS, row stride LSTR. Frag layouts per m89/m120 mappings.
__device__ __forceinline__ void mm_strip(const u16* P, const u16* QT,
                                         int wr, int ln, int quad, f32x4 (&acc)[4]) {
#pragma unroll
    for (int k0 = 0; k0 < 64; k0 += 32) {
        const bf16x8 a = *(const bf16x8*)&P[(wr + ln) * LSTR + k0 + quad * 8];
#pragma unroll
        for (int nt = 0; nt < 4; ++nt) {
            const bf16x8 b = *(const bf16x8*)&QT[(nt * 16 + ln) * LSTR + k0 + quad * 8];
            acc[nt] = __builtin_amdgcn_mfma_f32_16x16x32_bf16(a, b, acc[nt], 0, 0, 0);
        }
    }
}

// ---------------- Kernel A (MFMA): per-(bh,chunk) W, U, C ---------------
// N = b'*SL(G), G=KK^T; T=(I+N)^{-1}=(I-N)(I+N^2)(I+N^4)(I+N^8)(I+N^16)(I+N^32)
// W = T K ; U = (T*SL(H))*K, H[t][s]=k_t.vt_s ; C = Vt^T K - b' K^T U.
// Wave w owns output rows [16w,16w+16) of every strip matmul; Y/M1 are
// left-operands only => in-place, wave-private. Right-operands keep
// transposed LDS copies.
__global__ __launch_bounds__(256)
void chunkA(const float* __restrict__ qkv, float* __restrict__ ws) {
    __shared__ u16 Kb[64 * LSTR], Vb[64 * LSTR], KT[64 * LSTR],
                   VT[64 * LSTR], NT[64 * LSTR], HbT[64 * LSTR];
    u16* const Yb = Kb;   // Kb dead after G/H/no-more-reads sync
    u16* const Np = Vb;   // Vb dead likewise; later M1 = Vb too
    u16* const UT = NT;   // NT dead after chain's last apply

    const int cc = blockIdx.x;
    const int bh = cc >> 4, c = cc & 15;
    const int b = bh / NH, h = bh - b * NH;
    const int tid = threadIdx.x;
    const int w = tid >> 6, lane = tid & 63;
    const int ln = lane & 15, quad = lane >> 4;
    const int wr = w * 16;
    const float* base = qkv + ((size_t)(b * T_ + c * CS)) * QKVW + h * HS;

    // ---- stage K, Vt (+ transposes), bf16
#pragma unroll
    for (int p = 0; p < 16; ++p) {
        const int t = p * 4 + w;
        const float kv = base[(size_t)t * QKVW + CDIM + lane];
        const float vv = base[(size_t)t * QKVW + 2 * CDIM + lane]
                         * __powf(LAM, -(float)(t + 1));
        const u16 kb = f2bf(kv), vb = f2bf(vv);
        Kb[t * LSTR + lane] = kb;
        KT[lane * LSTR + t] = kb;
        Vb[t * LSTR + lane] = vb;
        VT[lane * LSTR + t] = vb;
    }
    __syncthreads();

    // ---- G = K K^T ; H = K Vt^T   (rows t = own strip)
    f32x4 accG[4] = {}, accH[4] = {};
    mm_strip(Kb, Kb, wr, ln, quad, accG);
    mm_strip(Kb, Vb, wr, ln, quad, accH);
    __syncthreads();   // everyone done reading Kb/Vb

    // ---- write N (->Vb), NT, Y=I-N (->Kb), HbT (all-cells writes)
#pragma unroll
    for (int nt = 0; nt < 4; ++nt)
#pragma unroll
        for (int r = 0; r < 4; ++r) {
            const int row = wr + quad * 4 + r, col = nt * 16 + ln;
            const float g = accG[nt][r];
            const u16 nv = (col < row) ? f2bf(BP * g) : (u16)0;
            Np[row * LSTR + col] = nv;
            NT[col * LSTR + row] = nv;
            Yb[row * LSTR + col] = (row == col) ? f2bf(1.0f)
                                 : ((col < row) ? f2bf(-BP * g) : (u16)0);
            HbT[col * LSTR + row] = (col < row) ? f2bf(accH[nt][r]) : (u16)0;
        }
    __syncthreads();

    // ---- Neumann chain: for j=1..5: Np <- Np^2 ; Y <- Y + Y*Np
    for (int j = 0; j < 5; ++j) {
        f32x4 sq[4] = {};
        mm_strip(Np, NT, wr, ln, quad, sq);
        __syncthreads();                       // all reads of Np/NT done
#pragma unroll
        for (int nt = 0; nt < 4; ++nt)
#pragma unroll
            for (int r = 0; r < 4; ++r) {
                const int row = wr + quad * 4 + r, col = nt * 16 + ln;
                const u16 v = f2bf(sq[nt][r]);
                Np[row * LSTR + col] = v;
                NT[col * LSTR + row] = v;
            }
        __syncthreads();                       // new power visible
        f32x4 ya[4];
#pragma unroll
        for (int nt = 0; nt < 4; ++nt)
#pragma unroll
            for (int r = 0; r < 4; ++r)
                ya[nt][r] = bf2f(Yb[(wr + quad * 4 + r) * LSTR + nt * 16 + ln]);
        mm_strip(Yb, NT, wr, ln, quad, ya);    // Y*Np + Y (own rows, in place)
#pragma unroll
        for (int nt = 0; nt < 4; ++nt)
#pragma unroll
            for (int r = 0; r < 4; ++r)
                Yb[(wr + quad * 4 + r) * LSTR + nt * 16 + ln] = f2bf(ya[nt][r]);
    }

    float* Wg = ws + OFF_W + (size_t)cc * 4096;
    float* Ug = ws + OFF_U + (size_t)cc * 4096;
    float* Cg = ws + OFF_C + (size_t)cc * 4096;

    // ---- W = Y*K (QT=KT): rows t own strip -> global
    f32x4 wv[4] = {};
    mm_strip(Yb, KT, wr, ln, quad, wv);
#pragma unroll
    for (int nt = 0; nt < 4; ++nt)
#pragma unroll
        for (int r = 0; r < 4; ++r)
            Wg[(wr + quad * 4 + r) * 64 + nt * 16 + ln] = wv[nt][r];

    // ---- M1 = Y*H_SL (QT=HbT) -> LDS (Vb slot; own rows, no sync needed)
    f32x4 m1[4] = {};
    mm_strip(Yb, HbT, wr, ln, quad, m1);
#pragma unroll
    for (int nt = 0; nt < 4; ++nt)
#pragma unroll
        for (int r = 0; r < 4; ++r)
            Np[(wr + quad * 4 + r) * LSTR + nt * 16 + ln] = f2bf(m1[nt][r]);

    // ---- U = M1*K (QT=KT) -> global + UT
    f32x4 uv[4] = {};
    mm_strip(Np, KT, wr, ln, quad, uv);
#pragma unroll
    for (int nt = 0; nt < 4; ++nt)
#pragma unroll
        for (int r = 0; r < 4; ++r)
            Ug[(wr + quad * 4 + r) * 64 + nt * 16 + ln] = uv[nt][r];
    __syncthreads();                           // all waves past last NT reads
#pragma unroll
    for (int nt = 0; nt < 4; ++nt)
#pragma unroll
        for (int r = 0; r < 4; ++r)
            UT[(nt * 16 + ln) * LSTR + wr + quad * 4 + r] = f2bf(uv[nt][r]);
    __syncthreads();

    // ---- C = Vt^T K - b' K^T U   (rows d own strip)
    f32x4 c1[4] = {}, c2[4] = {};
    mm_strip(VT, KT, wr, ln, quad, c1);
    mm_strip(KT, UT, wr, ln, quad, c2);
#pragma unroll
    for (int nt = 0; nt < 4; ++nt)
#pragma unroll
        for (int r = 0; r < 4; ++r)
            Cg[(wr + quad * 4 + r) * 64 + nt * 16 + ln] =
                fmaf(-BP, c2[nt][r], c1[nt][r]);
}

// ---------------- 64x64x64 register-tile matmul microkernel (VALU) ------
template<bool AOM, bool BOM>
__device__ __forceinline__ void mm64(const float* __restrict__ A, int ast,
                                     const float* __restrict__ B, int bst,
                                     int ty, int tx, float (&acc)[4][4],
                                     float scale) {
    const int skew = 16 * (ty & 3);
#pragma unroll 4
    for (int r = 0; r < 64; ++r) {
        const int rr = (r + skew) & 63;
        float a_[4], b_[4];
#pragma unroll
        for (int i = 0; i < 4; ++i)
            a_[i] = AOM ? A[(4*ty + i)*ast + rr] : A[rr*ast + 4*ty + i];
#pragma unroll
        for (int j = 0; j < 4; ++j)
            b_[j] = BOM ? B[(4*tx + j)*bst + rr] : B[rr*bst + 4*tx + j];
#pragma unroll
        for (int i = 0; i < 4; ++i) {
            const float as = scale * a_[i];
#pragma unroll
            for (int j = 0; j < 4; ++j)
                acc[i][j] = fmaf(as, b_[j], acc[i][j]);
        }
    }
}

// ---------------- Kernel B: sequential 16-chunk sweep per bh ------------
__global__ __launch_bounds__(256)
void chunkB(const float* __restrict__ qkv, float* __restrict__ ws) {
    __shared__ float Rh[64*65], Wb[64*65], Pb[64*65];
    const int bh = blockIdx.x;
    const int b = bh / NH, h = bh - b * NH;
    const int tid = threadIdx.x;
    const int ty = tid >> 4, tx = tid & 15;
    const float lam64 = __powf(LAM, 64.0f);

    for (int e = tid; e < 4096; e += 256) Rh[(e >> 6)*65 + (e & 63)] = 0.f;
    __syncthreads();

    for (int c = 0; c < NC; ++c) {
        const int cc = bh * 16 + c;
        float* R0g = ws + OFF_R0 + (size_t)cc * 4096;
        const float* Wg = ws + OFF_W + (size_t)cc * 4096;
        const float* Cg = ws + OFF_C + (size_t)cc * 4096;
        for (int e = tid; e < 4096; e += 256) {
            const int t = e >> 6, d = e & 63;
            R0g[e] = Rh[t*65 + d];
            Wb[t*65 + d] = Wg[e];
        }
        __syncthreads();

        float pa[4][4] = {{0}};
        mm64<true,false>(Wb, 65, Rh, 65, ty, tx, pa, 1.0f);
#pragma unroll
        for (int i = 0; i < 4; ++i)
#pragma unroll
            for (int j = 0; j < 4; ++j)
                Pb[(4*ty + i)*65 + 4*tx + j] = pa[i][j];
        __syncthreads();

        const float* kb = qkv + ((size_t)(b * T_ + c * CS)) * QKVW + h * HS + CDIM;
        for (int e = tid; e < 4096; e += 256) {
            const int t = e >> 6, d = e & 63;
            Wb[t*65 + d] = kb[(size_t)t*QKVW + d];
        }
        __syncthreads();

        float ka[4][4] = {{0}};
        mm64<false,false>(Wb, 65, Pb, 65, ty, tx, ka, 1.0f);
#pragma unroll
        for (int i = 0; i < 4; ++i)
#pragma unroll
            for (int j = 0; j < 4; ++j) {
                const int y = 4*ty + i, x = 4*tx + j;
                Rh[y*65 + x] = lam64 * (fmaf(-BP, ka[i][j], Rh[y*65 + x]) + Cg[y*64 + x]);
            }
        __syncthreads();
    }
}

// ---------------- Kernel C: outputs per (bh,chunk), bf16 out ------------
__global__ __launch_bounds__(256)
void chunkC(const float* __restrict__ qkv, const float* __restrict__ ws,
            u16* __restrict__ ob) {
    __shared__ float S1[4096], S2[4096], S3[4096], S4[4096];
    const int cc = blockIdx.x;
    const int bh = cc >> 4, c = cc & 15;
    const int b = bh / NH, h = bh - b * NH;
    const int tid = threadIdx.x;
    const int ty = tid >> 4, tx = tid & 15;
    const float* base = qkv + ((size_t)(b * T_ + c * CS)) * QKVW + h * HS;
    const float* R0g = ws + OFF_R0 + (size_t)cc * 4096;
    const float* Wg  = ws + OFF_W  + (size_t)cc * 4096;
    const float* Ug  = ws + OFF_U  + (size_t)cc * 4096;

    for (int e = tid; e < 4096; e += 256) {
        const int t = e >> 6, d = e & 63;
        S1[t*64 + d] = base[(size_t)t*QKVW + d] * __powf(LAM, (float)(t+1));
        S3[t*64 + d] = base[(size_t)t*QKVW + CDIM + d];
        S4[t*64 + d] = base[(size_t)t*QKVW + 2*CDIM + d] * __powf(LAM, -(float)(t+1));
        S2[e] = R0g[e];
    }
    __syncthreads();

    float Oacc[4][4] = {{0}};
    mm64<true,false>(S1, 64, S2, 64, ty, tx, Oacc, 1.0f);
    float a1[4][4] = {{0}};
    mm64<true,true>(S3, 64, S1, 64, ty, tx, a1, 1.0f);
    float a2[4][4] = {{0}};
    mm64<true,true>(S4, 64, S1, 64, ty, tx, a2, 1.0f);
    __syncthreads();

    for (int e = tid; e < 4096; e += 256) S1[e] = Wg[e];
    __syncthreads();

    float rm[4][4] = {{0}};
    mm64<true,false>(S1, 64, S2, 64, ty, tx, rm, 1.0f);
    __syncthreads();

#pragma unroll
    for (int i = 0; i < 4; ++i)
#pragma unroll
        for (int j = 0; j < 4; ++j) {
            const int y = 4*ty + i, x = 4*tx + j;
            S2[y*64 + x] = rm[i][j] + Ug[y*64 + x];
            S1[y*64 + x] = (y <= x) ? (-BP) * a1[i][j] : 0.f;
            S4[y*64 + x] = (y <= x) ? a2[i][j] : 0.f;
        }
    __syncthreads();

    mm64<false,false>(S4, 64, S3, 64, ty, tx, Oacc, 1.0f);
    mm64<false,false>(S1, 64, S2, 64, ty, tx, Oacc, 1.0f);

#pragma unroll
    for (int i = 0; i < 4; ++i)
#pragma unroll
        for (int j = 0; j < 4; ++j)
            ob[((size_t)(b * T_ + c * CS + 4*ty + i)) * CDIM + h * HS + 4*tx + j] =
                f2bf(Oacc[i][j]);
}

// ------------------------------ launch ----------------------------------
extern "C" void kernel_launch(void* const* d_in, const int* in_sizes, int n_in,
                              void* d_out, int out_size, void* d_ws, size_t ws_size,
                              hipStream_t stream) {
    const float* x      = (const float*)d_in[0];   // (4,1024,768)
    const float* w_attn = (const float*)d_in[1];   // (768, 2304)
    const float* w_proj = (const float*)d_in[2];   // (768, 768)
    float* out = (float*)d_out;
    float* ws  = (float*)d_ws;
    float* qkv = ws;
    u16* xb  = (u16*)(ws + OFF_XB);
    u16* waT = (u16*)(ws + OFF_WAT);
    u16* ob  = (u16*)(ws + OFF_C);
    u16* wpT = (u16*)ws;   // qkv region, cast after chunkC

    // casts for gemm1
    cast_x_kernel<<<(MROWS * CDIM) / (256 * 4), 256, 0, stream>>>(x, xb);
    tcast_kernel<<<dim3(QKVW / 64, CDIM / 64), 256, 0, stream>>>(w_attn, waT, QKVW, CDIM);

    // 1) qkv = x @ w_attn   (bf16 MFMA)
    gemm_mfma<false><<<dim3(QKVW / 128, MROWS / 128), 256, 0, stream>>>(
        xb, waT, nullptr, qkv, QKVW, CDIM);

    // 2) standardization
    norm_kernel<<<(MROWS * 3 * NH) / 4, 256, 0, stream>>>(qkv);

    // 3) chunked WY scan
    chunkA<<<768, 256, 0, stream>>>(qkv, ws);
    chunkB<<<48,  256, 0, stream>>>(qkv, ws);
    chunkC<<<768, 256, 0, stream>>>(qkv, ws, ob);

    // 4) y = o @ w_proj + x  (bf16 MFMA, residual fused, writes d_out)
    tcast_kernel<<<dim3(CDIM / 64, CDIM / 64), 256, 0, stream>>>(w_proj, wpT, CDIM, CDIM);
    gemm_mfma<true><<<dim3(CDIM / 128, MROWS / 128), 256, 0, stream>>>(
        ob, wpT, x, out, CDIM, CDIM);
}

// Round 8
// 337.147 us; speedup vs baseline: 2.6204x; 1.3607x over previous
//
#include <hip/hip_runtime.h>

typedef unsigned short u16;
typedef __attribute__((ext_vector_type(4))) unsigned short u16x4;
typedef __attribute__((ext_vector_type(8))) short bf16x8;
typedef __attribute__((ext_vector_type(4))) float f32x4;

#define B_ 4
#define T_ 1024
#define NH 12
#define HS 64
#define CDIM 768
#define QKVW 2304   // 3*CDIM
#define NC 16
#define CS 64
#define LAM 0.99f
#define BP  (0.01f/0.99f)
#define MROWS 4096
#define LSTR 72     // bf16 LDS row stride: 144B, 16B-aligned, 2-way banks (free)

// ws layout (float offsets)
#define OFF_W  9437184            // after qkv (4096*2304)
#define OFF_U  (OFF_W  + 768*4096)
#define OFF_C  (OFF_U  + 768*4096)
#define OFF_R0 (OFF_C  + 768*4096)
#define OFF_XB (OFF_W)                       // bf16 x, aliases W (dead until chunkA)
#define OFF_WAT (OFF_W + 1572864)            // bf16 w_attn^T, aliases W
// ob (bf16 o) aliases OFF_C; w_proj^T bf16 goes at ws[0] (qkv dead after chunkC)
// d_out doubles as scratch: wbg (bf16 W, swizzled) + ktg (bf16 K^T, swizzled)

__device__ __forceinline__ u16 f2bf(float f) {
    union { float f; unsigned u; } a; a.f = f;
    const unsigned r = a.u + 0x7FFF + ((a.u >> 16) & 1);
    return (u16)(r >> 16);
}
__device__ __forceinline__ float bf2f(u16 h) {
    union { unsigned u; float f; } a; a.u = ((unsigned)h) << 16; return a.f;
}

// ---------------- cast kernels ------------------------------------------
__global__ __launch_bounds__(256)
void cast_x_kernel(const float* __restrict__ src, u16* __restrict__ dst) {
    const size_t i = ((size_t)blockIdx.x * 256 + threadIdx.x) * 4;
    const float4 v = *(const float4*)(src + i);
    u16x4 u;
    u.x = f2bf(v.x); u.y = f2bf(v.y); u.z = f2bf(v.z); u.w = f2bf(v.w);
    *(u16x4*)(dst + i) = u;
}

// src [Rr][Cn] fp32  ->  dst [Cn][Rr] bf16. grid (Cn/64, Rr/64), 256 thr.
__global__ __launch_bounds__(256)
void tcast_kernel(const float* __restrict__ src, u16* __restrict__ dst,
                  int Cn, int Rr) {
    const int ln = threadIdx.x & 63, kg = threadIdx.x >> 6;
    const int n = blockIdx.x * 64 + ln;
    const int kb = blockIdx.y * 64 + kg * 16;
    u16 tmp[16];
#pragma unroll
    for (int j = 0; j < 16; ++j)
        tmp[j] = f2bf(src[(size_t)(kb + j) * Cn + n]);
#pragma unroll
    for (int j4 = 0; j4 < 4; ++j4) {
        u16x4 u; u.x = tmp[j4*4]; u.y = tmp[j4*4+1]; u.z = tmp[j4*4+2]; u.w = tmp[j4*4+3];
        *(u16x4*)&dst[(size_t)n * Rr + kb + j4*4] = u;
    }
}

// ---------------- MFMA GEMM: C[M,N] = A[M,K] @ Bt[N,K]^T (+R) -----------
__device__ __forceinline__ void gll16(const u16* g, u16* lds) {
    __builtin_amdgcn_global_load_lds(
        (const __attribute__((address_space(1))) unsigned*)g,
        (__attribute__((address_space(3))) unsigned*)lds, 16, 0, 0);
}

template<bool ADD_RES>
__global__ __launch_bounds__(256)
void gemm_mfma(const u16* __restrict__ A, const u16* __restrict__ Bt,
               const float* __restrict__ R, float* __restrict__ C,
               int N, int K) {
    __shared__ u16 As[128 * 64];
    __shared__ u16 Bs[128 * 64];
    const int tid  = threadIdx.x;
    const int wave = tid >> 6, lane = tid & 63;
    const int wm = wave >> 1, wn = wave & 1;
    const int ln = lane & 15, quad = lane >> 4;
    const int m0 = blockIdx.y * 128, n0 = blockIdx.x * 128;

    const int rl = lane >> 3;
    const int kx = ((lane & 7) ^ rl) * 8;
    const u16* Ag = A + (size_t)(m0 + wave * 32 + rl) * K + kx;
    const u16* Bg = Bt + (size_t)(n0 + wave * 32 + rl) * K + kx;
    u16* AsW = &As[(wave * 32) * 64];
    u16* BsW = &Bs[(wave * 32) * 64];

    f32x4 acc[4][4] = {};

    for (int k0 = 0; k0 < K; k0 += 64) {
        __syncthreads();
#pragma unroll
        for (int c8 = 0; c8 < 4; ++c8) {
            gll16(Ag + (size_t)(c8 * 8) * K + k0, AsW + c8 * 8 * 64);
            gll16(Bg + (size_t)(c8 * 8) * K + k0, BsW + c8 * 8 * 64);
        }
        __syncthreads();
#pragma unroll
        for (int k32 = 0; k32 < 64; k32 += 32) {
            const int ko = (k32 + quad * 8) ^ ((ln & 7) * 8);
            bf16x8 af[4], bfr[4];
#pragma unroll
            for (int mi = 0; mi < 4; ++mi)
                af[mi] = *(const bf16x8*)&As[(wm * 64 + mi * 16 + ln) * 64 + ko];
#pragma unroll
            for (int ni = 0; ni < 4; ++ni)
                bfr[ni] = *(const bf16x8*)&Bs[(wn * 64 + ni * 16 + ln) * 64 + ko];
#pragma unroll
            for (int mi = 0; mi < 4; ++mi)
#pragma unroll
                for (int ni = 0; ni < 4; ++ni)
                    acc[mi][ni] = __builtin_amdgcn_mfma_f32_16x16x32_bf16(
                        af[mi], bfr[ni], acc[mi][ni], 0, 0, 0);
        }
    }

#pragma unroll
    for (int mi = 0; mi < 4; ++mi) {
        const int rb = m0 + wm * 64 + mi * 16 + quad * 4;
#pragma unroll
        for (int ni = 0; ni < 4; ++ni) {
            const int col = n0 + wn * 64 + ni * 16 + ln;
#pragma unroll
            for (int r = 0; r < 4; ++r) {
                float v = acc[mi][ni][r];
                if (ADD_RES) v += R[(size_t)(rb + r) * N + col];
                C[(size_t)(rb + r) * N + col] = v;
            }
        }
    }
}

// -------- per-64-element standardization (mean / unbiased std) ----------
__global__ __launch_bounds__(256)
void norm_kernel(float* __restrict__ qkv) {
    const int g    = blockIdx.x * 4 + (threadIdx.x >> 6);
    const int lane = threadIdx.x & 63;
    const size_t idx = (size_t)g * 64 + lane;
    const float v = qkv[idx];
    float s = v, ss = v * v;
#pragma unroll
    for (int off = 1; off < 64; off <<= 1) {
        s  += __shfl_xor(s,  off, 64);
        ss += __shfl_xor(ss, off, 64);
    }
    const float mu  = s * (1.0f / 64.0f);
    const float var = (ss - 64.0f * mu * mu) * (1.0f / 63.0f);
    const float rs  = rsqrtf(var);
    qkv[idx] = (v - mu) * rs;
}

// ---------------- MFMA strip microkernels -------------------------------
// acc[nt] += P[wr..wr+16][:] x QT[nt*16..][:]^T. P,QT padded LDS (LSTR).
__device__ __forceinline__ void mm_strip(const u16* P, const u16* QT,
                                         int wr, int ln, int quad, f32x4 (&acc)[4]) {
#pragma unroll
    for (int k0 = 0; k0 < 64; k0 += 32) {
        const bf16x8 a = *(const bf16x8*)&P[(wr + ln) * LSTR + k0 + quad * 8];
#pragma unroll
        for (int nt = 0; nt < 4; ++nt) {
            const bf16x8 b = *(const bf16x8*)&QT[(nt * 16 + ln) * LSTR + k0 + quad * 8];
            acc[nt] = __builtin_amdgcn_mfma_f32_16x16x32_bf16(a, b, acc[nt], 0, 0, 0);
        }
    }
}

// A operand from flat (stride 64) XOR-swizzled LDS (staged by global_load_lds)
__device__ __forceinline__ void mm_strip_swz(const u16* Aflat, const u16* QT,
                                             int wr, int ln, int quad, f32x4 (&acc)[4]) {
#pragma unroll
    for (int k0 = 0; k0 < 64; k0 += 32) {
        const int kk = (k0 + quad * 8) ^ ((ln & 7) * 8);
        const bf16x8 a = *(const bf16x8*)&Aflat[(wr + ln) * 64 + kk];
#pragma unroll
        for (int nt = 0; nt < 4; ++nt) {
            const bf16x8 b = *(const bf16x8*)&QT[(nt * 16 + ln) * LSTR + k0 + quad * 8];
            acc[nt] = __builtin_amdgcn_mfma_f32_16x16x32_bf16(a, b, acc[nt], 0, 0, 0);
        }
    }
}

// ---------------- Kernel A (MFMA): per-(bh,chunk) W, U, C ---------------
// Also exports bf16 swizzled W ([t][k']) and K^T ([d][t']) into scratch
// (d_out region) for chunkB's global_load_lds staging, and C in
// lane-contiguous permuted order.
__global__ __launch_bounds__(256)
void chunkA(const float* __restrict__ qkv, float* __restrict__ ws,
            u16* __restrict__ wbg, u16* __restrict__ ktg) {
    __shared__ u16 Kb[64 * LSTR], Vb[64 * LSTR], KT[64 * LSTR],
                   VT[64 * LSTR], NT[64 * LSTR], HbT[64 * LSTR];
    u16* const Yb = Kb;   // Kb dead after G/H
    u16* const Np = Vb;   // Vb dead likewise; later M1
    u16* const UT = NT;   // NT dead after chain

    const int cc = blockIdx.x;
    const int bh = cc >> 4, c = cc & 15;
    const int b = bh / NH, h = bh - b * NH;
    const int tid = threadIdx.x;
    const int w = tid >> 6, lane = tid & 63;
    const int ln = lane & 15, quad = lane >> 4;
    const int wr = w * 16;
    const float* base = qkv + ((size_t)(b * T_ + c * CS)) * QKVW + h * HS;

#pragma unroll
    for (int p = 0; p < 16; ++p) {
        const int t = p * 4 + w;
        const float kv = base[(size_t)t * QKVW + CDIM + lane];
        const float vv = base[(size_t)t * QKVW + 2 * CDIM + lane]
                         * __powf(LAM, -(float)(t + 1));
        const u16 kb = f2bf(kv), vb = f2bf(vv);
        Kb[t * LSTR + lane] = kb;
        KT[lane * LSTR + t] = kb;
        Vb[t * LSTR + lane] = vb;
        VT[lane * LSTR + t] = vb;
    }
    __syncthreads();

    f32x4 accG[4] = {}, accH[4] = {};
    mm_strip(Kb, Kb, wr, ln, quad, accG);
    mm_strip(Kb, Vb, wr, ln, quad, accH);
    __syncthreads();

#pragma unroll
    for (int nt = 0; nt < 4; ++nt)
#pragma unroll
        for (int r = 0; r < 4; ++r) {
            const int row = wr + quad * 4 + r, col = nt * 16 + ln;
            const float g = accG[nt][r];
            const u16 nv = (col < row) ? f2bf(BP * g) : (u16)0;
            Np[row * LSTR + col] = nv;
            NT[col * LSTR + row] = nv;
            Yb[row * LSTR + col] = (row == col) ? f2bf(1.0f)
                                 : ((col < row) ? f2bf(-BP * g) : (u16)0);
            HbT[col * LSTR + row] = (col < row) ? f2bf(accH[nt][r]) : (u16)0;
        }
    __syncthreads();

    for (int j = 0; j < 5; ++j) {
        f32x4 sq[4] = {};
        mm_strip(Np, NT, wr, ln, quad, sq);
        __syncthreads();
#pragma unroll
        for (int nt = 0; nt < 4; ++nt)
#pragma unroll
            for (int r = 0; r < 4; ++r) {
                const int row = wr + quad * 4 + r, col = nt * 16 + ln;
                const u16 v = f2bf(sq[nt][r]);
                Np[row * LSTR + col] = v;
                NT[col * LSTR + row] = v;
            }
        __syncthreads();
        f32x4 ya[4];
#pragma unroll
        for (int nt = 0; nt < 4; ++nt)
#pragma unroll
            for (int r = 0; r < 4; ++r)
                ya[nt][r] = bf2f(Yb[(wr + quad * 4 + r) * LSTR + nt * 16 + ln]);
        mm_strip(Yb, NT, wr, ln, quad, ya);
#pragma unroll
        for (int nt = 0; nt < 4; ++nt)
#pragma unroll
            for (int r = 0; r < 4; ++r)
                Yb[(wr + quad * 4 + r) * LSTR + nt * 16 + ln] = f2bf(ya[nt][r]);
    }

    float* Wg = ws + OFF_W + (size_t)cc * 4096;
    float* Ug = ws + OFF_U + (size_t)cc * 4096;
    float* Cg = ws + OFF_C + (size_t)cc * 4096;

    // W = Y*K -> fp32 global (for chunkC)
    f32x4 wv[4] = {};
    mm_strip(Yb, KT, wr, ln, quad, wv);
#pragma unroll
    for (int nt = 0; nt < 4; ++nt)
#pragma unroll
        for (int r = 0; r < 4; ++r)
            Wg[(wr + quad * 4 + r) * 64 + nt * 16 + ln] = wv[nt][r];

    // M1 = Y*H_SL -> Np (own rows)
    f32x4 m1[4] = {};
    mm_strip(Yb, HbT, wr, ln, quad, m1);
#pragma unroll
    for (int nt = 0; nt < 4; ++nt)
#pragma unroll
        for (int r = 0; r < 4; ++r)
            Np[(wr + quad * 4 + r) * LSTR + nt * 16 + ln] = f2bf(m1[nt][r]);

    // Y dead -> overwrite own rows with bf16 W (for export to chunkB)
#pragma unroll
    for (int nt = 0; nt < 4; ++nt)
#pragma unroll
        for (int r = 0; r < 4; ++r)
            Yb[(wr + quad * 4 + r) * LSTR + nt * 16 + ln] = f2bf(wv[nt][r]);

    // U = M1*K -> global + UT
    f32x4 uv[4] = {};
    mm_strip(Np, KT, wr, ln, quad, uv);
#pragma unroll
    for (int nt = 0; nt < 4; ++nt)
#pragma unroll
        for (int r = 0; r < 4; ++r)
            Ug[(wr + quad * 4 + r) * 64 + nt * 16 + ln] = uv[nt][r];
    __syncthreads();
#pragma unroll
    for (int nt = 0; nt < 4; ++nt)
#pragma unroll
        for (int r = 0; r < 4; ++r)
            UT[(nt * 16 + ln) * LSTR + wr + quad * 4 + r] = f2bf(uv[nt][r]);
    __syncthreads();

    // C = Vt^T K - b' K^T U  -> permuted (lane-contiguous) layout for chunkB
    f32x4 c1[4] = {}, c2[4] = {};
    mm_strip(VT, KT, wr, ln, quad, c1);
    mm_strip(KT, UT, wr, ln, quad, c2);
#pragma unroll
    for (int nt = 0; nt < 4; ++nt) {
        const f32x4 cv = c1[nt] - BP * c2[nt];
        *(f32x4*)&Cg[(size_t)(w * 64 + lane) * 16 + nt * 4] = cv;
    }

    // export bf16 swizzled W and K^T (reads Yb/KT; all writes synced above)
    for (int e = tid; e < 512; e += 256) {
        const int t = e >> 3, g = e & 7;
        *(bf16x8*)&wbg[(size_t)cc * 4096 + t * 64 + ((g ^ (t & 7)) << 3)] =
            *(const bf16x8*)&Yb[t * LSTR + (g << 3)];
    }
    for (int e = tid; e < 512; e += 256) {
        const int d = e >> 3, g = e & 7;
        *(bf16x8*)&ktg[(size_t)cc * 4096 + d * 64 + ((g ^ (d & 7)) << 3)] =
            *(const bf16x8*)&KT[d * LSTR + (g << 3)];
    }
}

// ---------------- Kernel B (MFMA): sequential 16-chunk sweep per bh -----
// R' = lam64*(R - b' K^T (W R) + C). R fp32 in registers (wave-owned
// 16-row strips); W/K^T staged bf16 via global_load_lds (double-buffered).
// Staging units: one gll16 = 64 lanes x 16 B = 512 u16. Wave w owns rows
// [16w,16w+16) = u16 [1024w, 1024w+1024) -> 2 instrs, step 512 u16.
__global__ __launch_bounds__(256)
void chunkB(float* __restrict__ ws, const u16* __restrict__ wbg,
            const u16* __restrict__ ktg) {
    __shared__ u16 WBs[2][4096], KTs[2][4096];
    __shared__ u16 RTb[64 * LSTR], PTb[64 * LSTR];

    const int bh = blockIdx.x;
    const int tid = threadIdx.x;
    const int w = tid >> 6, lane = tid & 63;
    const int ln = lane & 15, quad = lane >> 4;
    const int wr = w * 16;
    const float lam64 = __powf(LAM, 64.0f);

    f32x4 R[4] = {};   // rows d = wr+quad*4+r, cols nt*16+ln

    for (int e = tid; e < 64 * LSTR; e += 256) RTb[e] = 0;

    const int off = w * 1024;   // wave's 16-row segment in u16
    {
        const size_t b0 = (size_t)(bh * 16) * 4096;
#pragma unroll
        for (int i = 0; i < 2; ++i) {
            gll16(wbg + b0 + off + i * 512 + lane * 8, &WBs[0][off + i * 512]);
            gll16(ktg + b0 + off + i * 512 + lane * 8, &KTs[0][off + i * 512]);
        }
    }
    __syncthreads();   // staging (vm drain) + RTb zeros visible

    for (int c = 0; c < NC; ++c) {
        const int buf = c & 1;
        const size_t cc = (size_t)(bh * 16 + c);

        if (c + 1 < NC) {   // stage next chunk into other buffer
            const size_t b1 = (cc + 1) * 4096;
#pragma unroll
            for (int i = 0; i < 2; ++i) {
                gll16(wbg + b1 + off + i * 512 + lane * 8, &WBs[buf ^ 1][off + i * 512]);
                gll16(ktg + b1 + off + i * 512 + lane * 8, &KTs[buf ^ 1][off + i * 512]);
            }
        }

        // P = W x R   (A = staged W, B = R^T)
        f32x4 p[4] = {};
        mm_strip_swz(&WBs[buf][0], RTb, wr, ln, quad, p);
#pragma unroll
        for (int nt = 0; nt < 4; ++nt) {
            u16x4 pv;
            pv.x = f2bf(p[nt][0]); pv.y = f2bf(p[nt][1]);
            pv.z = f2bf(p[nt][2]); pv.w = f2bf(p[nt][3]);
            *(u16x4*)&PTb[(nt * 16 + ln) * LSTR + wr + quad * 4] = pv;
        }
        __syncthreads();   // PTb ready; everyone past P (RTb free)

        // ka = K^T x P  (A = staged K^T, B = P^T)
        f32x4 kp[4] = {};
        mm_strip_swz(&KTs[buf][0], PTb, wr, ln, quad, kp);

        float* r0 = ws + OFF_R0 + cc * 4096;
        const float* Cg = ws + OFF_C + cc * 4096 + (size_t)(w * 64 + lane) * 16;
        const int row = wr + quad * 4;
#pragma unroll
        for (int nt = 0; nt < 4; ++nt) {
            const int col = nt * 16 + ln;
#pragma unroll
            for (int r = 0; r < 4; ++r)
                r0[(size_t)(row + r) * 64 + col] = R[nt][r];   // R0 = pre-update
            const f32x4 cv = *(const f32x4*)&Cg[nt * 4];
            R[nt] = lam64 * (R[nt] - BP * kp[nt] + cv);
            u16x4 rv;
            rv.x = f2bf(R[nt][0]); rv.y = f2bf(R[nt][1]);
            rv.z = f2bf(R[nt][2]); rv.w = f2bf(R[nt][3]);
            *(u16x4*)&RTb[(nt * 16 + ln) * LSTR + wr + quad * 4] = rv;
        }
        __syncthreads();   // RTb_{c+1} + staged buffers visible
    }
}

// ---------------- 64x64x64 register-tile matmul microkernel (VALU) ------
template<bool AOM, bool BOM>
__device__ __forceinline__ void mm64(const float* __restrict__ A, int ast,
                                     const float* __restrict__ B, int bst,
                                     int ty, int tx, float (&acc)[4][4],
                                     float scale) {
    const int skew = 16 * (ty & 3);
#pragma unroll 4
    for (int r = 0; r < 64; ++r) {
        const int rr = (r + skew) & 63;
        float a_[4], b_[4];
#pragma unroll
        for (int i = 0; i < 4; ++i)
            a_[i] = AOM ? A[(4*ty + i)*ast + rr] : A[rr*ast + 4*ty + i];
#pragma unroll
        for (int j = 0; j < 4; ++j)
            b_[j] = BOM ? B[(4*tx + j)*bst + rr] : B[rr*bst + 4*tx + j];
#pragma unroll
        for (int i = 0; i < 4; ++i) {
            const float as = scale * a_[i];
#pragma unroll
            for (int j = 0; j < 4; ++j)
                acc[i][j] = fmaf(as, b_[j], acc[i][j]);
        }
    }
}

// ---------------- Kernel C: outputs per (bh,chunk), bf16 out ------------
__global__ __launch_bounds__(256)
void chunkC(const float* __restrict__ qkv, const float* __restrict__ ws,
            u16* __restrict__ ob) {
    __shared__ float S1[4096], S2[4096], S3[4096], S4[4096];
    const int cc = blockIdx.x;
    const int bh = cc >> 4, c = cc & 15;
    const int b = bh / NH, h = bh - b * NH;
    const int tid = threadIdx.x;
    const int ty = tid >> 4, tx = tid & 15;
    const float* base = qkv + ((size_t)(b * T_ + c * CS)) * QKVW + h * HS;
    const float* R0g = ws + OFF_R0 + (size_t)cc * 4096;
    const float* Wg  = ws + OFF_W  + (size_t)cc * 4096;
    const float* Ug  = ws + OFF_U  + (size_t)cc * 4096;

    for (int e = tid; e < 4096; e += 256) {
        const int t = e >> 6, d = e & 63;
        S1[t*64 + d] = base[(size_t)t*QKVW + d] * __powf(LAM, (float)(t+1));
        S3[t*64 + d] = base[(size_t)t*QKVW + CDIM + d];
        S4[t*64 + d] = base[(size_t)t*QKVW + 2*CDIM + d] * __powf(LAM, -(float)(t+1));
        S2[e] = R0g[e];
    }
    __syncthreads();

    float Oacc[4][4] = {{0}};
    mm64<true,false>(S1, 64, S2, 64, ty, tx, Oacc, 1.0f);
    float a1[4][4] = {{0}};
    mm64<true,true>(S3, 64, S1, 64, ty, tx, a1, 1.0f);
    float a2[4][4] = {{0}};
    mm64<true,true>(S4, 64, S1, 64, ty, tx, a2, 1.0f);
    __syncthreads();

    for (int e = tid; e < 4096; e += 256) S1[e] = Wg[e];
    __syncthreads();

    float rm[4][4] = {{0}};
    mm64<true,false>(S1, 64, S2, 64, ty, tx, rm, 1.0f);
    __syncthreads();

#pragma unroll
    for (int i = 0; i < 4; ++i)
#pragma unroll
        for (int j = 0; j < 4; ++j) {
            const int y = 4*ty + i, x = 4*tx + j;
            S2[y*64 + x] = rm[i][j] + Ug[y*64 + x];
            S1[y*64 + x] = (y <= x) ? (-BP) * a1[i][j] : 0.f;
            S4[y*64 + x] = (y <= x) ? a2[i][j] : 0.f;
        }
    __syncthreads();

    mm64<false,false>(S4, 64, S3, 64, ty, tx, Oacc, 1.0f);
    mm64<false,false>(S1, 64, S2, 64, ty, tx, Oacc, 1.0f);

#pragma unroll
    for (int i = 0; i < 4; ++i)
#pragma unroll
        for (int j = 0; j < 4; ++j)
            ob[((size_t)(b * T_ + c * CS + 4*ty + i)) * CDIM + h * HS + 4*tx + j] =
                f2bf(Oacc[i][j]);
}

// ------------------------------ launch ----------------------------------
extern "C" void kernel_launch(void* const* d_in, const int* in_sizes, int n_in,
                              void* d_out, int out_size, void* d_ws, size_t ws_size,
                              hipStream_t stream) {
    const float* x      = (const float*)d_in[0];   // (4,1024,768)
    const float* w_attn = (const float*)d_in[1];   // (768, 2304)
    const float* w_proj = (const float*)d_in[2];   // (768, 768)
    float* out = (float*)d_out;
    float* ws  = (float*)d_ws;
    float* qkv = ws;
    u16* xb  = (u16*)(ws + OFF_XB);
    u16* waT = (u16*)(ws + OFF_WAT);
    u16* ob  = (u16*)(ws + OFF_C);
    u16* wpT = (u16*)ws;   // qkv region, cast after chunkC
    u16* wbg = (u16*)d_out;               // scratch: bf16 W  (swizzled)
    u16* ktg = (u16*)d_out + 768 * 4096;  // scratch: bf16 K^T (swizzled)

    // casts for gemm1
    cast_x_kernel<<<(MROWS * CDIM) / (256 * 4), 256, 0, stream>>>(x, xb);
    tcast_kernel<<<dim3(QKVW / 64, CDIM / 64), 256, 0, stream>>>(w_attn, waT, QKVW, CDIM);

    // 1) qkv = x @ w_attn   (bf16 MFMA)
    gemm_mfma<false><<<dim3(QKVW / 128, MROWS / 128), 256, 0, stream>>>(
        xb, waT, nullptr, qkv, QKVW, CDIM);

    // 2) standardization
    norm_kernel<<<(MROWS * 3 * NH) / 4, 256, 0, stream>>>(qkv);

    // 3) chunked WY scan
    chunkA<<<768, 256, 0, stream>>>(qkv, ws, wbg, ktg);
    chunkB<<<48,  256, 0, stream>>>(ws, wbg, ktg);
    chunkC<<<768, 256, 0, stream>>>(qkv, ws, ob);

    // 4) y = o @ w_proj + x  (bf16 MFMA, residual fused, writes d_out)
    tcast_kernel<<<dim3(CDIM / 64, CDIM / 64), 256, 0, stream>>>(w_proj, wpT, CDIM, CDIM);
    gemm_mfma<true><<<dim3(CDIM / 128, MROWS / 128), 256, 0, stream>>>(
        ob, wpT, x, out, CDIM, CDIM);
}

// Round 9
// 233.226 us; speedup vs baseline: 3.7879x; 1.4456x over previous
//
#include <hip/hip_runtime.h>

typedef unsigned short u16;
typedef __attribute__((ext_vector_type(4))) unsigned short u16x4;
typedef __attribute__((ext_vector_type(8))) short bf16x8;
typedef __attribute__((ext_vector_type(4))) float f32x4;

#define B_ 4
#define T_ 1024
#define NH 12
#define HS 64
#define CDIM 768
#define QKVW 2304   // 3*CDIM
#define NC 16
#define CS 64
#define LAM 0.99f
#define BP  (0.01f/0.99f)
#define MROWS 4096
#define LSTR 72     // bf16 LDS row stride: 144B, 16B-aligned, 2-way banks (free)

// ws layout (float offsets)
#define OFF_W  9437184            // after qkv (4096*2304)
#define OFF_U  (OFF_W  + 768*4096)
#define OFF_C  (OFF_U  + 768*4096)
#define OFF_R0 (OFF_C  + 768*4096)   // now holds bf16 swizzled R0^T (u16)
#define OFF_XB (OFF_W)                       // bf16 x, aliases W (dead region)
#define OFF_WAT (OFF_W + 1572864)            // bf16 w_attn^T, aliases W
// ob (bf16 o) aliases OFF_C; w_proj^T bf16 goes at ws[0] (qkv dead after chunkC)
// d_out doubles as scratch: wbg (bf16 W, swizzled) + ktg (bf16 K^T, swizzled)

__device__ __forceinline__ u16 f2bf(float f) {
    union { float f; unsigned u; } a; a.f = f;
    const unsigned r = a.u + 0x7FFF + ((a.u >> 16) & 1);
    return (u16)(r >> 16);
}
__device__ __forceinline__ float bf2f(u16 h) {
    union { unsigned u; float f; } a; a.u = ((unsigned)h) << 16; return a.f;
}

// ---------------- cast kernels ------------------------------------------
__global__ __launch_bounds__(256)
void cast_x_kernel(const float* __restrict__ src, u16* __restrict__ dst) {
    const size_t i = ((size_t)blockIdx.x * 256 + threadIdx.x) * 4;
    const float4 v = *(const float4*)(src + i);
    u16x4 u;
    u.x = f2bf(v.x); u.y = f2bf(v.y); u.z = f2bf(v.z); u.w = f2bf(v.w);
    *(u16x4*)(dst + i) = u;
}

// src [Rr][Cn] fp32  ->  dst [Cn][Rr] bf16. grid (Cn/64, Rr/64), 256 thr.
__global__ __launch_bounds__(256)
void tcast_kernel(const float* __restrict__ src, u16* __restrict__ dst,
                  int Cn, int Rr) {
    const int ln = threadIdx.x & 63, kg = threadIdx.x >> 6;
    const int n = blockIdx.x * 64 + ln;
    const int kb = blockIdx.y * 64 + kg * 16;
    u16 tmp[16];
#pragma unroll
    for (int j = 0; j < 16; ++j)
        tmp[j] = f2bf(src[(size_t)(kb + j) * Cn + n]);
#pragma unroll
    for (int j4 = 0; j4 < 4; ++j4) {
        u16x4 u; u.x = tmp[j4*4]; u.y = tmp[j4*4+1]; u.z = tmp[j4*4+2]; u.w = tmp[j4*4+3];
        *(u16x4*)&dst[(size_t)n * Rr + kb + j4*4] = u;
    }
}

// ---------------- MFMA GEMM: C[M,N] = A[M,K] @ Bt[N,K]^T (+R) -----------
__device__ __forceinline__ void gll16(const u16* g, u16* lds) {
    __builtin_amdgcn_global_load_lds(
        (const __attribute__((address_space(1))) unsigned*)g,
        (__attribute__((address_space(3))) unsigned*)lds, 16, 0, 0);
}

template<bool ADD_RES>
__global__ __launch_bounds__(256)
void gemm_mfma(const u16* __restrict__ A, const u16* __restrict__ Bt,
               const float* __restrict__ R, float* __restrict__ C,
               int N, int K) {
    __shared__ u16 As[128 * 64];
    __shared__ u16 Bs[128 * 64];
    const int tid  = threadIdx.x;
    const int wave = tid >> 6, lane = tid & 63;
    const int wm = wave >> 1, wn = wave & 1;
    const int ln = lane & 15, quad = lane >> 4;
    const int m0 = blockIdx.y * 128, n0 = blockIdx.x * 128;

    const int rl = lane >> 3;
    const int kx = ((lane & 7) ^ rl) * 8;
    const u16* Ag = A + (size_t)(m0 + wave * 32 + rl) * K + kx;
    const u16* Bg = Bt + (size_t)(n0 + wave * 32 + rl) * K + kx;
    u16* AsW = &As[(wave * 32) * 64];
    u16* BsW = &Bs[(wave * 32) * 64];

    f32x4 acc[4][4] = {};

    for (int k0 = 0; k0 < K; k0 += 64) {
        __syncthreads();
#pragma unroll
        for (int c8 = 0; c8 < 4; ++c8) {
            gll16(Ag + (size_t)(c8 * 8) * K + k0, AsW + c8 * 8 * 64);
            gll16(Bg + (size_t)(c8 * 8) * K + k0, BsW + c8 * 8 * 64);
        }
        __syncthreads();
#pragma unroll
        for (int k32 = 0; k32 < 64; k32 += 32) {
            const int ko = (k32 + quad * 8) ^ ((ln & 7) * 8);
            bf16x8 af[4], bfr[4];
#pragma unroll
            for (int mi = 0; mi < 4; ++mi)
                af[mi] = *(const bf16x8*)&As[(wm * 64 + mi * 16 + ln) * 64 + ko];
#pragma unroll
            for (int ni = 0; ni < 4; ++ni)
                bfr[ni] = *(const bf16x8*)&Bs[(wn * 64 + ni * 16 + ln) * 64 + ko];
#pragma unroll
            for (int mi = 0; mi < 4; ++mi)
#pragma unroll
                for (int ni = 0; ni < 4; ++ni)
                    acc[mi][ni] = __builtin_amdgcn_mfma_f32_16x16x32_bf16(
                        af[mi], bfr[ni], acc[mi][ni], 0, 0, 0);
        }
    }

#pragma unroll
    for (int mi = 0; mi < 4; ++mi) {
        const int rb = m0 + wm * 64 + mi * 16 + quad * 4;
#pragma unroll
        for (int ni = 0; ni < 4; ++ni) {
            const int col = n0 + wn * 64 + ni * 16 + ln;
#pragma unroll
            for (int r = 0; r < 4; ++r) {
                float v = acc[mi][ni][r];
                if (ADD_RES) v += R[(size_t)(rb + r) * N + col];
                C[(size_t)(rb + r) * N + col] = v;
            }
        }
    }
}

// -------- per-64-element standardization (mean / unbiased std) ----------
__global__ __launch_bounds__(256)
void norm_kernel(float* __restrict__ qkv) {
    const int g    = blockIdx.x * 4 + (threadIdx.x >> 6);
    const int lane = threadIdx.x & 63;
    const size_t idx = (size_t)g * 64 + lane;
    const float v = qkv[idx];
    float s = v, ss = v * v;
#pragma unroll
    for (int off = 1; off < 64; off <<= 1) {
        s  += __shfl_xor(s,  off, 64);
        ss += __shfl_xor(ss, off, 64);
    }
    const float mu  = s * (1.0f / 64.0f);
    const float var = (ss - 64.0f * mu * mu) * (1.0f / 63.0f);
    const float rs  = rsqrtf(var);
    qkv[idx] = (v - mu) * rs;
}

// ---------------- MFMA strip microkernel --------------------------------
// acc[nt] += A[strip rows][k] x B[nt*16..][k]^T (contract k over 64).
// ASWZ/BSWZ: operand in flat stride-64 XOR-swizzled layout (gll16-staged
// or producer-swizzled); else padded LSTR layout.
template<bool ASWZ, bool BSWZ>
__device__ __forceinline__ void mm_strip2(const u16* A, const u16* Bq,
                                          int wr, int ln, int quad, f32x4 (&acc)[4]) {
#pragma unroll
    for (int k0 = 0; k0 < 64; k0 += 32) {
        const int kq = k0 + quad * 8;
        const int ks = kq ^ ((ln & 7) * 8);
        const bf16x8 a = ASWZ ? *(const bf16x8*)&A[(wr + ln) * 64 + ks]
                              : *(const bf16x8*)&A[(wr + ln) * LSTR + kq];
#pragma unroll
        for (int nt = 0; nt < 4; ++nt) {
            const bf16x8 b = BSWZ ? *(const bf16x8*)&Bq[(nt * 16 + ln) * 64 + ks]
                                  : *(const bf16x8*)&Bq[(nt * 16 + ln) * LSTR + kq];
            acc[nt] = __builtin_amdgcn_mfma_f32_16x16x32_bf16(a, b, acc[nt], 0, 0, 0);
        }
    }
}

// ---------------- Kernel A (MFMA): per-(bh,chunk) W, U, C ---------------
// Exports bf16 swizzled W ([t][k']) and K^T ([d][t']) for chunkB/chunkC
// staging; U fp32; C in lane-contiguous permuted order for chunkB.
__global__ __launch_bounds__(256)
void chunkA(const float* __restrict__ qkv, float* __restrict__ ws,
            u16* __restrict__ wbg, u16* __restrict__ ktg) {
    __shared__ u16 Kb[64 * LSTR], Vb[64 * LSTR], KT[64 * LSTR],
                   VT[64 * LSTR], NT[64 * LSTR], HbT[64 * LSTR];
    u16* const Yb = Kb;   // Kb dead after G/H
    u16* const Np = Vb;   // Vb dead likewise; later M1
    u16* const UT = NT;   // NT dead after chain

    const int cc = blockIdx.x;
    const int bh = cc >> 4, c = cc & 15;
    const int b = bh / NH, h = bh - b * NH;
    const int tid = threadIdx.x;
    const int w = tid >> 6, lane = tid & 63;
    const int ln = lane & 15, quad = lane >> 4;
    const int wr = w * 16;
    const float* base = qkv + ((size_t)(b * T_ + c * CS)) * QKVW + h * HS;

#pragma unroll
    for (int p = 0; p < 16; ++p) {
        const int t = p * 4 + w;
        const float kv = base[(size_t)t * QKVW + CDIM + lane];
        const float vv = base[(size_t)t * QKVW + 2 * CDIM + lane]
                         * __powf(LAM, -(float)(t + 1));
        const u16 kb = f2bf(kv), vb = f2bf(vv);
        Kb[t * LSTR + lane] = kb;
        KT[lane * LSTR + t] = kb;
        Vb[t * LSTR + lane] = vb;
        VT[lane * LSTR + t] = vb;
    }
    __syncthreads();

    f32x4 accG[4] = {}, accH[4] = {};
    mm_strip2<false,false>(Kb, Kb, wr, ln, quad, accG);
    mm_strip2<false,false>(Kb, Vb, wr, ln, quad, accH);
    __syncthreads();

#pragma unroll
    for (int nt = 0; nt < 4; ++nt)
#pragma unroll
        for (int r = 0; r < 4; ++r) {
            const int row = wr + quad * 4 + r, col = nt * 16 + ln;
            const float g = accG[nt][r];
            const u16 nv = (col < row) ? f2bf(BP * g) : (u16)0;
            Np[row * LSTR + col] = nv;
            NT[col * LSTR + row] = nv;
            Yb[row * LSTR + col] = (row == col) ? f2bf(1.0f)
                                 : ((col < row) ? f2bf(-BP * g) : (u16)0);
            HbT[col * LSTR + row] = (col < row) ? f2bf(accH[nt][r]) : (u16)0;
        }
    __syncthreads();

    for (int j = 0; j < 5; ++j) {
        f32x4 sq[4] = {};
        mm_strip2<false,false>(Np, NT, wr, ln, quad, sq);
        __syncthreads();
#pragma unroll
        for (int nt = 0; nt < 4; ++nt)
#pragma unroll
            for (int r = 0; r < 4; ++r) {
                const int row = wr + quad * 4 + r, col = nt * 16 + ln;
                const u16 v = f2bf(sq[nt][r]);
                Np[row * LSTR + col] = v;
                NT[col * LSTR + row] = v;
            }
        __syncthreads();
        f32x4 ya[4];
#pragma unroll
        for (int nt = 0; nt < 4; ++nt)
#pragma unroll
            for (int r = 0; r < 4; ++r)
                ya[nt][r] = bf2f(Yb[(wr + quad * 4 + r) * LSTR + nt * 16 + ln]);
        mm_strip2<false,false>(Yb, NT, wr, ln, quad, ya);
#pragma unroll
        for (int nt = 0; nt < 4; ++nt)
#pragma unroll
            for (int r = 0; r < 4; ++r)
                Yb[(wr + quad * 4 + r) * LSTR + nt * 16 + ln] = f2bf(ya[nt][r]);
    }

    float* Ug = ws + OFF_U + (size_t)cc * 4096;
    float* Cg = ws + OFF_C + (size_t)cc * 4096;

    // W = Y*K (bf16 export only; chunkC stages it from wbg)
    f32x4 wv[4] = {};
    mm_strip2<false,false>(Yb, KT, wr, ln, quad, wv);

    // M1 = Y*H_SL -> Np (own rows)
    f32x4 m1[4] = {};
    mm_strip2<false,false>(Yb, HbT, wr, ln, quad, m1);
#pragma unroll
    for (int nt = 0; nt < 4; ++nt)
#pragma unroll
        for (int r = 0; r < 4; ++r)
            Np[(wr + quad * 4 + r) * LSTR + nt * 16 + ln] = f2bf(m1[nt][r]);

    // Y dead -> overwrite own rows with bf16 W (for export)
#pragma unroll
    for (int nt = 0; nt < 4; ++nt)
#pragma unroll
        for (int r = 0; r < 4; ++r)
            Yb[(wr + quad * 4 + r) * LSTR + nt * 16 + ln] = f2bf(wv[nt][r]);

    // U = M1*K -> global + UT
    f32x4 uv[4] = {};
    mm_strip2<false,false>(Np, KT, wr, ln, quad, uv);
#pragma unroll
    for (int nt = 0; nt < 4; ++nt)
#pragma unroll
        for (int r = 0; r < 4; ++r)
            Ug[(wr + quad * 4 + r) * 64 + nt * 16 + ln] = uv[nt][r];
    __syncthreads();
#pragma unroll
    for (int nt = 0; nt < 4; ++nt)
#pragma unroll
        for (int r = 0; r < 4; ++r)
            UT[(nt * 16 + ln) * LSTR + wr + quad * 4 + r] = f2bf(uv[nt][r]);
    __syncthreads();

    // C = Vt^T K - b' K^T U  -> permuted (lane-contiguous) layout for chunkB
    f32x4 c1[4] = {}, c2[4] = {};
    mm_strip2<false,false>(VT, KT, wr, ln, quad, c1);
    mm_strip2<false,false>(KT, UT, wr, ln, quad, c2);
#pragma unroll
    for (int nt = 0; nt < 4; ++nt) {
        const f32x4 cv = c1[nt] - BP * c2[nt];
        *(f32x4*)&Cg[(size_t)(w * 64 + lane) * 16 + nt * 4] = cv;
    }

    // export bf16 swizzled W and K^T
    for (int e = tid; e < 512; e += 256) {
        const int t = e >> 3, g = e & 7;
        *(bf16x8*)&wbg[(size_t)cc * 4096 + t * 64 + ((g ^ (t & 7)) << 3)] =
            *(const bf16x8*)&Yb[t * LSTR + (g << 3)];
    }
    for (int e = tid; e < 512; e += 256) {
        const int d = e >> 3, g = e & 7;
        *(bf16x8*)&ktg[(size_t)cc * 4096 + d * 64 + ((g ^ (d & 7)) << 3)] =
            *(const bf16x8*)&KT[d * LSTR + (g << 3)];
    }
}

// ---------------- Kernel B (MFMA): sequential 16-chunk sweep per bh -----
// R' = lam64*(R - b' K^T (W R) + C). R fp32 in registers. Exports per-chunk
// incoming state as bf16 swizzled R0^T ([x][d'], flat stride 64) for chunkC.
__global__ __launch_bounds__(256)
void chunkB(float* __restrict__ ws, const u16* __restrict__ wbg,
            const u16* __restrict__ ktg) {
    __shared__ u16 WBs[2][4096], KTs[2][4096];
    __shared__ u16 RTb[64 * LSTR], PTb[64 * LSTR];

    const int bh = blockIdx.x;
    const int tid = threadIdx.x;
    const int w = tid >> 6, lane = tid & 63;
    const int ln = lane & 15, quad = lane >> 4;
    const int wr = w * 16;
    const float lam64 = __powf(LAM, 64.0f);
    u16* r0tg = (u16*)(ws + OFF_R0);

    f32x4 R[4] = {};   // rows d = wr+quad*4+r, cols x = nt*16+ln

    for (int e = tid; e < 64 * LSTR; e += 256) RTb[e] = 0;

    const int off = w * 1024;   // wave's 16-row segment in u16
    {
        const size_t b0 = (size_t)(bh * 16) * 4096;
#pragma unroll
        for (int i = 0; i < 2; ++i) {
            gll16(wbg + b0 + off + i * 512 + lane * 8, &WBs[0][off + i * 512]);
            gll16(ktg + b0 + off + i * 512 + lane * 8, &KTs[0][off + i * 512]);
        }
    }
    __syncthreads();

    for (int c = 0; c < NC; ++c) {
        const int buf = c & 1;
        const size_t cc = (size_t)(bh * 16 + c);

        if (c + 1 < NC) {
            const size_t b1 = (cc + 1) * 4096;
#pragma unroll
            for (int i = 0; i < 2; ++i) {
                gll16(wbg + b1 + off + i * 512 + lane * 8, &WBs[buf ^ 1][off + i * 512]);
                gll16(ktg + b1 + off + i * 512 + lane * 8, &KTs[buf ^ 1][off + i * 512]);
            }
        }

        // P = W x R
        f32x4 p[4] = {};
        mm_strip2<true,false>(&WBs[buf][0], RTb, wr, ln, quad, p);
#pragma unroll
        for (int nt = 0; nt < 4; ++nt) {
            u16x4 pv;
            pv.x = f2bf(p[nt][0]); pv.y = f2bf(p[nt][1]);
            pv.z = f2bf(p[nt][2]); pv.w = f2bf(p[nt][3]);
            *(u16x4*)&PTb[(nt * 16 + ln) * LSTR + wr + quad * 4] = pv;
        }
        __syncthreads();

        // ka = K^T x P
        f32x4 kp[4] = {};
        mm_strip2<true,false>(&KTs[buf][0], PTb, wr, ln, quad, kp);

        u16* r0t = r0tg + cc * 4096;
        const float* Cg = ws + OFF_C + cc * 4096 + (size_t)(w * 64 + lane) * 16;
        const int swz = (wr + quad * 4) ^ ((ln & 7) * 8);
#pragma unroll
        for (int nt = 0; nt < 4; ++nt) {
            const int x = nt * 16 + ln;
            u16x4 rv;                          // R0 = pre-update state, transposed
            rv.x = f2bf(R[nt][0]); rv.y = f2bf(R[nt][1]);
            rv.z = f2bf(R[nt][2]); rv.w = f2bf(R[nt][3]);
            *(u16x4*)&r0t[x * 64 + swz] = rv;
            const f32x4 cv = *(const f32x4*)&Cg[nt * 4];
            R[nt] = lam64 * (R[nt] - BP * kp[nt] + cv);
            u16x4 nv;
            nv.x = f2bf(R[nt][0]); nv.y = f2bf(R[nt][1]);
            nv.z = f2bf(R[nt][2]); nv.w = f2bf(R[nt][3]);
            *(u16x4*)&RTb[x * LSTR + wr + quad * 4] = nv;
        }
        __syncthreads();
    }
}

// ---------------- Kernel C (MFMA): outputs per (bh,chunk) ---------------
// O = Qh R0 + TRIL(Qh Vt^T) K - b' TRIL(Qh K^T) (W R0 + U)
__global__ __launch_bounds__(256)
void chunkC(const float* __restrict__ qkv, float* __restrict__ ws,
            const u16* __restrict__ wbg, const u16* __restrict__ ktg,
            u16* __restrict__ ob) {
    __shared__ u16 Wb[4096], KTb[4096], R0Tb[4096];                 // flat swz
    __shared__ u16 Qhb[64 * LSTR], Kb[64 * LSTR], Vtb[64 * LSTR],
                   RmTb[64 * LSTR];
    u16* const A1m = Kb;    // Kb dead after M1 (barrier-protected)
    u16* const A2m = Vtb;   // Vtb dead after M2

    const int cc = blockIdx.x;
    const int bh = cc >> 4, c = cc & 15;
    const int b = bh / NH, h = bh - b * NH;
    const int tid = threadIdx.x;
    const int w = tid >> 6, lane = tid & 63;
    const int ln = lane & 15, quad = lane >> 4;
    const int wr = w * 16;
    const float* base = qkv + ((size_t)(b * T_ + c * CS)) * QKVW + h * HS;
    const u16* r0tg = (const u16*)(ws + OFF_R0);

    // async staging of producer-formatted operands
    const int off = w * 1024;
    {
        const size_t bb = (size_t)cc * 4096;
#pragma unroll
        for (int i = 0; i < 2; ++i) {
            gll16(wbg  + bb + off + i * 512 + lane * 8, &Wb[off + i * 512]);
            gll16(ktg  + bb + off + i * 512 + lane * 8, &KTb[off + i * 512]);
            gll16(r0tg + bb + off + i * 512 + lane * 8, &R0Tb[off + i * 512]);
        }
    }
    // VALU staging of Qh, K, Vt
#pragma unroll
    for (int p = 0; p < 16; ++p) {
        const int t = p * 4 + w;
        const float sc = __powf(LAM, (float)(t + 1));
        Qhb[t * LSTR + lane] = f2bf(base[(size_t)t * QKVW + lane] * sc);
        Kb[t * LSTR + lane]  = f2bf(base[(size_t)t * QKVW + CDIM + lane]);
        Vtb[t * LSTR + lane] = f2bf(base[(size_t)t * QKVW + 2 * CDIM + lane] / sc);
    }
    __syncthreads();

    f32x4 a1[4] = {}, a2[4] = {}, Oacc[4] = {}, wr0[4] = {};
    mm_strip2<false,false>(Qhb, Kb,   wr, ln, quad, a1);    // Qh K^T   rows t
    mm_strip2<false,false>(Qhb, Vtb,  wr, ln, quad, a2);    // Qh Vt^T  rows t
    mm_strip2<false,true >(Qhb, R0Tb, wr, ln, quad, Oacc);  // O1       rows t
    mm_strip2<true ,true >(Wb,  R0Tb, wr, ln, quad, wr0);   // W R0     rows s

    // Rm = W R0 + U (rows s own strip)
    const float* Ug = ws + OFF_U + (size_t)cc * 4096;
    const int row = wr + quad * 4;
#pragma unroll
    for (int nt = 0; nt < 4; ++nt) {
        const int col = nt * 16 + ln;
#pragma unroll
        for (int r = 0; r < 4; ++r)
            wr0[nt][r] += Ug[(size_t)(row + r) * 64 + col];
    }
    __syncthreads();   // all reads of Kb/Vtb done -> safe to overwrite

    // masked A1/A2 (own rows), Rm^T (transposed, cross-wave)
#pragma unroll
    for (int nt = 0; nt < 4; ++nt) {
        const int col = nt * 16 + ln;
#pragma unroll
        for (int r = 0; r < 4; ++r) {
            const int t = row + r;
            A1m[t * LSTR + col] = (col <= t) ? f2bf(a1[nt][r]) : (u16)0;
            A2m[t * LSTR + col] = (col <= t) ? f2bf(a2[nt][r]) : (u16)0;
        }
        u16x4 rm;
        rm.x = f2bf(wr0[nt][0]); rm.y = f2bf(wr0[nt][1]);
        rm.z = f2bf(wr0[nt][2]); rm.w = f2bf(wr0[nt][3]);
        *(u16x4*)&RmTb[col * LSTR + row] = rm;
    }
    __syncthreads();   // RmTb complete

    f32x4 O3[4] = {};
    mm_strip2<false,true >(A2m, KTb,  wr, ln, quad, Oacc);  // += TRIL(A2) K
    mm_strip2<false,false>(A1m, RmTb, wr, ln, quad, O3);    // TRIL(A1) Rm

#pragma unroll
    for (int nt = 0; nt < 4; ++nt) {
        const int col = nt * 16 + ln;
#pragma unroll
        for (int r = 0; r < 4; ++r) {
            const float o = Oacc[nt][r] - BP * O3[nt][r];
            ob[((size_t)(b * T_ + c * CS + row + r)) * CDIM + h * HS + col] = f2bf(o);
        }
    }
}

// ------------------------------ launch ----------------------------------
extern "C" void kernel_launch(void* const* d_in, const int* in_sizes, int n_in,
                              void* d_out, int out_size, void* d_ws, size_t ws_size,
                              hipStream_t stream) {
    const float* x      = (const float*)d_in[0];   // (4,1024,768)
    const float* w_attn = (const float*)d_in[1];   // (768, 2304)
    const float* w_proj = (const float*)d_in[2];   // (768, 768)
    float* out = (float*)d_out;
    float* ws  = (float*)d_ws;
    float* qkv = ws;
    u16* xb  = (u16*)(ws + OFF_XB);
    u16* waT = (u16*)(ws + OFF_WAT);
    u16* ob  = (u16*)(ws + OFF_C);
    u16* wpT = (u16*)ws;   // qkv region, cast after chunkC
    u16* wbg = (u16*)d_out;               // scratch: bf16 W  (swizzled)
    u16* ktg = (u16*)d_out + 768 * 4096;  // scratch: bf16 K^T (swizzled)

    // casts for gemm1
    cast_x_kernel<<<(MROWS * CDIM) / (256 * 4), 256, 0, stream>>>(x, xb);
    tcast_kernel<<<dim3(QKVW / 64, CDIM / 64), 256, 0, stream>>>(w_attn, waT, QKVW, CDIM);

    // 1) qkv = x @ w_attn   (bf16 MFMA)
    gemm_mfma<false><<<dim3(QKVW / 128, MROWS / 128), 256, 0, stream>>>(
        xb, waT, nullptr, qkv, QKVW, CDIM);

    // 2) standardization
    norm_kernel<<<(MROWS * 3 * NH) / 4, 256, 0, stream>>>(qkv);

    // 3) chunked WY scan (all MFMA)
    chunkA<<<768, 256, 0, stream>>>(qkv, ws, wbg, ktg);
    chunkB<<<48,  256, 0, stream>>>(ws, wbg, ktg);
    chunkC<<<768, 256, 0, stream>>>(qkv, ws, wbg, ktg, ob);

    // 4) y = o @ w_proj + x  (bf16 MFMA, residual fused, writes d_out)
    tcast_kernel<<<dim3(CDIM / 64, CDIM / 64), 256, 0, stream>>>(w_proj, wpT, CDIM, CDIM);
    gemm_mfma<true><<<dim3(CDIM / 128, MROWS / 128), 256, 0, stream>>>(
        ob, wpT, x, out, CDIM, CDIM);
}

// Round 10
// 223.055 us; speedup vs baseline: 3.9607x; 1.0456x over previous
//
#include <hip/hip_runtime.h>

typedef unsigned short u16;
typedef __attribute__((ext_vector_type(4))) unsigned short u16x4;
typedef __attribute__((ext_vector_type(8))) short bf16x8;
typedef __attribute__((ext_vector_type(4))) float f32x4;

#define B_ 4
#define T_ 1024
#define NH 12
#define HS 64
#define CDIM 768
#define QKVW 2304   // 3*CDIM
#define NC 16
#define CS 64
#define LAM 0.99f
#define BP  (0.01f/0.99f)
#define MROWS 4096
#define LSTR 72     // bf16 LDS row stride: 144B, 16B-aligned, 2-way banks (free)

// ws layout (float offsets)
#define OFF_W  9437184            // after qkv (4096*2304)
#define OFF_U  (OFF_W  + 768*4096)   // bf16 permuted U (u16, half-used)
#define OFF_C  (OFF_U  + 768*4096)
#define OFF_R0 (OFF_C  + 768*4096)   // bf16 swizzled R0^T (u16)
#define OFF_XB (OFF_W)                       // bf16 x, aliases W (dead region)
#define OFF_WAT (OFF_W + 1572864)            // bf16 w_attn^T, aliases W
// ob (bf16 o) aliases OFF_C; w_proj^T bf16 goes at ws[0] (qkv dead after chunkC)
// d_out doubles as scratch: wbg (bf16 W, swizzled) + ktg (bf16 K^T, swizzled)

__device__ __forceinline__ u16 f2bf(float f) {
    union { float f; unsigned u; } a; a.f = f;
    const unsigned r = a.u + 0x7FFF + ((a.u >> 16) & 1);
    return (u16)(r >> 16);
}
__device__ __forceinline__ float bf2f(u16 h) {
    union { unsigned u; float f; } a; a.u = ((unsigned)h) << 16; return a.f;
}
__device__ __forceinline__ u16x4 f2bf4(const f32x4 v) {
    u16x4 u; u.x = f2bf(v[0]); u.y = f2bf(v[1]); u.z = f2bf(v[2]); u.w = f2bf(v[3]);
    return u;
}

// ---------------- cast kernels ------------------------------------------
__global__ __launch_bounds__(256)
void cast_x_kernel(const float* __restrict__ src, u16* __restrict__ dst) {
    const size_t i = ((size_t)blockIdx.x * 256 + threadIdx.x) * 4;
    const float4 v = *(const float4*)(src + i);
    u16x4 u;
    u.x = f2bf(v.x); u.y = f2bf(v.y); u.z = f2bf(v.z); u.w = f2bf(v.w);
    *(u16x4*)(dst + i) = u;
}

// src [Rr][Cn] fp32  ->  dst [Cn][Rr] bf16. grid (Cn/64, Rr/64), 256 thr.
__global__ __launch_bounds__(256)
void tcast_kernel(const float* __restrict__ src, u16* __restrict__ dst,
                  int Cn, int Rr) {
    const int ln = threadIdx.x & 63, kg = threadIdx.x >> 6;
    const int n = blockIdx.x * 64 + ln;
    const int kb = blockIdx.y * 64 + kg * 16;
    u16 tmp[16];
#pragma unroll
    for (int j = 0; j < 16; ++j)
        tmp[j] = f2bf(src[(size_t)(kb + j) * Cn + n]);
#pragma unroll
    for (int j4 = 0; j4 < 4; ++j4) {
        u16x4 u; u.x = tmp[j4*4]; u.y = tmp[j4*4+1]; u.z = tmp[j4*4+2]; u.w = tmp[j4*4+3];
        *(u16x4*)&dst[(size_t)n * Rr + kb + j4*4] = u;
    }
}

// ---------------- MFMA GEMM: C[M,N] = A[M,K] @ Bt[N,K]^T (+R) -----------
__device__ __forceinline__ void gll16(const u16* g, u16* lds) {
    __builtin_amdgcn_global_load_lds(
        (const __attribute__((address_space(1))) unsigned*)g,
        (__attribute__((address_space(3))) unsigned*)lds, 16, 0, 0);
}

template<bool ADD_RES>
__global__ __launch_bounds__(256)
void gemm_mfma(const u16* __restrict__ A, const u16* __restrict__ Bt,
               const float* __restrict__ R, float* __restrict__ C,
               int N, int K) {
    __shared__ u16 As[128 * 64];
    __shared__ u16 Bs[128 * 64];
    const int tid  = threadIdx.x;
    const int wave = tid >> 6, lane = tid & 63;
    const int wm = wave >> 1, wn = wave & 1;
    const int ln = lane & 15, quad = lane >> 4;
    const int m0 = blockIdx.y * 128, n0 = blockIdx.x * 128;

    const int rl = lane >> 3;
    const int kx = ((lane & 7) ^ rl) * 8;
    const u16* Ag = A + (size_t)(m0 + wave * 32 + rl) * K + kx;
    const u16* Bg = Bt + (size_t)(n0 + wave * 32 + rl) * K + kx;
    u16* AsW = &As[(wave * 32) * 64];
    u16* BsW = &Bs[(wave * 32) * 64];

    f32x4 acc[4][4] = {};

    for (int k0 = 0; k0 < K; k0 += 64) {
        __syncthreads();
#pragma unroll
        for (int c8 = 0; c8 < 4; ++c8) {
            gll16(Ag + (size_t)(c8 * 8) * K + k0, AsW + c8 * 8 * 64);
            gll16(Bg + (size_t)(c8 * 8) * K + k0, BsW + c8 * 8 * 64);
        }
        __syncthreads();
#pragma unroll
        for (int k32 = 0; k32 < 64; k32 += 32) {
            const int ko = (k32 + quad * 8) ^ ((ln & 7) * 8);
            bf16x8 af[4], bfr[4];
#pragma unroll
            for (int mi = 0; mi < 4; ++mi)
                af[mi] = *(const bf16x8*)&As[(wm * 64 + mi * 16 + ln) * 64 + ko];
#pragma unroll
            for (int ni = 0; ni < 4; ++ni)
                bfr[ni] = *(const bf16x8*)&Bs[(wn * 64 + ni * 16 + ln) * 64 + ko];
#pragma unroll
            for (int mi = 0; mi < 4; ++mi)
#pragma unroll
                for (int ni = 0; ni < 4; ++ni)
                    acc[mi][ni] = __builtin_amdgcn_mfma_f32_16x16x32_bf16(
                        af[mi], bfr[ni], acc[mi][ni], 0, 0, 0);
        }
    }

#pragma unroll
    for (int mi = 0; mi < 4; ++mi) {
        const int rb = m0 + wm * 64 + mi * 16 + quad * 4;
#pragma unroll
        for (int ni = 0; ni < 4; ++ni) {
            const int col = n0 + wn * 64 + ni * 16 + ln;
#pragma unroll
            for (int r = 0; r < 4; ++r) {
                float v = acc[mi][ni][r];
                if (ADD_RES) v += R[(size_t)(rb + r) * N + col];
                C[(size_t)(rb + r) * N + col] = v;
            }
        }
    }
}

// -------- per-64-element standardization (mean / unbiased std) ----------
__global__ __launch_bounds__(256)
void norm_kernel(float* __restrict__ qkv) {
    const int g    = blockIdx.x * 4 + (threadIdx.x >> 6);
    const int lane = threadIdx.x & 63;
    const size_t idx = (size_t)g * 64 + lane;
    const float v = qkv[idx];
    float s = v, ss = v * v;
#pragma unroll
    for (int off = 1; off < 64; off <<= 1) {
        s  += __shfl_xor(s,  off, 64);
        ss += __shfl_xor(ss, off, 64);
    }
    const float mu  = s * (1.0f / 64.0f);
    const float var = (ss - 64.0f * mu * mu) * (1.0f / 63.0f);
    const float rs  = rsqrtf(var);
    qkv[idx] = (v - mu) * rs;
}

// ---------------- MFMA strip microkernel --------------------------------
// acc[nt] += A[strip rows][k] x B[nt*16..][k]^T (contract k over 64).
template<bool ASWZ, bool BSWZ>
__device__ __forceinline__ void mm_strip2(const u16* A, const u16* Bq,
                                          int wr, int ln, int quad, f32x4 (&acc)[4]) {
#pragma unroll
    for (int k0 = 0; k0 < 64; k0 += 32) {
        const int kq = k0 + quad * 8;
        const int ks = kq ^ ((ln & 7) * 8);
        const bf16x8 a = ASWZ ? *(const bf16x8*)&A[(wr + ln) * 64 + ks]
                              : *(const bf16x8*)&A[(wr + ln) * LSTR + kq];
#pragma unroll
        for (int nt = 0; nt < 4; ++nt) {
            const bf16x8 b = BSWZ ? *(const bf16x8*)&Bq[(nt * 16 + ln) * 64 + ks]
                                  : *(const bf16x8*)&Bq[(nt * 16 + ln) * LSTR + kq];
            acc[nt] = __builtin_amdgcn_mfma_f32_16x16x32_bf16(a, b, acc[nt], 0, 0, 0);
        }
    }
}

// ---------------- Kernel A (MFMA): per-(bh,chunk) W, U, C ---------------
// T = (I+N)^{-1} ~= (I-N)(I+N^2)(I+N^4)(I+N^8)  [exact through N^15;
// sigma(N^16) ~ 1e-5 << bf16 eps]. Exports bf16 swizzled W / K^T, bf16
// permuted U, fp32 permuted C.
__global__ __launch_bounds__(256)
void chunkA(const float* __restrict__ qkv, float* __restrict__ ws,
            u16* __restrict__ wbg, u16* __restrict__ ktg) {
    __shared__ u16 Kb[64 * LSTR], Vb[64 * LSTR], KT[64 * LSTR],
                   VT[64 * LSTR], NT[64 * LSTR], HbT[64 * LSTR];
    u16* const Yb = Kb;   // Kb dead after G/H
    u16* const Np = Vb;   // Vb dead likewise; later M1
    u16* const UT = NT;   // NT dead after chain

    const int cc = blockIdx.x;
    const int bh = cc >> 4, c = cc & 15;
    const int b = bh / NH, h = bh - b * NH;
    const int tid = threadIdx.x;
    const int w = tid >> 6, lane = tid & 63;
    const int ln = lane & 15, quad = lane >> 4;
    const int wr = w * 16;
    const float* base = qkv + ((size_t)(b * T_ + c * CS)) * QKVW + h * HS;

    // ---- staging: 4 rows/pass/wave; float4 loads, u16x4 row writes,
    //      scalar transposed writes. No powf in the loop.
    {
        const int tr0 = w * 4 + quad;          // row for p=0
        const int d0 = ln * 4;
        float vsc = __powf(LAM, -(float)(tr0 + 1));
        const float v16 = __powf(LAM, -16.0f);
#pragma unroll
        for (int p = 0; p < 4; ++p) {
            const int t = p * 16 + tr0;
            const float4 kv = *(const float4*)(base + (size_t)t * QKVW + CDIM + d0);
            const float4 vv = *(const float4*)(base + (size_t)t * QKVW + 2 * CDIM + d0);
            u16x4 k4; k4.x = f2bf(kv.x); k4.y = f2bf(kv.y); k4.z = f2bf(kv.z); k4.w = f2bf(kv.w);
            u16x4 v4; v4.x = f2bf(vv.x * vsc); v4.y = f2bf(vv.y * vsc);
            v4.z = f2bf(vv.z * vsc); v4.w = f2bf(vv.w * vsc);
            *(u16x4*)&Kb[t * LSTR + d0] = k4;
            *(u16x4*)&Vb[t * LSTR + d0] = v4;
            KT[(d0 + 0) * LSTR + t] = k4.x; KT[(d0 + 1) * LSTR + t] = k4.y;
            KT[(d0 + 2) * LSTR + t] = k4.z; KT[(d0 + 3) * LSTR + t] = k4.w;
            VT[(d0 + 0) * LSTR + t] = v4.x; VT[(d0 + 1) * LSTR + t] = v4.y;
            VT[(d0 + 2) * LSTR + t] = v4.z; VT[(d0 + 3) * LSTR + t] = v4.w;
            vsc *= v16;
        }
    }
    __syncthreads();

    f32x4 accG[4] = {}, accH[4] = {};
    mm_strip2<false,false>(Kb, Kb, wr, ln, quad, accG);   // G = K K^T
    mm_strip2<false,false>(Kb, Vb, wr, ln, quad, accH);   // H = K Vt^T
    __syncthreads();

#pragma unroll
    for (int nt = 0; nt < 4; ++nt) {
        const int col = nt * 16 + ln;
        u16x4 nvT, hvT;
#pragma unroll
        for (int r = 0; r < 4; ++r) {
            const int row = wr + quad * 4 + r;
            const float g = accG[nt][r];
            const u16 nv = (col < row) ? f2bf(BP * g) : (u16)0;
            Np[row * LSTR + col] = nv;
            Yb[row * LSTR + col] = (row == col) ? f2bf(1.0f)
                                 : ((col < row) ? f2bf(-BP * g) : (u16)0);
            ((u16*)&nvT)[r] = nv;
            ((u16*)&hvT)[r] = (col < row) ? f2bf(accH[nt][r]) : (u16)0;
        }
        *(u16x4*)&NT[col * LSTR + wr + quad * 4] = nvT;
        *(u16x4*)&HbT[col * LSTR + wr + quad * 4] = hvT;
    }
    __syncthreads();

    // ---- Neumann chain (3 iterations)
    for (int j = 0; j < 3; ++j) {
        f32x4 sq[4] = {};
        mm_strip2<false,false>(Np, NT, wr, ln, quad, sq);
        __syncthreads();
#pragma unroll
        for (int nt = 0; nt < 4; ++nt) {
            const int col = nt * 16 + ln;
            u16x4 sv;
#pragma unroll
            for (int r = 0; r < 4; ++r) {
                const u16 v = f2bf(sq[nt][r]);
                Np[(wr + quad * 4 + r) * LSTR + col] = v;
                ((u16*)&sv)[r] = v;
            }
            *(u16x4*)&NT[col * LSTR + wr + quad * 4] = sv;
        }
        __syncthreads();
        f32x4 ya[4];
#pragma unroll
        for (int nt = 0; nt < 4; ++nt)
#pragma unroll
            for (int r = 0; r < 4; ++r)
                ya[nt][r] = bf2f(Yb[(wr + quad * 4 + r) * LSTR + nt * 16 + ln]);
        mm_strip2<false,false>(Yb, NT, wr, ln, quad, ya);   // Y += Y*Np
#pragma unroll
        for (int nt = 0; nt < 4; ++nt)
#pragma unroll
            for (int r = 0; r < 4; ++r)
                Yb[(wr + quad * 4 + r) * LSTR + nt * 16 + ln] = f2bf(ya[nt][r]);
    }

    u16* Ugp = (u16*)(ws + OFF_U) + (size_t)cc * 4096;
    float* Cg = ws + OFF_C + (size_t)cc * 4096;

    // W = Y*K
    f32x4 wv[4] = {};
    mm_strip2<false,false>(Yb, KT, wr, ln, quad, wv);

    // M1 = Y*H_SL -> Np (own rows)
    f32x4 m1[4] = {};
    mm_strip2<false,false>(Yb, HbT, wr, ln, quad, m1);
#pragma unroll
    for (int nt = 0; nt < 4; ++nt)
#pragma unroll
        for (int r = 0; r < 4; ++r)
            Np[(wr + quad * 4 + r) * LSTR + nt * 16 + ln] = f2bf(m1[nt][r]);

    // Y dead -> overwrite own rows with bf16 W (export source)
#pragma unroll
    for (int nt = 0; nt < 4; ++nt)
#pragma unroll
        for (int r = 0; r < 4; ++r)
            Yb[(wr + quad * 4 + r) * LSTR + nt * 16 + ln] = f2bf(wv[nt][r]);

    // U = M1*K -> permuted bf16 global + UT
    f32x4 uv[4] = {};
    mm_strip2<false,false>(Np, KT, wr, ln, quad, uv);
#pragma unroll
    for (int nt = 0; nt < 4; ++nt)
        *(u16x4*)&Ugp[(size_t)(w * 64 + lane) * 16 + nt * 4] = f2bf4(uv[nt]);
    __syncthreads();   // all waves past last NT (chain) reads
#pragma unroll
    for (int nt = 0; nt < 4; ++nt)
        *(u16x4*)&UT[(nt * 16 + ln) * LSTR + wr + quad * 4] = f2bf4(uv[nt]);
    __syncthreads();

    // C = Vt^T K - b' K^T U  -> permuted fp32 (for chunkB)
    f32x4 c1[4] = {}, c2[4] = {};
    mm_strip2<false,false>(VT, KT, wr, ln, quad, c1);
    mm_strip2<false,false>(KT, UT, wr, ln, quad, c2);
#pragma unroll
    for (int nt = 0; nt < 4; ++nt) {
        const f32x4 cv = c1[nt] - BP * c2[nt];
        *(f32x4*)&Cg[(size_t)(w * 64 + lane) * 16 + nt * 4] = cv;
    }

    // export bf16 swizzled W and K^T
    for (int e = tid; e < 512; e += 256) {
        const int t = e >> 3, g = e & 7;
        *(bf16x8*)&wbg[(size_t)cc * 4096 + t * 64 + ((g ^ (t & 7)) << 3)] =
            *(const bf16x8*)&Yb[t * LSTR + (g << 3)];
    }
    for (int e = tid; e < 512; e += 256) {
        const int d = e >> 3, g = e & 7;
        *(bf16x8*)&ktg[(size_t)cc * 4096 + d * 64 + ((g ^ (d & 7)) << 3)] =
            *(const bf16x8*)&KT[d * LSTR + (g << 3)];
    }
}

// ---------------- Kernel B (MFMA): sequential 16-chunk sweep per bh -----
__global__ __launch_bounds__(256)
void chunkB(float* __restrict__ ws, const u16* __restrict__ wbg,
            const u16* __restrict__ ktg) {
    __shared__ u16 WBs[2][4096], KTs[2][4096];
    __shared__ u16 RTb[64 * LSTR], PTb[64 * LSTR];

    const int bh = blockIdx.x;
    const int tid = threadIdx.x;
    const int w = tid >> 6, lane = tid & 63;
    const int ln = lane & 15, quad = lane >> 4;
    const int wr = w * 16;
    const float lam64 = __powf(LAM, 64.0f);
    u16* r0tg = (u16*)(ws + OFF_R0);

    f32x4 R[4] = {};

    for (int e = tid; e < 64 * LSTR; e += 256) RTb[e] = 0;

    const int off = w * 1024;
    {
        const size_t b0 = (size_t)(bh * 16) * 4096;
#pragma unroll
        for (int i = 0; i < 2; ++i) {
            gll16(wbg + b0 + off + i * 512 + lane * 8, &WBs[0][off + i * 512]);
            gll16(ktg + b0 + off + i * 512 + lane * 8, &KTs[0][off + i * 512]);
        }
    }
    __syncthreads();

    for (int c = 0; c < NC; ++c) {
        const int buf = c & 1;
        const size_t cc = (size_t)(bh * 16 + c);

        if (c + 1 < NC) {
            const size_t b1 = (cc + 1) * 4096;
#pragma unroll
            for (int i = 0; i < 2; ++i) {
                gll16(wbg + b1 + off + i * 512 + lane * 8, &WBs[buf ^ 1][off + i * 512]);
                gll16(ktg + b1 + off + i * 512 + lane * 8, &KTs[buf ^ 1][off + i * 512]);
            }
        }

        // P = W x R
        f32x4 p[4] = {};
        mm_strip2<true,false>(&WBs[buf][0], RTb, wr, ln, quad, p);
#pragma unroll
        for (int nt = 0; nt < 4; ++nt)
            *(u16x4*)&PTb[(nt * 16 + ln) * LSTR + wr + quad * 4] = f2bf4(p[nt]);
        __syncthreads();

        // ka = K^T x P
        f32x4 kp[4] = {};
        mm_strip2<true,false>(&KTs[buf][0], PTb, wr, ln, quad, kp);

        u16* r0t = r0tg + cc * 4096;
        const float* Cg = ws + OFF_C + cc * 4096 + (size_t)(w * 64 + lane) * 16;
        const int swz = (wr + quad * 4) ^ ((ln & 7) * 8);
#pragma unroll
        for (int nt = 0; nt < 4; ++nt) {
            const int x = nt * 16 + ln;
            *(u16x4*)&r0t[x * 64 + swz] = f2bf4(R[nt]);     // pre-update R0^T
            const f32x4 cv = *(const f32x4*)&Cg[nt * 4];
            R[nt] = lam64 * (R[nt] - BP * kp[nt] + cv);
            *(u16x4*)&RTb[x * LSTR + wr + quad * 4] = f2bf4(R[nt]);
        }
        __syncthreads();
    }
}

// ---------------- Kernel C (MFMA): outputs per (bh,chunk) ---------------
// O = Qh R0 + TRIL(Qh Vt^T) K - b' TRIL(Qh K^T) (W R0 + U)
__global__ __launch_bounds__(256)
void chunkC(const float* __restrict__ qkv, float* __restrict__ ws,
            const u16* __restrict__ wbg, const u16* __restrict__ ktg,
            u16* __restrict__ ob) {
    __shared__ u16 Wb[4096], KTb[4096], R0Tb[4096];
    __shared__ u16 Qhb[64 * LSTR], Kb[64 * LSTR], Vtb[64 * LSTR],
                   RmTb[64 * LSTR];
    u16* const A1m = Kb;
    u16* const A2m = Vtb;

    const int cc = blockIdx.x;
    const int bh = cc >> 4, c = cc & 15;
    const int b = bh / NH, h = bh - b * NH;
    const int tid = threadIdx.x;
    const int w = tid >> 6, lane = tid & 63;
    const int ln = lane & 15, quad = lane >> 4;
    const int wr = w * 16;
    const float* base = qkv + ((size_t)(b * T_ + c * CS)) * QKVW + h * HS;
    const u16* r0tg = (const u16*)(ws + OFF_R0);

    const int off = w * 1024;
    {
        const size_t bb = (size_t)cc * 4096;
#pragma unroll
        for (int i = 0; i < 2; ++i) {
            gll16(wbg  + bb + off + i * 512 + lane * 8, &Wb[off + i * 512]);
            gll16(ktg  + bb + off + i * 512 + lane * 8, &KTb[off + i * 512]);
            gll16(r0tg + bb + off + i * 512 + lane * 8, &R0Tb[off + i * 512]);
        }
    }
    // VALU staging of Qh, K, Vt: float4 loads, u16x4 writes, no powf loop
    {
        const int tr0 = w * 4 + quad;
        const int d0 = ln * 4;
        float qsc = __powf(LAM, (float)(tr0 + 1));
        float vsc = 1.0f / qsc;
        const float q16 = __powf(LAM, 16.0f);
        const float v16 = 1.0f / q16;
#pragma unroll
        for (int p = 0; p < 4; ++p) {
            const int t = p * 16 + tr0;
            const float4 qv = *(const float4*)(base + (size_t)t * QKVW + d0);
            const float4 kv = *(const float4*)(base + (size_t)t * QKVW + CDIM + d0);
            const float4 vv = *(const float4*)(base + (size_t)t * QKVW + 2 * CDIM + d0);
            u16x4 q4; q4.x = f2bf(qv.x * qsc); q4.y = f2bf(qv.y * qsc);
            q4.z = f2bf(qv.z * qsc); q4.w = f2bf(qv.w * qsc);
            u16x4 k4; k4.x = f2bf(kv.x); k4.y = f2bf(kv.y);
            k4.z = f2bf(kv.z); k4.w = f2bf(kv.w);
            u16x4 v4; v4.x = f2bf(vv.x * vsc); v4.y = f2bf(vv.y * vsc);
            v4.z = f2bf(vv.z * vsc); v4.w = f2bf(vv.w * vsc);
            *(u16x4*)&Qhb[t * LSTR + d0] = q4;
            *(u16x4*)&Kb[t * LSTR + d0] = k4;
            *(u16x4*)&Vtb[t * LSTR + d0] = v4;
            qsc *= q16; vsc *= v16;
        }
    }
    __syncthreads();

    f32x4 a1[4] = {}, a2[4] = {}, Oacc[4] = {}, wr0[4] = {};
    mm_strip2<false,false>(Qhb, Kb,   wr, ln, quad, a1);    // Qh K^T
    mm_strip2<false,false>(Qhb, Vtb,  wr, ln, quad, a2);    // Qh Vt^T
    mm_strip2<false,true >(Qhb, R0Tb, wr, ln, quad, Oacc);  // O1
    mm_strip2<true ,true >(Wb,  R0Tb, wr, ln, quad, wr0);   // W R0

    // Rm = W R0 + U (permuted bf16 U)
    const u16* Ugp = (const u16*)(ws + OFF_U) + (size_t)cc * 4096
                     + (size_t)(w * 64 + lane) * 16;
    const int row = wr + quad * 4;
#pragma unroll
    for (int nt = 0; nt < 4; ++nt) {
        const u16x4 uu = *(const u16x4*)&Ugp[nt * 4];
        wr0[nt][0] += bf2f(uu.x); wr0[nt][1] += bf2f(uu.y);
        wr0[nt][2] += bf2f(uu.z); wr0[nt][3] += bf2f(uu.w);
    }
    __syncthreads();   // Kb/Vtb reads done -> safe to overwrite

    // masked A1/A2 (own rows), Rm^T
#pragma unroll
    for (int nt = 0; nt < 4; ++nt) {
        const int col = nt * 16 + ln;
#pragma unroll
        for (int r = 0; r < 4; ++r) {
            const int t = row + r;
            A1m[t * LSTR + col] = (col <= t) ? f2bf(a1[nt][r]) : (u16)0;
            A2m[t * LSTR + col] = (col <= t) ? f2bf(a2[nt][r]) : (u16)0;
        }
        *(u16x4*)&RmTb[col * LSTR + row] = f2bf4(wr0[nt]);
    }
    __syncthreads();

    f32x4 O3[4] = {};
    mm_strip2<false,true >(A2m, KTb,  wr, ln, quad, Oacc);  // += TRIL(A2) K
    mm_strip2<false,false>(A1m, RmTb, wr, ln, quad, O3);    // TRIL(A1) Rm

#pragma unroll
    for (int nt = 0; nt < 4; ++nt) {
        const int col = nt * 16 + ln;
#pragma unroll
        for (int r = 0; r < 4; ++r) {
            const float o = Oacc[nt][r] - BP * O3[nt][r];
            ob[((size_t)(b * T_ + c * CS + row + r)) * CDIM + h * HS + col] = f2bf(o);
        }
    }
}

// ------------------------------ launch ----------------------------------
extern "C" void kernel_launch(void* const* d_in, const int* in_sizes, int n_in,
                              void* d_out, int out_size, void* d_ws, size_t ws_size,
                              hipStream_t stream) {
    const float* x      = (const float*)d_in[0];   // (4,1024,768)
    const float* w_attn = (const float*)d_in[1];   // (768, 2304)
    const float* w_proj = (const float*)d_in[2];   // (768, 768)
    float* out = (float*)d_out;
    float* ws  = (float*)d_ws;
    float* qkv = ws;
    u16* xb  = (u16*)(ws + OFF_XB);
    u16* waT = (u16*)(ws + OFF_WAT);
    u16* ob  = (u16*)(ws + OFF_C);
    u16* wpT = (u16*)ws;   // qkv region, cast after chunkC
    u16* wbg = (u16*)d_out;               // scratch: bf16 W  (swizzled)
    u16* ktg = (u16*)d_out + 768 * 4096;  // scratch: bf16 K^T (swizzled)

    // casts for gemm1
    cast_x_kernel<<<(MROWS * CDIM) / (256 * 4), 256, 0, stream>>>(x, xb);
    tcast_kernel<<<dim3(QKVW / 64, CDIM / 64), 256, 0, stream>>>(w_attn, waT, QKVW, CDIM);

    // 1) qkv = x @ w_attn   (bf16 MFMA)
    gemm_mfma<false><<<dim3(QKVW / 128, MROWS / 128), 256, 0, stream>>>(
        xb, waT, nullptr, qkv, QKVW, CDIM);

    // 2) standardization
    norm_kernel<<<(MROWS * 3 * NH) / 4, 256, 0, stream>>>(qkv);

    // 3) chunked WY scan (all MFMA)
    chunkA<<<768, 256, 0, stream>>>(qkv, ws, wbg, ktg);
    chunkB<<<48,  256, 0, stream>>>(ws, wbg, ktg);
    chunkC<<<768, 256, 0, stream>>>(qkv, ws, wbg, ktg, ob);

    // 4) y = o @ w_proj + x  (bf16 MFMA, residual fused, writes d_out)
    tcast_kernel<<<dim3(CDIM / 64, CDIM / 64), 256, 0, stream>>>(w_proj, wpT, CDIM, CDIM);
    gemm_mfma<true><<<dim3(CDIM / 128, MROWS / 128), 256, 0, stream>>>(
        ob, wpT, x, out, CDIM, CDIM);
}

// Round 11
// 187.530 us; speedup vs baseline: 4.7110x; 1.1894x over previous
//
#include <hip/hip_runtime.h>

typedef unsigned short u16;
typedef __attribute__((ext_vector_type(4))) unsigned short u16x4;
typedef __attribute__((ext_vector_type(8))) short bf16x8;
typedef __attribute__((ext_vector_type(4))) float f32x4;

#define B_ 4
#define T_ 1024
#define NH 12
#define HS 64
#define CDIM 768
#define QKVW 2304   // 3*CDIM
#define NC 16
#define CS 64
#define LAM 0.99f
#define BP  (0.01f/0.99f)
#define MROWS 4096
#define LSTR 72     // bf16 LDS row stride: 144B, 16B-aligned, 2-way banks (free)

// ws layout (float offsets). qkv is now bf16 (u16) at ws[0].
#define OFF_W  9437184            // scratch region after (old) qkv span
#define OFF_U  (OFF_W  + 768*4096)   // bf16 permuted U (u16, half-used)
#define OFF_C  (OFF_U  + 768*4096)   // fp32 permuted C; later bf16 ob
#define OFF_R0 (OFF_C  + 768*4096)   // bf16 swizzled R0^T (u16)
#define OFF_XB (OFF_W)                       // bf16 x
#define OFF_WAT (OFF_W + 1572864)            // bf16 w_attn^T
// d_out doubles as scratch: wbg (bf16 W, swizzled) + ktg (bf16 K^T, swizzled)

__device__ __forceinline__ u16 f2bf(float f) {
    union { float f; unsigned u; } a; a.f = f;
    const unsigned r = a.u + 0x7FFF + ((a.u >> 16) & 1);
    return (u16)(r >> 16);
}
__device__ __forceinline__ float bf2f(u16 h) {
    union { unsigned u; float f; } a; a.u = ((unsigned)h) << 16; return a.f;
}
__device__ __forceinline__ u16x4 f2bf4(const f32x4 v) {
    u16x4 u; u.x = f2bf(v[0]); u.y = f2bf(v[1]); u.z = f2bf(v[2]); u.w = f2bf(v[3]);
    return u;
}

// ---------------- cast kernels ------------------------------------------
__global__ __launch_bounds__(256)
void cast_x_kernel(const float* __restrict__ src, u16* __restrict__ dst) {
    const size_t i = ((size_t)blockIdx.x * 256 + threadIdx.x) * 4;
    const float4 v = *(const float4*)(src + i);
    u16x4 u;
    u.x = f2bf(v.x); u.y = f2bf(v.y); u.z = f2bf(v.z); u.w = f2bf(v.w);
    *(u16x4*)(dst + i) = u;
}

// src [Rr][Cn] fp32  ->  dst [Cn][Rr] bf16. grid (Cn/64, Rr/64), 256 thr.
__global__ __launch_bounds__(256)
void tcast_kernel(const float* __restrict__ src, u16* __restrict__ dst,
                  int Cn, int Rr) {
    const int ln = threadIdx.x & 63, kg = threadIdx.x >> 6;
    const int n = blockIdx.x * 64 + ln;
    const int kb = blockIdx.y * 64 + kg * 16;
    u16 tmp[16];
#pragma unroll
    for (int j = 0; j < 16; ++j)
        tmp[j] = f2bf(src[(size_t)(kb + j) * Cn + n]);
#pragma unroll
    for (int j4 = 0; j4 < 4; ++j4) {
        u16x4 u; u.x = tmp[j4*4]; u.y = tmp[j4*4+1]; u.z = tmp[j4*4+2]; u.w = tmp[j4*4+3];
        *(u16x4*)&dst[(size_t)n * Rr + kb + j4*4] = u;
    }
}

// ---------------- MFMA GEMM: C[M,N] = A[M,K] @ Bt[N,K]^T ----------------
// NORM: per-64-col-group standardization in the epilogue (group == wave's
// col span), output bf16. Else: fp32 out (+residual R).
__device__ __forceinline__ void gll16(const u16* g, u16* lds) {
    __builtin_amdgcn_global_load_lds(
        (const __attribute__((address_space(1))) unsigned*)g,
        (__attribute__((address_space(3))) unsigned*)lds, 16, 0, 0);
}

template<bool ADD_RES, bool NORM>
__global__ __launch_bounds__(256)
void gemm_mfma(const u16* __restrict__ A, const u16* __restrict__ Bt,
               const float* __restrict__ R, void* __restrict__ Cout,
               int N, int K) {
    __shared__ u16 As[128 * 64];
    __shared__ u16 Bs[128 * 64];
    const int tid  = threadIdx.x;
    const int wave = tid >> 6, lane = tid & 63;
    const int wm = wave >> 1, wn = wave & 1;
    const int ln = lane & 15, quad = lane >> 4;
    const int m0 = blockIdx.y * 128, n0 = blockIdx.x * 128;

    const int rl = lane >> 3;
    const int kx = ((lane & 7) ^ rl) * 8;
    const u16* Ag = A + (size_t)(m0 + wave * 32 + rl) * K + kx;
    const u16* Bg = Bt + (size_t)(n0 + wave * 32 + rl) * K + kx;
    u16* AsW = &As[(wave * 32) * 64];
    u16* BsW = &Bs[(wave * 32) * 64];

    f32x4 acc[4][4] = {};

    for (int k0 = 0; k0 < K; k0 += 64) {
        __syncthreads();
#pragma unroll
        for (int c8 = 0; c8 < 4; ++c8) {
            gll16(Ag + (size_t)(c8 * 8) * K + k0, AsW + c8 * 8 * 64);
            gll16(Bg + (size_t)(c8 * 8) * K + k0, BsW + c8 * 8 * 64);
        }
        __syncthreads();
#pragma unroll
        for (int k32 = 0; k32 < 64; k32 += 32) {
            const int ko = (k32 + quad * 8) ^ ((ln & 7) * 8);
            bf16x8 af[4], bfr[4];
#pragma unroll
            for (int mi = 0; mi < 4; ++mi)
                af[mi] = *(const bf16x8*)&As[(wm * 64 + mi * 16 + ln) * 64 + ko];
#pragma unroll
            for (int ni = 0; ni < 4; ++ni)
                bfr[ni] = *(const bf16x8*)&Bs[(wn * 64 + ni * 16 + ln) * 64 + ko];
#pragma unroll
            for (int mi = 0; mi < 4; ++mi)
#pragma unroll
                for (int ni = 0; ni < 4; ++ni)
                    acc[mi][ni] = __builtin_amdgcn_mfma_f32_16x16x32_bf16(
                        af[mi], bfr[ni], acc[mi][ni], 0, 0, 0);
        }
    }

#pragma unroll
    for (int mi = 0; mi < 4; ++mi) {
        const int rb = m0 + wm * 64 + mi * 16 + quad * 4;
#pragma unroll
        for (int r = 0; r < 4; ++r) {
            if (NORM) {
                // wave's 4 ni-values x 16 lanes == one 64-elem norm group
                const float a0 = acc[mi][0][r], a1 = acc[mi][1][r];
                const float a2 = acc[mi][2][r], a3 = acc[mi][3][r];
                float s1 = a0 + a1 + a2 + a3;
                float s2 = a0*a0 + a1*a1 + a2*a2 + a3*a3;
#pragma unroll
                for (int m = 1; m < 16; m <<= 1) {
                    s1 += __shfl_xor(s1, m, 64);
                    s2 += __shfl_xor(s2, m, 64);
                }
                const float mu = s1 * (1.0f / 64.0f);
                const float rs = rsqrtf((s2 - 64.0f * mu * mu) * (1.0f / 63.0f));
                u16* op = (u16*)Cout + (size_t)(rb + r) * N + n0 + wn * 64 + ln;
                op[0]  = f2bf((a0 - mu) * rs);
                op[16] = f2bf((a1 - mu) * rs);
                op[32] = f2bf((a2 - mu) * rs);
                op[48] = f2bf((a3 - mu) * rs);
            } else {
#pragma unroll
                for (int ni = 0; ni < 4; ++ni) {
                    const int col = n0 + wn * 64 + ni * 16 + ln;
                    float v = acc[mi][ni][r];
                    if (ADD_RES) v += R[(size_t)(rb + r) * N + col];
                    ((float*)Cout)[(size_t)(rb + r) * N + col] = v;
                }
            }
        }
    }
}

// ---------------- MFMA strip microkernel --------------------------------
template<bool ASWZ, bool BSWZ>
__device__ __forceinline__ void mm_strip2(const u16* A, const u16* Bq,
                                          int wr, int ln, int quad, f32x4 (&acc)[4]) {
#pragma unroll
    for (int k0 = 0; k0 < 64; k0 += 32) {
        const int kq = k0 + quad * 8;
        const int ks = kq ^ ((ln & 7) * 8);
        const bf16x8 a = ASWZ ? *(const bf16x8*)&A[(wr + ln) * 64 + ks]
                              : *(const bf16x8*)&A[(wr + ln) * LSTR + kq];
#pragma unroll
        for (int nt = 0; nt < 4; ++nt) {
            const bf16x8 b = BSWZ ? *(const bf16x8*)&Bq[(nt * 16 + ln) * 64 + ks]
                                  : *(const bf16x8*)&Bq[(nt * 16 + ln) * LSTR + kq];
            acc[nt] = __builtin_amdgcn_mfma_f32_16x16x32_bf16(a, b, acc[nt], 0, 0, 0);
        }
    }
}

// ---------------- Kernel A (MFMA): per-(bh,chunk) W, U, C ---------------
// qkv input is bf16 now. T=(I+N)^{-1}~=(I-N)(I+N^2)(I+N^4)(I+N^8).
__global__ __launch_bounds__(256)
void chunkA(const u16* __restrict__ qkv, float* __restrict__ ws,
            u16* __restrict__ wbg, u16* __restrict__ ktg) {
    __shared__ u16 Kb[64 * LSTR], Vb[64 * LSTR], KT[64 * LSTR],
                   VT[64 * LSTR], NT[64 * LSTR], HbT[64 * LSTR];
    u16* const Yb = Kb;
    u16* const Np = Vb;
    u16* const UT = NT;

    const int cc = blockIdx.x;
    const int bh = cc >> 4, c = cc & 15;
    const int b = bh / NH, h = bh - b * NH;
    const int tid = threadIdx.x;
    const int w = tid >> 6, lane = tid & 63;
    const int ln = lane & 15, quad = lane >> 4;
    const int wr = w * 16;
    const u16* base = qkv + ((size_t)(b * T_ + c * CS)) * QKVW + h * HS;

    // staging: u16x4 loads; K copied exactly, V scaled by lam^-(t+1)
    {
        const int tr0 = w * 4 + quad;
        const int d0 = ln * 4;
        float vsc = __powf(LAM, -(float)(tr0 + 1));
        const float v16 = __powf(LAM, -16.0f);
#pragma unroll
        for (int p = 0; p < 4; ++p) {
            const int t = p * 16 + tr0;
            const u16x4 k4 = *(const u16x4*)(base + (size_t)t * QKVW + CDIM + d0);
            const u16x4 vu = *(const u16x4*)(base + (size_t)t * QKVW + 2 * CDIM + d0);
            u16x4 v4; v4.x = f2bf(bf2f(vu.x) * vsc); v4.y = f2bf(bf2f(vu.y) * vsc);
            v4.z = f2bf(bf2f(vu.z) * vsc); v4.w = f2bf(bf2f(vu.w) * vsc);
            *(u16x4*)&Kb[t * LSTR + d0] = k4;
            *(u16x4*)&Vb[t * LSTR + d0] = v4;
            KT[(d0 + 0) * LSTR + t] = k4.x; KT[(d0 + 1) * LSTR + t] = k4.y;
            KT[(d0 + 2) * LSTR + t] = k4.z; KT[(d0 + 3) * LSTR + t] = k4.w;
            VT[(d0 + 0) * LSTR + t] = v4.x; VT[(d0 + 1) * LSTR + t] = v4.y;
            VT[(d0 + 2) * LSTR + t] = v4.z; VT[(d0 + 3) * LSTR + t] = v4.w;
            vsc *= v16;
        }
    }
    __syncthreads();

    f32x4 accG[4] = {}, accH[4] = {};
    mm_strip2<false,false>(Kb, Kb, wr, ln, quad, accG);   // G = K K^T
    mm_strip2<false,false>(Kb, Vb, wr, ln, quad, accH);   // H = K Vt^T
    __syncthreads();

#pragma unroll
    for (int nt = 0; nt < 4; ++nt) {
        const int col = nt * 16 + ln;
        u16x4 nvT, hvT;
#pragma unroll
        for (int r = 0; r < 4; ++r) {
            const int row = wr + quad * 4 + r;
            const float g = accG[nt][r];
            const u16 nv = (col < row) ? f2bf(BP * g) : (u16)0;
            Np[row * LSTR + col] = nv;
            Yb[row * LSTR + col] = (row == col) ? f2bf(1.0f)
                                 : ((col < row) ? f2bf(-BP * g) : (u16)0);
            ((u16*)&nvT)[r] = nv;
            ((u16*)&hvT)[r] = (col < row) ? f2bf(accH[nt][r]) : (u16)0;
        }
        *(u16x4*)&NT[col * LSTR + wr + quad * 4] = nvT;
        *(u16x4*)&HbT[col * LSTR + wr + quad * 4] = hvT;
    }
    __syncthreads();

    for (int j = 0; j < 3; ++j) {
        f32x4 sq[4] = {};
        mm_strip2<false,false>(Np, NT, wr, ln, quad, sq);
        __syncthreads();
#pragma unroll
        for (int nt = 0; nt < 4; ++nt) {
            const int col = nt * 16 + ln;
            u16x4 sv;
#pragma unroll
            for (int r = 0; r < 4; ++r) {
                const u16 v = f2bf(sq[nt][r]);
                Np[(wr + quad * 4 + r) * LSTR + col] = v;
                ((u16*)&sv)[r] = v;
            }
            *(u16x4*)&NT[col * LSTR + wr + quad * 4] = sv;
        }
        __syncthreads();
        f32x4 ya[4];
#pragma unroll
        for (int nt = 0; nt < 4; ++nt)
#pragma unroll
            for (int r = 0; r < 4; ++r)
                ya[nt][r] = bf2f(Yb[(wr + quad * 4 + r) * LSTR + nt * 16 + ln]);
        mm_strip2<false,false>(Yb, NT, wr, ln, quad, ya);
#pragma unroll
        for (int nt = 0; nt < 4; ++nt)
#pragma unroll
            for (int r = 0; r < 4; ++r)
                Yb[(wr + quad * 4 + r) * LSTR + nt * 16 + ln] = f2bf(ya[nt][r]);
    }

    u16* Ugp = (u16*)(ws + OFF_U) + (size_t)cc * 4096;
    float* Cg = ws + OFF_C + (size_t)cc * 4096;

    f32x4 wv[4] = {};
    mm_strip2<false,false>(Yb, KT, wr, ln, quad, wv);       // W = Y*K

    f32x4 m1[4] = {};
    mm_strip2<false,false>(Yb, HbT, wr, ln, quad, m1);      // M1 = Y*H_SL
#pragma unroll
    for (int nt = 0; nt < 4; ++nt)
#pragma unroll
        for (int r = 0; r < 4; ++r)
            Np[(wr + quad * 4 + r) * LSTR + nt * 16 + ln] = f2bf(m1[nt][r]);

#pragma unroll
    for (int nt = 0; nt < 4; ++nt)
#pragma unroll
        for (int r = 0; r < 4; ++r)
            Yb[(wr + quad * 4 + r) * LSTR + nt * 16 + ln] = f2bf(wv[nt][r]);

    f32x4 uv[4] = {};
    mm_strip2<false,false>(Np, KT, wr, ln, quad, uv);       // U = M1*K
#pragma unroll
    for (int nt = 0; nt < 4; ++nt)
        *(u16x4*)&Ugp[(size_t)(w * 64 + lane) * 16 + nt * 4] = f2bf4(uv[nt]);
    __syncthreads();
#pragma unroll
    for (int nt = 0; nt < 4; ++nt)
        *(u16x4*)&UT[(nt * 16 + ln) * LSTR + wr + quad * 4] = f2bf4(uv[nt]);
    __syncthreads();

    f32x4 c1[4] = {}, c2[4] = {};
    mm_strip2<false,false>(VT, KT, wr, ln, quad, c1);       // Vt^T K
    mm_strip2<false,false>(KT, UT, wr, ln, quad, c2);       // K^T U
#pragma unroll
    for (int nt = 0; nt < 4; ++nt) {
        const f32x4 cv = c1[nt] - BP * c2[nt];
        *(f32x4*)&Cg[(size_t)(w * 64 + lane) * 16 + nt * 4] = cv;
    }

    for (int e = tid; e < 512; e += 256) {
        const int t = e >> 3, g = e & 7;
        *(bf16x8*)&wbg[(size_t)cc * 4096 + t * 64 + ((g ^ (t & 7)) << 3)] =
            *(const bf16x8*)&Yb[t * LSTR + (g << 3)];
    }
    for (int e = tid; e < 512; e += 256) {
        const int d = e >> 3, g = e & 7;
        *(bf16x8*)&ktg[(size_t)cc * 4096 + d * 64 + ((g ^ (d & 7)) << 3)] =
            *(const bf16x8*)&KT[d * LSTR + (g << 3)];
    }
}

// ---------------- Kernel B (MFMA): sequential 16-chunk sweep per bh -----
__global__ __launch_bounds__(256)
void chunkB(float* __restrict__ ws, const u16* __restrict__ wbg,
            const u16* __restrict__ ktg) {
    __shared__ u16 WBs[2][4096], KTs[2][4096];
    __shared__ u16 RTb[64 * LSTR], PTb[64 * LSTR];

    const int bh = blockIdx.x;
    const int tid = threadIdx.x;
    const int w = tid >> 6, lane = tid & 63;
    const int ln = lane & 15, quad = lane >> 4;
    const int wr = w * 16;
    const float lam64 = __powf(LAM, 64.0f);
    u16* r0tg = (u16*)(ws + OFF_R0);

    f32x4 R[4] = {};

    for (int e = tid; e < 64 * LSTR; e += 256) RTb[e] = 0;

    const int off = w * 1024;
    {
        const size_t b0 = (size_t)(bh * 16) * 4096;
#pragma unroll
        for (int i = 0; i < 2; ++i) {
            gll16(wbg + b0 + off + i * 512 + lane * 8, &WBs[0][off + i * 512]);
            gll16(ktg + b0 + off + i * 512 + lane * 8, &KTs[0][off + i * 512]);
        }
    }
    __syncthreads();

    for (int c = 0; c < NC; ++c) {
        const int buf = c & 1;
        const size_t cc = (size_t)(bh * 16 + c);

        if (c + 1 < NC) {
            const size_t b1 = (cc + 1) * 4096;
#pragma unroll
            for (int i = 0; i < 2; ++i) {
                gll16(wbg + b1 + off + i * 512 + lane * 8, &WBs[buf ^ 1][off + i * 512]);
                gll16(ktg + b1 + off + i * 512 + lane * 8, &KTs[buf ^ 1][off + i * 512]);
            }
        }

        f32x4 p[4] = {};
        mm_strip2<true,false>(&WBs[buf][0], RTb, wr, ln, quad, p);   // P = W R
#pragma unroll
        for (int nt = 0; nt < 4; ++nt)
            *(u16x4*)&PTb[(nt * 16 + ln) * LSTR + wr + quad * 4] = f2bf4(p[nt]);
        __syncthreads();

        f32x4 kp[4] = {};
        mm_strip2<true,false>(&KTs[buf][0], PTb, wr, ln, quad, kp);  // K^T P

        u16* r0t = r0tg + cc * 4096;
        const float* Cg = ws + OFF_C + cc * 4096 + (size_t)(w * 64 + lane) * 16;
        const int swz = (wr + quad * 4) ^ ((ln & 7) * 8);
#pragma unroll
        for (int nt = 0; nt < 4; ++nt) {
            const int x = nt * 16 + ln;
            *(u16x4*)&r0t[x * 64 + swz] = f2bf4(R[nt]);
            const f32x4 cv = *(const f32x4*)&Cg[nt * 4];
            R[nt] = lam64 * (R[nt] - BP * kp[nt] + cv);
            *(u16x4*)&RTb[x * LSTR + wr + quad * 4] = f2bf4(R[nt]);
        }
        __syncthreads();
    }
}

// ---------------- Kernel C (MFMA): outputs per (bh,chunk) ---------------
__global__ __launch_bounds__(256)
void chunkC(const u16* __restrict__ qkv, float* __restrict__ ws,
            const u16* __restrict__ wbg, const u16* __restrict__ ktg,
            u16* __restrict__ ob) {
    __shared__ u16 Wb[4096], KTb[4096], R0Tb[4096];
    __shared__ u16 Qhb[64 * LSTR], Kb[64 * LSTR], Vtb[64 * LSTR],
                   RmTb[64 * LSTR];
    u16* const A1m = Kb;
    u16* const A2m = Vtb;

    const int cc = blockIdx.x;
    const int bh = cc >> 4, c = cc & 15;
    const int b = bh / NH, h = bh - b * NH;
    const int tid = threadIdx.x;
    const int w = tid >> 6, lane = tid & 63;
    const int ln = lane & 15, quad = lane >> 4;
    const int wr = w * 16;
    const u16* base = qkv + ((size_t)(b * T_ + c * CS)) * QKVW + h * HS;
    const u16* r0tg = (const u16*)(ws + OFF_R0);

    const int off = w * 1024;
    {
        const size_t bb = (size_t)cc * 4096;
#pragma unroll
        for (int i = 0; i < 2; ++i) {
            gll16(wbg  + bb + off + i * 512 + lane * 8, &Wb[off + i * 512]);
            gll16(ktg  + bb + off + i * 512 + lane * 8, &KTb[off + i * 512]);
            gll16(r0tg + bb + off + i * 512 + lane * 8, &R0Tb[off + i * 512]);
        }
    }
    {
        const int tr0 = w * 4 + quad;
        const int d0 = ln * 4;
        float qsc = __powf(LAM, (float)(tr0 + 1));
        float vsc = 1.0f / qsc;
        const float q16 = __powf(LAM, 16.0f);
        const float v16 = 1.0f / q16;
#pragma unroll
        for (int p = 0; p < 4; ++p) {
            const int t = p * 16 + tr0;
            const u16x4 qu = *(const u16x4*)(base + (size_t)t * QKVW + d0);
            const u16x4 ku = *(const u16x4*)(base + (size_t)t * QKVW + CDIM + d0);
            const u16x4 vu = *(const u16x4*)(base + (size_t)t * QKVW + 2 * CDIM + d0);
            u16x4 q4; q4.x = f2bf(bf2f(qu.x) * qsc); q4.y = f2bf(bf2f(qu.y) * qsc);
            q4.z = f2bf(bf2f(qu.z) * qsc); q4.w = f2bf(bf2f(qu.w) * qsc);
            u16x4 v4; v4.x = f2bf(bf2f(vu.x) * vsc); v4.y = f2bf(bf2f(vu.y) * vsc);
            v4.z = f2bf(bf2f(vu.z) * vsc); v4.w = f2bf(bf2f(vu.w) * vsc);
            *(u16x4*)&Qhb[t * LSTR + d0] = q4;
            *(u16x4*)&Kb[t * LSTR + d0] = ku;
            *(u16x4*)&Vtb[t * LSTR + d0] = v4;
            qsc *= q16; vsc *= v16;
        }
    }
    __syncthreads();

    f32x4 a1[4] = {}, a2[4] = {}, Oacc[4] = {}, wr0[4] = {};
    mm_strip2<false,false>(Qhb, Kb,   wr, ln, quad, a1);
    mm_strip2<false,false>(Qhb, Vtb,  wr, ln, quad, a2);
    mm_strip2<false,true >(Qhb, R0Tb, wr, ln, quad, Oacc);
    mm_strip2<true ,true >(Wb,  R0Tb, wr, ln, quad, wr0);

    const u16* Ugp = (const u16*)(ws + OFF_U) + (size_t)cc * 4096
                     + (size_t)(w * 64 + lane) * 16;
    const int row = wr + quad * 4;
#pragma unroll
    for (int nt = 0; nt < 4; ++nt) {
        const u16x4 uu = *(const u16x4*)&Ugp[nt * 4];
        wr0[nt][0] += bf2f(uu.x); wr0[nt][1] += bf2f(uu.y);
        wr0[nt][2] += bf2f(uu.z); wr0[nt][3] += bf2f(uu.w);
    }
    __syncthreads();

#pragma unroll
    for (int nt = 0; nt < 4; ++nt) {
        const int col = nt * 16 + ln;
#pragma unroll
        for (int r = 0; r < 4; ++r) {
            const int t = row + r;
            A1m[t * LSTR + col] = (col <= t) ? f2bf(a1[nt][r]) : (u16)0;
            A2m[t * LSTR + col] = (col <= t) ? f2bf(a2[nt][r]) : (u16)0;
        }
        *(u16x4*)&RmTb[col * LSTR + row] = f2bf4(wr0[nt]);
    }
    __syncthreads();

    f32x4 O3[4] = {};
    mm_strip2<false,true >(A2m, KTb,  wr, ln, quad, Oacc);
    mm_strip2<false,false>(A1m, RmTb, wr, ln, quad, O3);

#pragma unroll
    for (int nt = 0; nt < 4; ++nt) {
        const int col = nt * 16 + ln;
#pragma unroll
        for (int r = 0; r < 4; ++r) {
            const float o = Oacc[nt][r] - BP * O3[nt][r];
            ob[((size_t)(b * T_ + c * CS + row + r)) * CDIM + h * HS + col] = f2bf(o);
        }
    }
}

// ------------------------------ launch ----------------------------------
extern "C" void kernel_launch(void* const* d_in, const int* in_sizes, int n_in,
                              void* d_out, int out_size, void* d_ws, size_t ws_size,
                              hipStream_t stream) {
    const float* x      = (const float*)d_in[0];   // (4,1024,768)
    const float* w_attn = (const float*)d_in[1];   // (768, 2304)
    const float* w_proj = (const float*)d_in[2];   // (768, 768)
    float* ws  = (float*)d_ws;
    u16* qkv = (u16*)ws;                  // bf16 normalized qkv
    u16* xb  = (u16*)(ws + OFF_XB);
    u16* waT = (u16*)(ws + OFF_WAT);
    u16* ob  = (u16*)(ws + OFF_C);
    u16* wpT = (u16*)(ws + OFF_R0 - 294912);  // dead fp32 C region tail (after ob span)
    u16* wbg = (u16*)d_out;               // scratch: bf16 W  (swizzled)
    u16* ktg = (u16*)d_out + 768 * 4096;  // scratch: bf16 K^T (swizzled)

    // casts for gemm1
    cast_x_kernel<<<(MROWS * CDIM) / (256 * 4), 256, 0, stream>>>(x, xb);
    tcast_kernel<<<dim3(QKVW / 64, CDIM / 64), 256, 0, stream>>>(w_attn, waT, QKVW, CDIM);

    // 1) qkv = norm(x @ w_attn), bf16 out (fused standardization epilogue)
    gemm_mfma<false, true><<<dim3(QKVW / 128, MROWS / 128), 256, 0, stream>>>(
        xb, waT, nullptr, qkv, QKVW, CDIM);

    // 2) chunked WY scan (all MFMA)
    chunkA<<<768, 256, 0, stream>>>(qkv, ws, wbg, ktg);
    chunkB<<<48,  256, 0, stream>>>(ws, wbg, ktg);
    chunkC<<<768, 256, 0, stream>>>(qkv, ws, wbg, ktg, ob);

    // 3) y = o @ w_proj + x  (bf16 MFMA, residual fused, writes d_out)
    tcast_kernel<<<dim3(CDIM / 64, CDIM / 64), 256, 0, stream>>>(w_proj, wpT, CDIM, CDIM);
    gemm_mfma<true, false><<<dim3(CDIM / 128, MROWS / 128), 256, 0, stream>>>(
        ob, wpT, x, (float*)d_out, CDIM, CDIM);
}

// Round 12
// 181.821 us; speedup vs baseline: 4.8589x; 1.0314x over previous
//
#include <hip/hip_runtime.h>

typedef unsigned short u16;
typedef __attribute__((ext_vector_type(4))) unsigned short u16x4;
typedef __attribute__((ext_vector_type(8))) short bf16x8;
typedef __attribute__((ext_vector_type(4))) float f32x4;

#define B_ 4
#define T_ 1024
#define NH 12
#define HS 64
#define CDIM 768
#define QKVW 2304   // 3*CDIM
#define NC 16
#define CS 64
#define LAM 0.99f
#define BP  (0.01f/0.99f)
#define MROWS 4096
#define LSTR 72     // bf16 LDS row stride: 144B, 16B-aligned, 2-way banks (free)

// ws layout (float offsets). qkv bf16 at ws[0] (span 4718592 floats).
// [4718592, 9437184) is permanently free -> wpT lives there.
#define OFF_WPT 4718592
#define OFF_W  9437184
#define OFF_U  (OFF_W  + 768*4096)   // bf16 permuted U (u16, half-used)
#define OFF_C  (OFF_U  + 768*4096)   // bf16 permuted C; later bf16 ob (aliased)
#define OFF_R0 (OFF_C  + 768*4096)   // bf16 swizzled R0^T (u16)
#define OFF_XB (OFF_W)                       // bf16 x
#define OFF_WAT (OFF_W + 1572864)            // bf16 w_attn^T
// d_out doubles as scratch: wbg (bf16 W, swizzled) + ktg (bf16 K^T, swizzled)

__device__ __forceinline__ u16 f2bf(float f) {
    union { float f; unsigned u; } a; a.f = f;
    const unsigned r = a.u + 0x7FFF + ((a.u >> 16) & 1);
    return (u16)(r >> 16);
}
__device__ __forceinline__ float bf2f(u16 h) {
    union { unsigned u; float f; } a; a.u = ((unsigned)h) << 16; return a.f;
}
__device__ __forceinline__ u16x4 f2bf4(const f32x4 v) {
    u16x4 u; u.x = f2bf(v[0]); u.y = f2bf(v[1]); u.z = f2bf(v[2]); u.w = f2bf(v[3]);
    return u;
}

// ---------------- merged cast kernel ------------------------------------
// blocks [0,3072): x -> bf16 xb (straight)
// blocks [3072,3504): w_attn [768][2304] -> waT [2304][768] bf16
// blocks [3504,3648): w_proj [768][768]  -> wpT [768][768]  bf16
__device__ __forceinline__ void tcast_body(const float* __restrict__ src,
                                           u16* __restrict__ dst,
                                           int Cn, int Rr, int bx, int by) {
    const int ln = threadIdx.x & 63, kg = threadIdx.x >> 6;
    const int n = bx * 64 + ln;
    const int kb = by * 64 + kg * 16;
    u16 tmp[16];
#pragma unroll
    for (int j = 0; j < 16; ++j)
        tmp[j] = f2bf(src[(size_t)(kb + j) * Cn + n]);
#pragma unroll
    for (int j4 = 0; j4 < 4; ++j4) {
        u16x4 u; u.x = tmp[j4*4]; u.y = tmp[j4*4+1]; u.z = tmp[j4*4+2]; u.w = tmp[j4*4+3];
        *(u16x4*)&dst[(size_t)n * Rr + kb + j4*4] = u;
    }
}

__global__ __launch_bounds__(256)
void cast_all_kernel(const float* __restrict__ x, const float* __restrict__ wa,
                     const float* __restrict__ wp, u16* __restrict__ xb,
                     u16* __restrict__ waT, u16* __restrict__ wpT) {
    const int bid = blockIdx.x;
    if (bid < 3072) {
        const size_t i = ((size_t)bid * 256 + threadIdx.x) * 4;
        const float4 v = *(const float4*)(x + i);
        u16x4 u;
        u.x = f2bf(v.x); u.y = f2bf(v.y); u.z = f2bf(v.z); u.w = f2bf(v.w);
        *(u16x4*)(xb + i) = u;
    } else if (bid < 3504) {
        const int idx = bid - 3072;
        tcast_body(wa, waT, QKVW, CDIM, idx % 36, idx / 36);
    } else {
        const int idx = bid - 3504;
        tcast_body(wp, wpT, CDIM, CDIM, idx % 12, idx / 12);
    }
}

// ---------------- MFMA GEMM: C[M,N] = A[M,K] @ Bt[N,K]^T ----------------
// NORM: per-64-col-group standardization epilogue, bf16 out. Else fp32 (+R).
__device__ __forceinline__ void gll16(const u16* g, u16* lds) {
    __builtin_amdgcn_global_load_lds(
        (const __attribute__((address_space(1))) unsigned*)g,
        (__attribute__((address_space(3))) unsigned*)lds, 16, 0, 0);
}

template<bool ADD_RES, bool NORM>
__global__ __launch_bounds__(256)
void gemm_mfma(const u16* __restrict__ A, const u16* __restrict__ Bt,
               const float* __restrict__ R, void* __restrict__ Cout,
               int N, int K) {
    __shared__ u16 As[128 * 64];
    __shared__ u16 Bs[128 * 64];
    const int tid  = threadIdx.x;
    const int wave = tid >> 6, lane = tid & 63;
    const int wm = wave >> 1, wn = wave & 1;
    const int ln = lane & 15, quad = lane >> 4;
    const int m0 = blockIdx.y * 128, n0 = blockIdx.x * 128;

    const int rl = lane >> 3;
    const int kx = ((lane & 7) ^ rl) * 8;
    const u16* Ag = A + (size_t)(m0 + wave * 32 + rl) * K + kx;
    const u16* Bg = Bt + (size_t)(n0 + wave * 32 + rl) * K + kx;
    u16* AsW = &As[(wave * 32) * 64];
    u16* BsW = &Bs[(wave * 32) * 64];

    f32x4 acc[4][4] = {};

    for (int k0 = 0; k0 < K; k0 += 64) {
        __syncthreads();
#pragma unroll
        for (int c8 = 0; c8 < 4; ++c8) {
            gll16(Ag + (size_t)(c8 * 8) * K + k0, AsW + c8 * 8 * 64);
            gll16(Bg + (size_t)(c8 * 8) * K + k0, BsW + c8 * 8 * 64);
        }
        __syncthreads();
#pragma unroll
        for (int k32 = 0; k32 < 64; k32 += 32) {
            const int ko = (k32 + quad * 8) ^ ((ln & 7) * 8);
            bf16x8 af[4], bfr[4];
#pragma unroll
            for (int mi = 0; mi < 4; ++mi)
                af[mi] = *(const bf16x8*)&As[(wm * 64 + mi * 16 + ln) * 64 + ko];
#pragma unroll
            for (int ni = 0; ni < 4; ++ni)
                bfr[ni] = *(const bf16x8*)&Bs[(wn * 64 + ni * 16 + ln) * 64 + ko];
#pragma unroll
            for (int mi = 0; mi < 4; ++mi)
#pragma unroll
                for (int ni = 0; ni < 4; ++ni)
                    acc[mi][ni] = __builtin_amdgcn_mfma_f32_16x16x32_bf16(
                        af[mi], bfr[ni], acc[mi][ni], 0, 0, 0);
        }
    }

#pragma unroll
    for (int mi = 0; mi < 4; ++mi) {
        const int rb = m0 + wm * 64 + mi * 16 + quad * 4;
#pragma unroll
        for (int r = 0; r < 4; ++r) {
            if (NORM) {
                const float a0 = acc[mi][0][r], a1 = acc[mi][1][r];
                const float a2 = acc[mi][2][r], a3 = acc[mi][3][r];
                float s1 = a0 + a1 + a2 + a3;
                float s2 = a0*a0 + a1*a1 + a2*a2 + a3*a3;
#pragma unroll
                for (int m = 1; m < 16; m <<= 1) {
                    s1 += __shfl_xor(s1, m, 64);
                    s2 += __shfl_xor(s2, m, 64);
                }
                const float mu = s1 * (1.0f / 64.0f);
                const float rs = rsqrtf((s2 - 64.0f * mu * mu) * (1.0f / 63.0f));
                u16* op = (u16*)Cout + (size_t)(rb + r) * N + n0 + wn * 64 + ln;
                op[0]  = f2bf((a0 - mu) * rs);
                op[16] = f2bf((a1 - mu) * rs);
                op[32] = f2bf((a2 - mu) * rs);
                op[48] = f2bf((a3 - mu) * rs);
            } else {
#pragma unroll
                for (int ni = 0; ni < 4; ++ni) {
                    const int col = n0 + wn * 64 + ni * 16 + ln;
                    float v = acc[mi][ni][r];
                    if (ADD_RES) v += R[(size_t)(rb + r) * N + col];
                    ((float*)Cout)[(size_t)(rb + r) * N + col] = v;
                }
            }
        }
    }
}

// ---------------- MFMA strip microkernel --------------------------------
template<bool ASWZ, bool BSWZ>
__device__ __forceinline__ void mm_strip2(const u16* A, const u16* Bq,
                                          int wr, int ln, int quad, f32x4 (&acc)[4]) {
#pragma unroll
    for (int k0 = 0; k0 < 64; k0 += 32) {
        const int kq = k0 + quad * 8;
        const int ks = kq ^ ((ln & 7) * 8);
        const bf16x8 a = ASWZ ? *(const bf16x8*)&A[(wr + ln) * 64 + ks]
                              : *(const bf16x8*)&A[(wr + ln) * LSTR + kq];
#pragma unroll
        for (int nt = 0; nt < 4; ++nt) {
            const bf16x8 b = BSWZ ? *(const bf16x8*)&Bq[(nt * 16 + ln) * 64 + ks]
                                  : *(const bf16x8*)&Bq[(nt * 16 + ln) * LSTR + kq];
            acc[nt] = __builtin_amdgcn_mfma_f32_16x16x32_bf16(a, b, acc[nt], 0, 0, 0);
        }
    }
}

// ---------------- Kernel A (MFMA): per-(bh,chunk) W, U, C ---------------
__global__ __launch_bounds__(256)
void chunkA(const u16* __restrict__ qkv, float* __restrict__ ws,
            u16* __restrict__ wbg, u16* __restrict__ ktg) {
    __shared__ u16 Kb[64 * LSTR], Vb[64 * LSTR], KT[64 * LSTR],
                   VT[64 * LSTR], NT[64 * LSTR], HbT[64 * LSTR];
    u16* const Yb = Kb;
    u16* const Np = Vb;
    u16* const UT = NT;

    const int cc = blockIdx.x;
    const int bh = cc >> 4, c = cc & 15;
    const int b = bh / NH, h = bh - b * NH;
    const int tid = threadIdx.x;
    const int w = tid >> 6, lane = tid & 63;
    const int ln = lane & 15, quad = lane >> 4;
    const int wr = w * 16;
    const u16* base = qkv + ((size_t)(b * T_ + c * CS)) * QKVW + h * HS;

    {
        const int tr0 = w * 4 + quad;
        const int d0 = ln * 4;
        float vsc = __powf(LAM, -(float)(tr0 + 1));
        const float v16 = __powf(LAM, -16.0f);
#pragma unroll
        for (int p = 0; p < 4; ++p) {
            const int t = p * 16 + tr0;
            const u16x4 k4 = *(const u16x4*)(base + (size_t)t * QKVW + CDIM + d0);
            const u16x4 vu = *(const u16x4*)(base + (size_t)t * QKVW + 2 * CDIM + d0);
            u16x4 v4; v4.x = f2bf(bf2f(vu.x) * vsc); v4.y = f2bf(bf2f(vu.y) * vsc);
            v4.z = f2bf(bf2f(vu.z) * vsc); v4.w = f2bf(bf2f(vu.w) * vsc);
            *(u16x4*)&Kb[t * LSTR + d0] = k4;
            *(u16x4*)&Vb[t * LSTR + d0] = v4;
            KT[(d0 + 0) * LSTR + t] = k4.x; KT[(d0 + 1) * LSTR + t] = k4.y;
            KT[(d0 + 2) * LSTR + t] = k4.z; KT[(d0 + 3) * LSTR + t] = k4.w;
            VT[(d0 + 0) * LSTR + t] = v4.x; VT[(d0 + 1) * LSTR + t] = v4.y;
            VT[(d0 + 2) * LSTR + t] = v4.z; VT[(d0 + 3) * LSTR + t] = v4.w;
            vsc *= v16;
        }
    }
    __syncthreads();

    f32x4 accG[4] = {}, accH[4] = {};
    mm_strip2<false,false>(Kb, Kb, wr, ln, quad, accG);   // G = K K^T
    mm_strip2<false,false>(Kb, Vb, wr, ln, quad, accH);   // H = K Vt^T
    __syncthreads();

#pragma unroll
    for (int nt = 0; nt < 4; ++nt) {
        const int col = nt * 16 + ln;
        u16x4 nvT, hvT;
#pragma unroll
        for (int r = 0; r < 4; ++r) {
            const int row = wr + quad * 4 + r;
            const float g = accG[nt][r];
            const u16 nv = (col < row) ? f2bf(BP * g) : (u16)0;
            Np[row * LSTR + col] = nv;
            Yb[row * LSTR + col] = (row == col) ? f2bf(1.0f)
                                 : ((col < row) ? f2bf(-BP * g) : (u16)0);
            ((u16*)&nvT)[r] = nv;
            ((u16*)&hvT)[r] = (col < row) ? f2bf(accH[nt][r]) : (u16)0;
        }
        *(u16x4*)&NT[col * LSTR + wr + quad * 4] = nvT;
        *(u16x4*)&HbT[col * LSTR + wr + quad * 4] = hvT;
    }
    __syncthreads();

    for (int j = 0; j < 3; ++j) {
        f32x4 sq[4] = {};
        mm_strip2<false,false>(Np, NT, wr, ln, quad, sq);
        __syncthreads();
#pragma unroll
        for (int nt = 0; nt < 4; ++nt) {
            const int col = nt * 16 + ln;
            u16x4 sv;
#pragma unroll
            for (int r = 0; r < 4; ++r) {
                const u16 v = f2bf(sq[nt][r]);
                Np[(wr + quad * 4 + r) * LSTR + col] = v;
                ((u16*)&sv)[r] = v;
            }
            *(u16x4*)&NT[col * LSTR + wr + quad * 4] = sv;
        }
        __syncthreads();
        f32x4 ya[4];
#pragma unroll
        for (int nt = 0; nt < 4; ++nt)
#pragma unroll
            for (int r = 0; r < 4; ++r)
                ya[nt][r] = bf2f(Yb[(wr + quad * 4 + r) * LSTR + nt * 16 + ln]);
        mm_strip2<false,false>(Yb, NT, wr, ln, quad, ya);
#pragma unroll
        for (int nt = 0; nt < 4; ++nt)
#pragma unroll
            for (int r = 0; r < 4; ++r)
                Yb[(wr + quad * 4 + r) * LSTR + nt * 16 + ln] = f2bf(ya[nt][r]);
    }

    u16* Ugp = (u16*)(ws + OFF_U) + (size_t)cc * 4096;
    u16* Cgp = (u16*)(ws + OFF_C) + (size_t)cc * 4096;

    f32x4 wv[4] = {};
    mm_strip2<false,false>(Yb, KT, wr, ln, quad, wv);       // W = Y*K

    f32x4 m1[4] = {};
    mm_strip2<false,false>(Yb, HbT, wr, ln, quad, m1);      // M1 = Y*H_SL
#pragma unroll
    for (int nt = 0; nt < 4; ++nt)
#pragma unroll
        for (int r = 0; r < 4; ++r)
            Np[(wr + quad * 4 + r) * LSTR + nt * 16 + ln] = f2bf(m1[nt][r]);

#pragma unroll
    for (int nt = 0; nt < 4; ++nt)
#pragma unroll
        for (int r = 0; r < 4; ++r)
            Yb[(wr + quad * 4 + r) * LSTR + nt * 16 + ln] = f2bf(wv[nt][r]);

    f32x4 uv[4] = {};
    mm_strip2<false,false>(Np, KT, wr, ln, quad, uv);       // U = M1*K
#pragma unroll
    for (int nt = 0; nt < 4; ++nt)
        *(u16x4*)&Ugp[(size_t)(w * 64 + lane) * 16 + nt * 4] = f2bf4(uv[nt]);
    __syncthreads();
#pragma unroll
    for (int nt = 0; nt < 4; ++nt)
        *(u16x4*)&UT[(nt * 16 + ln) * LSTR + wr + quad * 4] = f2bf4(uv[nt]);
    __syncthreads();

    f32x4 c1[4] = {}, c2[4] = {};
    mm_strip2<false,false>(VT, KT, wr, ln, quad, c1);       // Vt^T K
    mm_strip2<false,false>(KT, UT, wr, ln, quad, c2);       // K^T U
#pragma unroll
    for (int nt = 0; nt < 4; ++nt) {
        const f32x4 cv = c1[nt] - BP * c2[nt];
        *(u16x4*)&Cgp[(size_t)(w * 64 + lane) * 16 + nt * 4] = f2bf4(cv);
    }

    for (int e = tid; e < 512; e += 256) {
        const int t = e >> 3, g = e & 7;
        *(bf16x8*)&wbg[(size_t)cc * 4096 + t * 64 + ((g ^ (t & 7)) << 3)] =
            *(const bf16x8*)&Yb[t * LSTR + (g << 3)];
    }
    for (int e = tid; e < 512; e += 256) {
        const int d = e >> 3, g = e & 7;
        *(bf16x8*)&ktg[(size_t)cc * 4096 + d * 64 + ((g ^ (d & 7)) << 3)] =
            *(const bf16x8*)&KT[d * LSTR + (g << 3)];
    }
}

// ---------------- Kernel B (MFMA): sequential 16-chunk sweep per bh -----
__global__ __launch_bounds__(256)
void chunkB(float* __restrict__ ws, const u16* __restrict__ wbg,
            const u16* __restrict__ ktg) {
    __shared__ u16 WBs[2][4096], KTs[2][4096];
    __shared__ u16 RTb[64 * LSTR], PTb[64 * LSTR];

    const int bh = blockIdx.x;
    const int tid = threadIdx.x;
    const int w = tid >> 6, lane = tid & 63;
    const int ln = lane & 15, quad = lane >> 4;
    const int wr = w * 16;
    const float lam64 = __powf(LAM, 64.0f);
    u16* r0tg = (u16*)(ws + OFF_R0);

    f32x4 R[4] = {};

    for (int e = tid; e < 64 * LSTR; e += 256) RTb[e] = 0;

    const int off = w * 1024;
    {
        const size_t b0 = (size_t)(bh * 16) * 4096;
#pragma unroll
        for (int i = 0; i < 2; ++i) {
            gll16(wbg + b0 + off + i * 512 + lane * 8, &WBs[0][off + i * 512]);
            gll16(ktg + b0 + off + i * 512 + lane * 8, &KTs[0][off + i * 512]);
        }
    }
    __syncthreads();

    for (int c = 0; c < NC; ++c) {
        const int buf = c & 1;
        const size_t cc = (size_t)(bh * 16 + c);

        if (c + 1 < NC) {
            const size_t b1 = (cc + 1) * 4096;
#pragma unroll
            for (int i = 0; i < 2; ++i) {
                gll16(wbg + b1 + off + i * 512 + lane * 8, &WBs[buf ^ 1][off + i * 512]);
                gll16(ktg + b1 + off + i * 512 + lane * 8, &KTs[buf ^ 1][off + i * 512]);
            }
        }

        f32x4 p[4] = {};
        mm_strip2<true,false>(&WBs[buf][0], RTb, wr, ln, quad, p);   // P = W R
#pragma unroll
        for (int nt = 0; nt < 4; ++nt)
            *(u16x4*)&PTb[(nt * 16 + ln) * LSTR + wr + quad * 4] = f2bf4(p[nt]);
        __syncthreads();

        f32x4 kp[4] = {};
        mm_strip2<true,false>(&KTs[buf][0], PTb, wr, ln, quad, kp);  // K^T P

        u16* r0t = r0tg + cc * 4096;
        const u16* Cg = (const u16*)(ws + OFF_C) + cc * 4096
                        + (size_t)(w * 64 + lane) * 16;
        const int swz = (wr + quad * 4) ^ ((ln & 7) * 8);
#pragma unroll
        for (int nt = 0; nt < 4; ++nt) {
            const int x = nt * 16 + ln;
            *(u16x4*)&r0t[x * 64 + swz] = f2bf4(R[nt]);
            const u16x4 cu = *(const u16x4*)&Cg[nt * 4];
            f32x4 cv; cv[0] = bf2f(cu.x); cv[1] = bf2f(cu.y);
            cv[2] = bf2f(cu.z); cv[3] = bf2f(cu.w);
            R[nt] = lam64 * (R[nt] - BP * kp[nt] + cv);
            *(u16x4*)&RTb[x * LSTR + wr + quad * 4] = f2bf4(R[nt]);
        }
        __syncthreads();
    }
}

// ---------------- Kernel C (MFMA): outputs per (bh,chunk) ---------------
__global__ __launch_bounds__(256)
void chunkC(const u16* __restrict__ qkv, float* __restrict__ ws,
            const u16* __restrict__ wbg, const u16* __restrict__ ktg,
            u16* __restrict__ ob) {
    __shared__ u16 Wb[4096], KTb[4096], R0Tb[4096];
    __shared__ u16 Qhb[64 * LSTR], Kb[64 * LSTR], Vtb[64 * LSTR],
                   RmTb[64 * LSTR];
    u16* const A1m = Kb;
    u16* const A2m = Vtb;

    const int cc = blockIdx.x;
    const int bh = cc >> 4, c = cc & 15;
    const int b = bh / NH, h = bh - b * NH;
    const int tid = threadIdx.x;
    const int w = tid >> 6, lane = tid & 63;
    const int ln = lane & 15, quad = lane >> 4;
    const int wr = w * 16;
    const u16* base = qkv + ((size_t)(b * T_ + c * CS)) * QKVW + h * HS;
    const u16* r0tg = (const u16*)(ws + OFF_R0);

    const int off = w * 1024;
    {
        const size_t bb = (size_t)cc * 4096;
#pragma unroll
        for (int i = 0; i < 2; ++i) {
            gll16(wbg  + bb + off + i * 512 + lane * 8, &Wb[off + i * 512]);
            gll16(ktg  + bb + off + i * 512 + lane * 8, &KTb[off + i * 512]);
            gll16(r0tg + bb + off + i * 512 + lane * 8, &R0Tb[off + i * 512]);
        }
    }
    {
        const int tr0 = w * 4 + quad;
        const int d0 = ln * 4;
        float qsc = __powf(LAM, (float)(tr0 + 1));
        float vsc = 1.0f / qsc;
        const float q16 = __powf(LAM, 16.0f);
        const float v16 = 1.0f / q16;
#pragma unroll
        for (int p = 0; p < 4; ++p) {
            const int t = p * 16 + tr0;
            const u16x4 qu = *(const u16x4*)(base + (size_t)t * QKVW + d0);
            const u16x4 ku = *(const u16x4*)(base + (size_t)t * QKVW + CDIM + d0);
            const u16x4 vu = *(const u16x4*)(base + (size_t)t * QKVW + 2 * CDIM + d0);
            u16x4 q4; q4.x = f2bf(bf2f(qu.x) * qsc); q4.y = f2bf(bf2f(qu.y) * qsc);
            q4.z = f2bf(bf2f(qu.z) * qsc); q4.w = f2bf(bf2f(qu.w) * qsc);
            u16x4 v4; v4.x = f2bf(bf2f(vu.x) * vsc); v4.y = f2bf(bf2f(vu.y) * vsc);
            v4.z = f2bf(bf2f(vu.z) * vsc); v4.w = f2bf(bf2f(vu.w) * vsc);
            *(u16x4*)&Qhb[t * LSTR + d0] = q4;
            *(u16x4*)&Kb[t * LSTR + d0] = ku;
            *(u16x4*)&Vtb[t * LSTR + d0] = v4;
            qsc *= q16; vsc *= v16;
        }
    }
    __syncthreads();

    f32x4 a1[4] = {}, a2[4] = {}, Oacc[4] = {}, wr0[4] = {};
    mm_strip2<false,false>(Qhb, Kb,   wr, ln, quad, a1);
    mm_strip2<false,false>(Qhb, Vtb,  wr, ln, quad, a2);
    mm_strip2<false,true >(Qhb, R0Tb, wr, ln, quad, Oacc);
    mm_strip2<true ,true >(Wb,  R0Tb, wr, ln, quad, wr0);

    const u16* Ugp = (const u16*)(ws + OFF_U) + (size_t)cc * 4096
                     + (size_t)(w * 64 + lane) * 16;
    const int row = wr + quad * 4;
#pragma unroll
    for (int nt = 0; nt < 4; ++nt) {
        const u16x4 uu = *(const u16x4*)&Ugp[nt * 4];
        wr0[nt][0] += bf2f(uu.x); wr0[nt][1] += bf2f(uu.y);
        wr0[nt][2] += bf2f(uu.z); wr0[nt][3] += bf2f(uu.w);
    }
    __syncthreads();

#pragma unroll
    for (int nt = 0; nt < 4; ++nt) {
        const int col = nt * 16 + ln;
#pragma unroll
        for (int r = 0; r < 4; ++r) {
            const int t = row + r;
            A1m[t * LSTR + col] = (col <= t) ? f2bf(a1[nt][r]) : (u16)0;
            A2m[t * LSTR + col] = (col <= t) ? f2bf(a2[nt][r]) : (u16)0;
        }
        *(u16x4*)&RmTb[col * LSTR + row] = f2bf4(wr0[nt]);
    }
    __syncthreads();

    f32x4 O3[4] = {};
    mm_strip2<false,true >(A2m, KTb,  wr, ln, quad, Oacc);
    mm_strip2<false,false>(A1m, RmTb, wr, ln, quad, O3);

#pragma unroll
    for (int nt = 0; nt < 4; ++nt) {
        const int col = nt * 16 + ln;
#pragma unroll
        for (int r = 0; r < 4; ++r) {
            const float o = Oacc[nt][r] - BP * O3[nt][r];
            ob[((size_t)(b * T_ + c * CS + row + r)) * CDIM + h * HS + col] = f2bf(o);
        }
    }
}

// ------------------------------ launch ----------------------------------
extern "C" void kernel_launch(void* const* d_in, const int* in_sizes, int n_in,
                              void* d_out, int out_size, void* d_ws, size_t ws_size,
                              hipStream_t stream) {
    const float* x      = (const float*)d_in[0];   // (4,1024,768)
    const float* w_attn = (const float*)d_in[1];   // (768, 2304)
    const float* w_proj = (const float*)d_in[2];   // (768, 768)
    float* ws  = (float*)d_ws;
    u16* qkv = (u16*)ws;                  // bf16 normalized qkv
    u16* xb  = (u16*)(ws + OFF_XB);
    u16* waT = (u16*)(ws + OFF_WAT);
    u16* wpT = (u16*)(ws + OFF_WPT);      // free region, survives whole pipeline
    u16* ob  = (u16*)(ws + OFF_C);
    u16* wbg = (u16*)d_out;               // scratch: bf16 W  (swizzled)
    u16* ktg = (u16*)d_out + 768 * 4096;  // scratch: bf16 K^T (swizzled)

    // 0) all input casts in one launch
    cast_all_kernel<<<3648, 256, 0, stream>>>(x, w_attn, w_proj, xb, waT, wpT);

    // 1) qkv = norm(x @ w_attn), bf16 out (fused standardization epilogue)
    gemm_mfma<false, true><<<dim3(QKVW / 128, MROWS / 128), 256, 0, stream>>>(
        xb, waT, nullptr, qkv, QKVW, CDIM);

    // 2) chunked WY scan (all MFMA)
    chunkA<<<768, 256, 0, stream>>>(qkv, ws, wbg, ktg);
    chunkB<<<48,  256, 0, stream>>>(ws, wbg, ktg);
    chunkC<<<768, 256, 0, stream>>>(qkv, ws, wbg, ktg, ob);

    // 3) y = o @ w_proj + x  (bf16 MFMA, residual fused, writes d_out)
    gemm_mfma<true, false><<<dim3(CDIM / 128, MROWS / 128), 256, 0, stream>>>(
        ob, wpT, x, (float*)d_out, CDIM, CDIM);
}